// Round 10
// baseline (452.434 us; speedup 1.0000x reference)
//
#include <hip/hip_runtime.h>
#include <stdint.h>

#define L_TOK 16384
#define DM 256
#define DI 512
#define DS 64
#define NH 8
#define HD 64
#define CD 640
#define DP 1160
#define CHUNK 64
#define NC 256
#define EPSF 1e-5f

typedef __attribute__((ext_vector_type(8))) short short8;
typedef __attribute__((ext_vector_type(4))) float f32x4;

#define GLL16(gp, lp) __builtin_amdgcn_global_load_lds((const __attribute__((address_space(1))) void*)(gp), (__attribute__((address_space(3))) void*)(lp), 16, 0, 0)

__device__ __forceinline__ float warp_sum(float v) {
  v += __shfl_xor(v, 1, 64);
  v += __shfl_xor(v, 2, 64);
  v += __shfl_xor(v, 4, 64);
  v += __shfl_xor(v, 8, 64);
  v += __shfl_xor(v, 16, 64);
  v += __shfl_xor(v, 32, 64);
  return v;
}

__device__ __forceinline__ float fexp(float x) { return __expf(x); }
__device__ __forceinline__ float fsilu(float x) { return x * __builtin_amdgcn_rcpf(1.0f + __expf(-x)); }

__device__ __forceinline__ unsigned short f2bf(float f) {
  unsigned int u = __float_as_uint(f);
  unsigned int r = (u + 0x7FFFu + ((u >> 16) & 1u)) >> 16;
  return (unsigned short)r;
}
__device__ __forceinline__ float bf2f(unsigned short u) {
  return __uint_as_float(((unsigned int)u) << 16);
}

// ---------------- serialization ----------------

__global__ __launch_bounds__(256) void minmax_part(const float* __restrict__ pos, float* __restrict__ part) {
  __shared__ float sm[6][4];
  int tid = threadIdx.x;
  int t = blockIdx.x*256 + tid;
  float a = pos[t*3+0], b = pos[t*3+1], c = pos[t*3+2];
  float mn0=a, mn1=b, mn2=c, mx0=a, mx1=b, mx2=c;
  #pragma unroll
  for (int d = 1; d < 64; d <<= 1) {
    mn0=fminf(mn0,__shfl_xor(mn0,d,64));
    mn1=fminf(mn1,__shfl_xor(mn1,d,64));
    mn2=fminf(mn2,__shfl_xor(mn2,d,64));
    mx0=fmaxf(mx0,__shfl_xor(mx0,d,64));
    mx1=fmaxf(mx1,__shfl_xor(mx1,d,64));
    mx2=fmaxf(mx2,__shfl_xor(mx2,d,64));
  }
  if ((tid & 63) == 0) {
    int w = tid >> 6;
    sm[0][w]=mn0; sm[1][w]=mn1; sm[2][w]=mn2;
    sm[3][w]=mx0; sm[4][w]=mx1; sm[5][w]=mx2;
  }
  __syncthreads();
  if (tid < 6) {
    float r = sm[tid][0];
    if (tid < 3) { r=fminf(r,sm[tid][1]); r=fminf(r,sm[tid][2]); r=fminf(r,sm[tid][3]); }
    else         { r=fmaxf(r,sm[tid][1]); r=fmaxf(r,sm[tid][2]); r=fmaxf(r,sm[tid][3]); }
    part[blockIdx.x*6 + tid] = r;
  }
}

__device__ unsigned int hilbert3(unsigned int a, unsigned int b, unsigned int c) {
  unsigned int x0 = a, x1 = b, x2 = c;
  for (unsigned int Q = 512u; Q > 1u; Q >>= 1) {
    unsigned int P = Q - 1u;
    { if (x0 & Q) x0 ^= P; }
    {
      unsigned int t = (x0 ^ x1) & P;
      if (x1 & Q) { x0 ^= P; }
      else { x0 ^= t; x1 ^= t; }
    }
    {
      unsigned int t = (x0 ^ x2) & P;
      if (x2 & Q) { x0 ^= P; }
      else { x0 ^= t; x2 ^= t; }
    }
  }
  x1 ^= x0; x2 ^= x1;
  unsigned int tt = 0;
  for (unsigned int Q = 512u; Q > 1u; Q >>= 1)
    if (x2 & Q) tt ^= (Q - 1u);
  x0 ^= tt; x1 ^= tt; x2 ^= tt;
  unsigned int code = 0;
  #pragma unroll
  for (int bb = 9; bb >= 0; --bb) {
    code = (code << 1) | ((x0 >> bb) & 1u);
    code = (code << 1) | ((x1 >> bb) & 1u);
    code = (code << 1) | ((x2 >> bb) & 1u);
  }
  return code;
}

// hilbert keys; minmax finalization folded in (each block reduces the 64x6 partials)
__global__ __launch_bounds__(256) void hilbert_kernel(const float* __restrict__ pos, const float* __restrict__ part,
                                                      unsigned long long* __restrict__ keys) {
  __shared__ float spmm[6];
  int tid = threadIdx.x;
  if (tid < 64) {
    const float* p = part + tid*6;
    float mn0=p[0], mn1=p[1], mn2=p[2], mx0=p[3], mx1=p[4], mx2=p[5];
    #pragma unroll
    for (int d = 1; d < 64; d <<= 1) {
      mn0=fminf(mn0,__shfl_xor(mn0,d,64));
      mn1=fminf(mn1,__shfl_xor(mn1,d,64));
      mn2=fminf(mn2,__shfl_xor(mn2,d,64));
      mx0=fmaxf(mx0,__shfl_xor(mx0,d,64));
      mx1=fmaxf(mx1,__shfl_xor(mx1,d,64));
      mx2=fmaxf(mx2,__shfl_xor(mx2,d,64));
    }
    if (tid == 0) {
      spmm[0]=mn0; spmm[1]=mn1; spmm[2]=mn2;
      spmm[3]=mx0; spmm[4]=mx1; spmm[5]=mx2;
    }
  }
  __syncthreads();
  int t = blockIdx.x*256 + tid;
  unsigned int g[3];
  #pragma unroll
  for (int d = 0; d < 3; ++d) {
    float v = (pos[t*3+d] - spmm[d]) / (spmm[3+d] - spmm[d] + 1e-6f) * 1023.0f;
    v = fminf(fmaxf(v, 0.0f), 1023.0f);
    g[d] = (unsigned int)(int)v;
  }
  unsigned int ca = hilbert3(g[0], g[1], g[2]);
  unsigned int cb = hilbert3(g[1], g[0], g[2]);
  keys[t]         = ((unsigned long long)ca << 14) | (unsigned long long)t;
  keys[L_TOK + t] = ((unsigned long long)cb << 14) | (unsigned long long)t;
}

// bitonic-sort each 512-key tile in LDS (64 tiles = 2 arrays x 32)
__global__ __launch_bounds__(256) void sort_tiles(const unsigned long long* __restrict__ keys,
                                                  unsigned long long* __restrict__ skeys) {
  __shared__ unsigned long long s[512];
  int b = blockIdx.x, tid = threadIdx.x;
  size_t base = (size_t)(b >> 5)*L_TOK + (size_t)(b & 31)*512;
  s[tid]       = keys[base + tid];
  s[tid + 256] = keys[base + tid + 256];
  for (unsigned int k = 2; k <= 512; k <<= 1) {
    for (unsigned int j = k >> 1; j > 0; j >>= 1) {
      __syncthreads();
      #pragma unroll
      for (int h = 0; h < 2; ++h) {
        int i = tid + 256*h;
        int ixj = i ^ (int)j;
        if (ixj > i) {
          unsigned long long a = s[i], c = s[ixj];
          bool up = ((i & (int)k) == 0);
          if (up ? (a > c) : (a < c)) { s[i] = c; s[ixj] = a; }
        }
      }
    }
  }
  __syncthreads();
  skeys[base + tid]       = s[tid];
  skeys[base + tid + 256] = s[tid + 256];
}

// rank via binary search in sorted tiles (ranks bit-identical to brute force)
__global__ __launch_bounds__(256) void rank_partial(const unsigned long long* __restrict__ keys,
                                                    const unsigned long long* __restrict__ skeys,
                                                    unsigned int* __restrict__ partial) {
  __shared__ unsigned long long tile[512];
  int arr = blockIdx.y, ks = blockIdx.z;
  const unsigned long long* k = keys + (size_t)arr * L_TOK;
  int qbase = blockIdx.x*1024 + threadIdx.x;
  unsigned long long q[4];
  #pragma unroll
  for (int i = 0; i < 4; ++i) q[i] = k[qbase + 256*i];
  const unsigned long long* src = skeys + (size_t)arr*L_TOK + ks*512;
  tile[threadIdx.x]       = src[threadIdx.x];
  tile[threadIdx.x + 256] = src[threadIdx.x + 256];
  __syncthreads();
  #pragma unroll
  for (int i = 0; i < 4; ++i) {
    unsigned int lo = 0;
    #pragma unroll
    for (unsigned int st = 256; st > 0; st >>= 1)
      if (tile[lo + st - 1] < q[i]) lo += st;
    lo += (tile[lo] < q[i]) ? 1u : 0u;
    partial[(size_t)(ks*2 + arr)*L_TOK + qbase + 256*i] = lo;
  }
}

__global__ __launch_bounds__(256) void rank_scatter(const unsigned long long* __restrict__ keys,
                                                    const unsigned int* __restrict__ partial,
                                                    unsigned int* __restrict__ ord,
                                                    unsigned int* __restrict__ inv) {
  int i = blockIdx.x*256 + threadIdx.x;
  int arr = i >> 14;
  int qi = i & (L_TOK - 1);
  unsigned int r = 0;
  #pragma unroll
  for (int ks = 0; ks < 32; ++ks) r += partial[(size_t)(ks*2 + arr)*L_TOK + qi];
  unsigned int tok = (unsigned int)(keys[i] & 0x3FFFu);
  ord[(size_t)arr*L_TOK + r] = tok;
  inv[(size_t)arr*L_TOK + tok] = r;
}

// ---------------- layernorm ----------------

__global__ __launch_bounds__(256) void ln_kernel(const float* __restrict__ in, float* __restrict__ out,
                                                 unsigned short* __restrict__ outbf,
                                                 const float* __restrict__ w, const float* __restrict__ b) {
  int row = blockIdx.x*4 + (threadIdx.x >> 6);
  int lane = threadIdx.x & 63;
  const float4 v = *(const float4*)(in + (size_t)row*DM + lane*4);
  float s = v.x + v.y + v.z + v.w;
  float mean = warp_sum(s) * (1.0f/DM);
  float4 xc = make_float4(v.x-mean, v.y-mean, v.z-mean, v.w-mean);
  float ss = xc.x*xc.x + xc.y*xc.y + xc.z*xc.z + xc.w*xc.w;
  ss = warp_sum(ss) * (1.0f/DM);
  float inv = rsqrtf(ss + EPSF);
  const float4 w4 = *(const float4*)(w + lane*4);
  const float4 b4 = *(const float4*)(b + lane*4);
  float4 o;
  o.x = xc.x*inv*w4.x + b4.x;
  o.y = xc.y*inv*w4.y + b4.y;
  o.z = xc.z*inv*w4.z + b4.z;
  o.w = xc.w*inv*w4.w + b4.w;
  *(float4*)(out + (size_t)row*DM + lane*4) = o;
  if (outbf) {
    ushort4 ob = make_ushort4(f2bf(o.x), f2bf(o.y), f2bf(o.z), f2bf(o.w));
    *(ushort4*)(outbf + (size_t)row*DM + lane*4) = ob;
  }
}

// fin-LN (in place on io) fused with next layer's pre-LN (writes qn/qnbf) in one read
__global__ __launch_bounds__(256) void lnfuse_kernel(float* __restrict__ io,
                                                     float* __restrict__ qn, unsigned short* __restrict__ qnbf,
                                                     const float* __restrict__ fw, const float* __restrict__ fb,
                                                     const float* __restrict__ pw, const float* __restrict__ pb) {
  int row = blockIdx.x*4 + (threadIdx.x >> 6);
  int lane = threadIdx.x & 63;
  const float4 v = *(const float4*)(io + (size_t)row*DM + lane*4);
  float s = v.x + v.y + v.z + v.w;
  float mean = warp_sum(s) * (1.0f/DM);
  float4 xc = make_float4(v.x-mean, v.y-mean, v.z-mean, v.w-mean);
  float ss = xc.x*xc.x + xc.y*xc.y + xc.z*xc.z + xc.w*xc.w;
  ss = warp_sum(ss) * (1.0f/DM);
  float inv = rsqrtf(ss + EPSF);
  const float4 w4 = *(const float4*)(fw + lane*4);
  const float4 b4 = *(const float4*)(fb + lane*4);
  float4 o;
  o.x = xc.x*inv*w4.x + b4.x;
  o.y = xc.y*inv*w4.y + b4.y;
  o.z = xc.z*inv*w4.z + b4.z;
  o.w = xc.w*inv*w4.w + b4.w;
  *(float4*)(io + (size_t)row*DM + lane*4) = o;
  if (qn) {
    float s2 = o.x + o.y + o.z + o.w;
    float mean2 = warp_sum(s2) * (1.0f/DM);
    float4 x2 = make_float4(o.x-mean2, o.y-mean2, o.z-mean2, o.w-mean2);
    float ss2 = x2.x*x2.x + x2.y*x2.y + x2.z*x2.z + x2.w*x2.w;
    ss2 = warp_sum(ss2) * (1.0f/DM);
    float inv2 = rsqrtf(ss2 + EPSF);
    const float4 pw4 = *(const float4*)(pw + lane*4);
    const float4 pb4 = *(const float4*)(pb + lane*4);
    float4 qv;
    qv.x = x2.x*inv2*pw4.x + pb4.x;
    qv.y = x2.y*inv2*pw4.y + pb4.y;
    qv.z = x2.z*inv2*pw4.z + pb4.z;
    qv.w = x2.w*inv2*pw4.w + pb4.w;
    *(float4*)(qn + (size_t)row*DM + lane*4) = qv;
    ushort4 qb = make_ushort4(f2bf(qv.x), f2bf(qv.y), f2bf(qv.z), f2bf(qv.w));
    *(ushort4*)(qnbf + (size_t)row*DM + lane*4) = qb;
  }
}

// ---------------- weight transpose+convert: both layers in one launch ----------------
// per layer: WtA 72 blocks (18 n-tiles x 4 k-tiles); WtO 32 blocks (4 n-tiles x 8 k-tiles)

__global__ __launch_bounds__(256) void tcvt_all(const float* __restrict__ Wi0, const float* __restrict__ Wo0,
                                                const float* __restrict__ nw0,
                                                const float* __restrict__ Wi1, const float* __restrict__ Wo1,
                                                const float* __restrict__ nw1,
                                                unsigned short* __restrict__ WtA, unsigned short* __restrict__ WtO) {
  __shared__ float lds[64*65];
  int b = blockIdx.x, tid = threadIdx.x;
  int lyr = (b >= 104) ? 1 : 0;
  b -= lyr*104;
  const float* Wi = lyr ? Wi1 : Wi0;
  const float* Wo = lyr ? Wo1 : Wo0;
  const float* nw = lyr ? nw1 : nw0;
  WtA += (size_t)lyr*1152*DM;
  WtO += (size_t)lyr*DM*DI;
  const float* src; int srcld, n0, k0t, dstld; unsigned short* dst; bool useNw;
  if (b < 72) {
    int nt = b >> 2, kt = b & 3;
    n0 = nt*64; k0t = kt*64;
    src = Wi; srcld = DP; dst = WtA; dstld = 256; useNw = false;
  } else {
    int j = b - 72;
    int nt = j >> 3, kt = j & 7;
    n0 = nt*64; k0t = kt*64;
    src = Wo; srcld = DM; dst = WtO; dstld = 512; useNw = true;
  }
  int nn = (tid & 15)*4, kk = tid >> 4;
  #pragma unroll
  for (int p = 0; p < 4; ++p) {
    int k = kk + p*16;
    float4 v = *(const float4*)(src + (size_t)(k0t + k)*srcld + n0 + nn);
    lds[k*65 + nn]   = v.x;
    lds[k*65 + nn+1] = v.y;
    lds[k*65 + nn+2] = v.z;
    lds[k*65 + nn+3] = v.w;
  }
  __syncthreads();
  int n = tid >> 2, kq = (tid & 3)*16;
  float nwv[16];
  if (useNw) {
    #pragma unroll
    for (int e = 0; e < 16; e += 4) {
      float4 t4 = *(const float4*)(nw + k0t + kq + e);
      nwv[e]=t4.x; nwv[e+1]=t4.y; nwv[e+2]=t4.z; nwv[e+3]=t4.w;
    }
  } else {
    #pragma unroll
    for (int e = 0; e < 16; ++e) nwv[e] = 1.0f;
  }
  short8 o0, o1;
  #pragma unroll
  for (int e = 0; e < 8; ++e) {
    o0[e] = (short)f2bf(lds[(kq+e)*65 + n] * nwv[e]);
    o1[e] = (short)f2bf(lds[(kq+8+e)*65 + n] * nwv[8+e]);
  }
  unsigned short* dp = dst + (size_t)(n0 + n)*dstld + k0t + kq;
  *(short8*)dp = o0;
  *(short8*)(dp + 8) = o1;
}

// ---------------- fused input GEMM: nat (gate+BC, 640 blocks) + x (Hilbert transposed, 1024 blocks) ----------------

__global__ __launch_bounds__(256) void gemm_in2(const unsigned short* __restrict__ Abf,
                                                const unsigned short* __restrict__ Wt,
                                                const unsigned int* __restrict__ ord,
                                                unsigned short* __restrict__ gate_nat,
                                                unsigned short* __restrict__ bcraw,
                                                unsigned short* __restrict__ xTg) {
  __shared__ unsigned short Alds[128*64];
  __shared__ unsigned short Blds[128*64];
  int tid = threadIdx.x, lane = tid & 63, w = tid >> 6;
  int bid = blockIdx.x;
  bool natp = bid < 640;
  int rb, cb, dir = 0, wcol0;
  if (natp) {
    int xcd = bid & 7, g = bid >> 3;
    rb = (xcd*16 + g/5)*128;
    cb = (g % 5)*128;
    wcol0 = cb;
  } else {
    int id = bid - 640;
    dir = id >> 9;
    int b = id & 511;
    int xcd = b & 7, g = b >> 3;
    rb = (xcd*16 + g/4)*128;
    cb = (g % 4)*128;
    wcol0 = DI + cb;
  }
  int wm = (w & 1)*64, wn = (w >> 1)*64;
  const unsigned int* ordp = ord + (size_t)dir*L_TOK;
  const unsigned short* pA[4]; const unsigned short* pB[4];
  unsigned short* dA[4]; unsigned short* dB[4];
  #pragma unroll
  for (int s = 0; s < 4; ++s) {
    int inst = w*4 + s;
    int r = inst*8 + (lane >> 3);
    int cA = (lane & 7) ^ (r & 7);
    int arow = natp ? (rb + r) : (int)ordp[rb + r];
    pA[s] = Abf + (size_t)arow*DM + cA*8;
    pB[s] = Wt + (size_t)(wcol0 + r)*DM + cA*8;
    dA[s] = &Alds[inst*512];
    dB[s] = &Blds[inst*512];
  }
  f32x4 zero = {0.f, 0.f, 0.f, 0.f};
  f32x4 acc[4][4];
  #pragma unroll
  for (int i = 0; i < 4; ++i)
    #pragma unroll
    for (int j = 0; j < 4; ++j) acc[i][j] = zero;
  int t = lane & 15, q = lane >> 4;
  for (int k0 = 0; k0 < DM; k0 += 64) {
    #pragma unroll
    for (int s = 0; s < 4; ++s) GLL16(pA[s] + k0, dA[s]);
    #pragma unroll
    for (int s = 0; s < 4; ++s) GLL16(pB[s] + k0, dB[s]);
    __syncthreads();
    #pragma unroll
    for (int ks = 0; ks < 2; ++ks) {
      short8 af[4], bfr[4];
      int cc = ks*4 + q;
      #pragma unroll
      for (int i = 0; i < 4; ++i) {
        int rr = wm + 16*i + t;
        af[i] = *(const short8*)&Alds[rr*64 + ((cc ^ (rr & 7))*8)];
      }
      #pragma unroll
      for (int j = 0; j < 4; ++j) {
        int rr = wn + 16*j + t;
        bfr[j] = *(const short8*)&Blds[rr*64 + ((cc ^ (rr & 7))*8)];
      }
      #pragma unroll
      for (int i = 0; i < 4; ++i)
        #pragma unroll
        for (int j = 0; j < 4; ++j)
          acc[i][j] = __builtin_amdgcn_mfma_f32_16x16x32_bf16(af[i], bfr[j], acc[i][j], 0, 0, 0);
    }
    __syncthreads();
  }
  if (natp) {
    unsigned short* dst; int ld;
    if (cb < DI) { dst = gate_nat + cb; ld = DI; }
    else         { dst = bcraw + (cb - DI); ld = 128; }
    #pragma unroll
    for (int i = 0; i < 4; ++i) {
      int rowb = rb + wm + 16*i + q*4;
      #pragma unroll
      for (int j = 0; j < 4; ++j) {
        int col = wn + 16*j + t;
        #pragma unroll
        for (int r = 0; r < 4; ++r)
          dst[(size_t)(rowb + r)*ld + col] = f2bf(acc[i][j][r]);
      }
    }
  } else {
    #pragma unroll
    for (int i = 0; i < 4; ++i) {
      int rowb = rb + wm + 16*i + q*4;
      #pragma unroll
      for (int j = 0; j < 4; ++j) {
        int col = wn + 16*j + t;
        ushort4 o = make_ushort4(f2bf(acc[i][j][0]), f2bf(acc[i][j][1]),
                                 f2bf(acc[i][j][2]), f2bf(acc[i][j][3]));
        *(ushort4*)(xTg + (size_t)(cb + col)*(2*L_TOK) + (size_t)dir*L_TOK + rowb) = o;
      }
    }
  }
}

// ---------------- gather-based out GEMM + in-kernel RMS (from A fragments) ----------------

__global__ __launch_bounds__(256) void gemm_out_gather(const unsigned short* __restrict__ ybuf,
                                                       const unsigned short* __restrict__ Wt,
                                                       const unsigned int* __restrict__ inv,
                                                       const float* __restrict__ shortcut,
                                                       float* __restrict__ out) {
  __shared__ unsigned short Alds[2*64*64];   // [dir][64 rows][64 k]
  __shared__ unsigned short Blds[128*64];
  __shared__ float sql[2][64];
  int tid = threadIdx.x, lane = tid & 63, w = tid >> 6;
  int bid = blockIdx.x;
  int xcd = bid & 7, g = bid >> 3;
  int rb = (xcd*32 + (g >> 1))*64;
  int cb = (g & 1)*128;
  int wm = (w & 1)*32, wn = (w >> 1)*64;
  bool rmsw = ((w >> 1) == 0);   // only wn==0 waves compute/publish row sums
  const unsigned short* pA0[2]; const unsigned short* pA1[2];
  unsigned short* dA0[2]; unsigned short* dA1[2];
  const unsigned short* pB[4]; unsigned short* dB[4];
  #pragma unroll
  for (int s = 0; s < 2; ++s) {
    int inst = w*2 + s;
    int r = inst*8 + (lane >> 3);
    int cA = (lane & 7) ^ (r & 7);
    int tok = rb + r;
    pA0[s] = ybuf + (size_t)inv[tok]*DI + cA*8;
    pA1[s] = ybuf + (size_t)L_TOK*DI + (size_t)inv[L_TOK + tok]*DI + cA*8;
    dA0[s] = &Alds[inst*512];
    dA1[s] = &Alds[4096 + inst*512];
  }
  #pragma unroll
  for (int s = 0; s < 4; ++s) {
    int inst = w*4 + s;
    int r = inst*8 + (lane >> 3);
    int cA = (lane & 7) ^ (r & 7);
    pB[s] = Wt + (size_t)(cb + r)*DI + cA*8;
    dB[s] = &Blds[inst*512];
  }
  f32x4 zero = {0.f, 0.f, 0.f, 0.f};
  f32x4 acc0[2][4], acc1[2][4];
  #pragma unroll
  for (int i = 0; i < 2; ++i)
    #pragma unroll
    for (int j = 0; j < 4; ++j) { acc0[i][j] = zero; acc1[i][j] = zero; }
  float sq0[2] = {0.f, 0.f}, sq1[2] = {0.f, 0.f};
  int t = lane & 15, q = lane >> 4;
  for (int k0 = 0; k0 < DI; k0 += 64) {
    #pragma unroll
    for (int s = 0; s < 2; ++s) { GLL16(pA0[s] + k0, dA0[s]); GLL16(pA1[s] + k0, dA1[s]); }
    #pragma unroll
    for (int s = 0; s < 4; ++s) GLL16(pB[s] + k0, dB[s]);
    __syncthreads();
    #pragma unroll
    for (int ks = 0; ks < 2; ++ks) {
      short8 af0[2], af1[2], bfr[4];
      int cc = ks*4 + q;
      #pragma unroll
      for (int i = 0; i < 2; ++i) {
        int rr = wm + 16*i + t;
        int off = rr*64 + ((cc ^ (rr & 7))*8);
        af0[i] = *(const short8*)&Alds[off];
        af1[i] = *(const short8*)&Alds[4096 + off];
      }
      // accumulate sum(y^2) from fragments (wn==0 waves only; hidden under MFMA pipe)
      if (rmsw) {
        #pragma unroll
        for (int i = 0; i < 2; ++i)
          #pragma unroll
          for (int e = 0; e < 8; ++e) {
            float a0 = bf2f((unsigned short)af0[i][e]);
            float a1 = bf2f((unsigned short)af1[i][e]);
            sq0[i] = fmaf(a0, a0, sq0[i]);
            sq1[i] = fmaf(a1, a1, sq1[i]);
          }
      }
      #pragma unroll
      for (int j = 0; j < 4; ++j) {
        int rr = wn + 16*j + t;
        bfr[j] = *(const short8*)&Blds[rr*64 + ((cc ^ (rr & 7))*8)];
      }
      #pragma unroll
      for (int i = 0; i < 2; ++i)
        #pragma unroll
        for (int j = 0; j < 4; ++j) {
          acc0[i][j] = __builtin_amdgcn_mfma_f32_16x16x32_bf16(af0[i], bfr[j], acc0[i][j], 0, 0, 0);
          acc1[i][j] = __builtin_amdgcn_mfma_f32_16x16x32_bf16(af1[i], bfr[j], acc1[i][j], 0, 0, 0);
        }
    }
    __syncthreads();
  }
  // reduce sq over the 4 lanes (q) sharing each A row; publish per-row sums via LDS
  if (rmsw) {
    #pragma unroll
    for (int i = 0; i < 2; ++i) {
      float s0 = sq0[i];
      s0 += __shfl_xor(s0, 16, 64);
      s0 += __shfl_xor(s0, 32, 64);
      float s1 = sq1[i];
      s1 += __shfl_xor(s1, 16, 64);
      s1 += __shfl_xor(s1, 32, 64);
      if (q == 0) { sql[0][wm + 16*i + t] = s0; sql[1][wm + 16*i + t] = s1; }
    }
  }
  __syncthreads();
  #pragma unroll
  for (int i = 0; i < 2; ++i) {
    #pragma unroll
    for (int r = 0; r < 4; ++r) {
      int rl = wm + 16*i + q*4 + r;
      int row = rb + rl;
      float ir0 = rsqrtf(sql[0][rl]*(1.0f/DI) + EPSF);
      float ir1 = rsqrtf(sql[1][rl]*(1.0f/DI) + EPSF);
      const float* sp = shortcut + (size_t)row*DM + cb;
      float* op = out + (size_t)row*DM + cb;
      #pragma unroll
      for (int j = 0; j < 4; ++j) {
        int col = wn + 16*j + t;
        op[col] = sp[col] + 0.5f*(ir0*acc0[i][j][r] + ir1*acc1[i][j][r]);
      }
    }
  }
}

// ---------------- fused dt GEMV (blocks 0..511) + convBC swizzled-tile (blocks 512..1023) ----------------

__global__ __launch_bounds__(256) void dtconv(const float* __restrict__ qn, const float* __restrict__ W,
                                              const float* __restrict__ dt_bias, float* __restrict__ dtb,
                                              const unsigned short* __restrict__ bcraw,
                                              const float* __restrict__ cw, const float* __restrict__ cbias,
                                              const unsigned int* __restrict__ ord,
                                              unsigned short* __restrict__ bcswz,
                                              unsigned short* __restrict__ bcswzA) {
  __shared__ unsigned short smem[131*64];
  int tid = threadIdx.x;
  int bx = blockIdx.x;
  if (bx < 512) {
    float* Wl = (float*)smem;
    {
      const float* wp = W + (size_t)tid*DP + (DI + CD);
      float4 wa = *(const float4*)wp;
      float4 wb = *(const float4*)(wp + 4);
      int off = tid*8 + (tid >> 5)*4;
      *(float4*)&Wl[off]     = wa;
      *(float4*)&Wl[off + 4] = wb;
    }
    __syncthreads();
    int lane = tid & 63, w = tid >> 6;
    int r = bx*32 + w*8 + (lane >> 3);
    int kg = lane & 7;
    const float* qp = qn + (size_t)r*DM + kg*32;
    float acc[8] = {};
    #pragma unroll
    for (int i = 0; i < 8; ++i) {
      float4 q4 = *(const float4*)(qp + i*4);
      float qv[4] = {q4.x, q4.y, q4.z, q4.w};
      #pragma unroll
      for (int e = 0; e < 4; ++e) {
        int k = kg*32 + i*4 + e;
        int off = k*8 + kg*4;
        float4 wa = *(const float4*)&Wl[off];
        float4 wb = *(const float4*)&Wl[off + 4];
        acc[0] = fmaf(qv[e], wa.x, acc[0]);
        acc[1] = fmaf(qv[e], wa.y, acc[1]);
        acc[2] = fmaf(qv[e], wa.z, acc[2]);
        acc[3] = fmaf(qv[e], wa.w, acc[3]);
        acc[4] = fmaf(qv[e], wb.x, acc[4]);
        acc[5] = fmaf(qv[e], wb.y, acc[5]);
        acc[6] = fmaf(qv[e], wb.z, acc[6]);
        acc[7] = fmaf(qv[e], wb.w, acc[7]);
      }
    }
    #pragma unroll
    for (int h = 0; h < 8; ++h) {
      acc[h] += __shfl_xor(acc[h], 8, 64);
      acc[h] += __shfl_xor(acc[h], 16, 64);
      acc[h] += __shfl_xor(acc[h], 32, 64);
    }
    float v = 0.f;
    #pragma unroll
    for (int h = 0; h < 8; ++h) if (kg == h) v = acc[h];
    v += dt_bias[kg];
    float sp = (v > 0.0f) ? (v + log1pf(__expf(-v))) : log1pf(__expf(v));
    dtb[(size_t)r*NH + kg] = sp;
  } else {
    int cid = bx - 512;
    int half = cid & 1, ty = (cid >> 1) & 127, dir = cid >> 8;
    unsigned short* tile = smem;
    const unsigned int* ordp = ord + (size_t)dir*L_TOK;
    int ch0 = DI + half*64;
    int co0 = half*64;
    int t0 = ty*128;
    for (int cc = tid; cc < 131*8; cc += 256) {
      int r = cc >> 3, cgc = cc & 7;
      int t = t0 - 3 + r;
      short8 v = {0,0,0,0,0,0,0,0};
      if (t >= 0) v = *(const short8*)(bcraw + (size_t)ordp[t]*128 + co0 + cgc*8);
      *(short8*)&tile[r*64 + ((cgc ^ (r & 7))*8)] = v;
    }
    int cg = tid & 7, tp = tid >> 3;
    int ch = ch0 + cg*8;
    float wv[8][4];
    float bias[8];
    #pragma unroll
    for (int e = 0; e < 8; ++e) {
      float4 c4 = *(const float4*)(cw + (ch + e)*4);
      wv[e][0] = c4.x; wv[e][1] = c4.y; wv[e][2] = c4.z; wv[e][3] = c4.w;
    }
    {
      float4 b0 = *(const float4*)(cbias + ch);
      float4 b1 = *(const float4*)(cbias + ch + 4);
      bias[0]=b0.x; bias[1]=b0.y; bias[2]=b0.z; bias[3]=b0.w;
      bias[4]=b1.x; bias[5]=b1.y; bias[6]=b1.z; bias[7]=b1.w;
    }
    __syncthreads();
    #pragma unroll
    for (int tk = 0; tk < 4; ++tk) {
      int rel = tp + 32*tk;
      float acc[8];
      #pragma unroll
      for (int e = 0; e < 8; ++e) acc[e] = bias[e];
      #pragma unroll
      for (int k = 0; k < 4; ++k) {
        int r = rel + k;
        short8 v = *(const short8*)&tile[r*64 + ((cg ^ (r & 7))*8)];
        #pragma unroll
        for (int e = 0; e < 8; ++e)
          acc[e] = fmaf(wv[e][k], bf2f((unsigned short)v[e]), acc[e]);
      }
      short8 o;
      #pragma unroll
      for (int e = 0; e < 8; ++e) o[e] = (short)f2bf(fsilu(acc[e]));
      int T = t0 + rel;
      int chn = T >> 6, tl = T & 63;
      unsigned short* tb = bcswz + ((size_t)((dir*NC + chn)*2 + half))*4096;
      *(short8*)(tb + tl*64 + ((cg ^ (tl & 7))*8)) = o;
      if (half == 0) {
        unsigned short* ta = bcswzA + ((size_t)(dir*NC + chn))*4096;
        #pragma unroll
        for (int e = 0; e < 8; ++e) {
          int s5 = cg*8 + e;
          ta[s5*64 + (((tl >> 3) ^ (s5 & 7))*8) + (tl & 7)] = (unsigned short)o[e];
        }
      }
    }
  }
}

// ---------------- chunked scan (MFMA, bf16 S) ----------------
// grid = (NH, NC, 2): 8 heads of a chunk are consecutive blocks -> same XCD -> B/C tile L2 reuse.

__global__ __launch_bounds__(256) void phaseA_mfma(const unsigned short* __restrict__ xTg,
                                                   const unsigned short* __restrict__ bcswzA,
                                                   const float* __restrict__ cw, const float* __restrict__ cbias,
                                                   const float* __restrict__ dtb, const float* __restrict__ A_log,
                                                   const unsigned int* __restrict__ ord,
                                                   unsigned short* __restrict__ S, float* __restrict__ P,
                                                   unsigned short* __restrict__ xsT) {
  int h = blockIdx.x, c = blockIdx.y, dir = blockIdx.z, tid = threadIdx.x;
  int lane = tid & 63, w = tid >> 6;
  int hh = dir*NH + h;
  __shared__ unsigned short xT[64*64];
  __shared__ unsigned short Bt[64*64];
  __shared__ float wgt[64];
  int c0 = c*CHUNK;
  float Ah = -expf(A_log[h]);
  const unsigned short* bA = bcswzA + ((size_t)(dir*NC + c))*4096;
  #pragma unroll
  for (int s = 0; s < 2; ++s) {
    int inst = w*2 + s;
    GLL16(bA + (size_t)inst*512 + lane*8, &Bt[inst*512]);
  }
  // wave0: parallel suffix scan of lg = dt*A (dtb gathered via ord)
  if (tid < 64) {
    unsigned int tok = ord[(size_t)dir*L_TOK + c0 + tid];
    float dtv = dtb[(size_t)tok*NH + h];
    float v = dtv*Ah;
    float s = v;
    #pragma unroll
    for (int d = 1; d < 64; d <<= 1) {
      float u = __shfl_down(s, d, 64);
      s += (tid + d < 64) ? u : 0.f;
    }
    wgt[tid] = dtv*fexp(s - v);
    if (tid == 0) P[hh*NC + c] = fexp(s);
  }
  __syncthreads();
  unsigned short* xpg = xsT + ((size_t)(hh*NC + c))*4096;
  #pragma unroll
  for (int i = 0; i < 2; ++i) {
    int q = tid + 256*i;
    int p = q >> 3, tg = q & 7;
    int sw8 = (tg ^ (p & 7))*8;
    const unsigned short* xrow = xTg + (size_t)(h*HD + p)*(2*L_TOK) + (size_t)dir*L_TOK;
    int tb = c0 + tg*8;
    short8 cur = *(const short8*)(xrow + tb);
    int sh5 = __shfl_up((int)(unsigned short)cur[5], 1, 64);
    int sh6 = __shfl_up((int)(unsigned short)cur[6], 1, 64);
    int sh7 = __shfl_up((int)(unsigned short)cur[7], 1, 64);
    unsigned short b5 = 0, b6 = 0, b7 = 0;
    if (tg == 0) {
      if (tb >= 8) {
        ushort4 pv = *(const ushort4*)(xrow + tb - 4);
        b5 = pv.y; b6 = pv.z; b7 = pv.w;
      }
    } else {
      b5 = (unsigned short)sh5; b6 = (unsigned short)sh6; b7 = (unsigned short)sh7;
    }
    float4 w4 = *(const float4*)(cw + (size_t)(h*HD + p)*4);
    float bb = cbias[h*HD + p];
    float xv[11];
    xv[0] = bf2f(b5);
    xv[1] = bf2f(b6);
    xv[2] = bf2f(b7);
    #pragma unroll
    for (int k = 0; k < 8; ++k) xv[3+k] = bf2f((unsigned short)cur[k]);
    short8 raw, wtd;
    #pragma unroll
    for (int k = 0; k < 8; ++k) {
      float a = bb + w4.x*xv[k] + w4.y*xv[k+1] + w4.z*xv[k+2] + w4.w*xv[k+3];
      unsigned short rbf = f2bf(fsilu(a));
      raw[k] = (short)rbf;
      wtd[k] = (short)f2bf(bf2f(rbf)*wgt[tg*8 + k]);
    }
    *(short8*)(xpg + p*64 + sw8) = raw;
    *(short8*)&xT[p*64 + sw8] = wtd;
  }
  __syncthreads();
  int t16 = lane & 15, q4 = lane >> 4;
  f32x4 zero = {0.f,0.f,0.f,0.f};
  f32x4 acc[4];
  #pragma unroll
  for (int j = 0; j < 4; ++j) acc[j] = zero;
  #pragma unroll
  for (int ks = 0; ks < 2; ++ks) {
    int rowA = 16*w + t16;
    short8 a = *(const short8*)&xT[rowA*64 + (((ks*4 + q4) ^ (rowA & 7))*8)];
    #pragma unroll
    for (int j = 0; j < 4; ++j) {
      int rowB = 16*j + t16;
      short8 b = *(const short8*)&Bt[rowB*64 + (((ks*4 + q4) ^ (rowB & 7))*8)];
      acc[j] = __builtin_amdgcn_mfma_f32_16x16x32_bf16(a, b, acc[j], 0, 0, 0);
    }
  }
  unsigned short* Sp = S + ((size_t)(hh*NC + c))*4096;
  #pragma unroll
  for (int j = 0; j < 4; ++j)
    #pragma unroll
    for (int r = 0; r < 4; ++r) {
      int row = 16*w + q4*4 + r;
      int cg2 = 2*j + (t16 >> 3);
      Sp[(size_t)row*64 + (((cg2 ^ (row & 7)) << 3) | (t16 & 7))] = f2bf(acc[j][r]);
    }
}

// ---- phaseB: single-pass in-place exclusive scan over chunks (layout-agnostic) ----

__global__ __launch_bounds__(128) void phaseB_scan(unsigned short* __restrict__ S, const float* __restrict__ P) {
  __shared__ float Pl[NC];
  int b = blockIdx.x;
  int hh = b >> 4;
  int e2 = (b & 15)*128 + threadIdx.x;
  for (int i = threadIdx.x; i < NC; i += 128) Pl[i] = P[hh*NC + i];
  __syncthreads();
  unsigned int* base = (unsigned int*)(S + ((size_t)hh*NC)*4096) + e2;
  float hx = 0.f, hy = 0.f;
  #pragma unroll 1
  for (int k0 = 0; k0 < NC; k0 += 16) {
    unsigned int v[16];
    #pragma unroll
    for (int u = 0; u < 16; ++u) v[u] = base[(size_t)(k0+u)*2048];
    #pragma unroll
    for (int u = 0; u < 16; ++u) {
      float p = Pl[k0+u];
      unsigned int old = v[u];
      base[(size_t)(k0+u)*2048] = (unsigned int)f2bf(hx) | ((unsigned int)f2bf(hy) << 16);
      hx = p*hx + bf2f((unsigned short)(old & 0xffffu));
      hy = p*hy + bf2f((unsigned short)(old >> 16));
    }
  }
}

// phaseC: grid (NH, NC, 2); all staging via GLL16 from pre-swizzled tiles; Gl aliased onto Cl;
// epilogue: accY -> f32 LDS overlay -> coalesced gate-mul + y store (RMS moved to gemm_out).
__global__ __launch_bounds__(256) void phaseC_mfma(const unsigned short* __restrict__ bcswz,
                                                   const unsigned short* __restrict__ xsT,
                                                   const unsigned short* __restrict__ gate_nat,
                                                   const float* __restrict__ dtb, const float* __restrict__ A_log,
                                                   const float* __restrict__ Dp,
                                                   const unsigned int* __restrict__ ord,
                                                   const unsigned short* __restrict__ S,
                                                   unsigned short* __restrict__ ybuf) {
  int h = blockIdx.x, c = blockIdx.y, dir = blockIdx.z, tid = threadIdx.x;
  int lane = tid & 63, w = tid >> 6;
  int hh = dir*NH + h;
  unsigned short* y = ybuf + (size_t)dir*L_TOK*DI;
  __shared__ __align__(16) unsigned short smemT[4*4096];
  __shared__ float dts[64], pl[64], pe[64];
  unsigned short* Cl  = smemT;            // reused as Gl after stage-1 (wave-private rows)
  unsigned short* Bl  = smemT + 4096;
  unsigned short* h0l = smemT + 8192;
  unsigned short* xT  = smemT + 12288;
  float* fT = (float*)(smemT + 8192);     // 16KB f32 overlay on h0l+xT (dead after MFMAs)
  int c0 = c*CHUNK;
  float Ah = -expf(A_log[h]);
  float Dh = Dp[h];
  const unsigned short* Sp = S + ((size_t)(hh*NC + c))*4096;
  const unsigned short* xp = xsT + ((size_t)(hh*NC + c))*4096;
  const unsigned short* Bg = bcswz + ((size_t)((dir*NC + c)*2 + 0))*4096;
  const unsigned short* Cg = bcswz + ((size_t)((dir*NC + c)*2 + 1))*4096;
  #pragma unroll
  for (int s = 0; s < 2; ++s) {
    int inst = w*2 + s;
    GLL16(Sp + (size_t)inst*512 + lane*8, &h0l[inst*512]);
    GLL16(xp + (size_t)inst*512 + lane*8, &xT[inst*512]);
    GLL16(Bg + (size_t)inst*512 + lane*8, &Bl[inst*512]);
    GLL16(Cg + (size_t)inst*512 + lane*8, &Cl[inst*512]);
  }
  // hoisted epilogue loads (independent): token + gate row-segment for this thread's row
  int erow = tid >> 2;
  int ech0 = (tid & 3) * 16;
  unsigned int etok = ord[(size_t)dir*L_TOK + c0 + erow];
  const unsigned short* gp = gate_nat + (size_t)etok*DI + h*HD + ech0;
  short8 g0 = *(const short8*)gp;
  short8 g1 = *(const short8*)(gp + 8);
  // wave0: parallel inclusive prefix scan of lg = dt*A (dtb gathered via ord)
  if (tid < 64) {
    unsigned int tok = ord[(size_t)dir*L_TOK + c0 + tid];
    float dtv = dtb[(size_t)tok*NH + h];
    dts[tid] = dtv;
    float v = dtv*Ah;
    float s = v;
    #pragma unroll
    for (int d = 1; d < 64; d <<= 1) {
      float u = __shfl_up(s, d, 64);
      s += (tid >= d) ? u : 0.f;
    }
    pl[tid] = s;
    pe[tid] = fexp(s);
  }
  __syncthreads();
  int t16 = lane & 15, q4 = lane >> 4;
  int t0 = 16*w;
  f32x4 zero = {0.f,0.f,0.f,0.f};
  f32x4 accG[4], accY[4];
  #pragma unroll
  for (int j = 0; j < 4; ++j) { accG[j] = zero; accY[j] = zero; }
  #pragma unroll
  for (int ks = 0; ks < 2; ++ks) {
    int rowA = t0 + t16;
    short8 a = *(const short8*)&Cl[rowA*64 + (((ks*4 + q4) ^ (rowA & 7))*8)];
    #pragma unroll
    for (int j = 0; j < 4; ++j) {
      int rowB = 16*j + t16;
      int off = rowB*64 + (((ks*4 + q4) ^ (rowB & 7))*8);
      accG[j] = __builtin_amdgcn_mfma_f32_16x16x32_bf16(a, *(const short8*)&Bl[off], accG[j], 0, 0, 0);
      accY[j] = __builtin_amdgcn_mfma_f32_16x16x32_bf16(a, *(const short8*)&h0l[off], accY[j], 0, 0, 0);
    }
  }
  // Gl (aliased onto Cl): wave w only touches rows [16w,16w+16), which it alone read as A-operand
  #pragma unroll
  for (int j = 0; j < 4; ++j) {
    #pragma unroll
    for (int r = 0; r < 4; ++r) {
      int t = t0 + q4*4 + r;
      int s = 16*j + t16;
      float v = 0.f;
      if (s <= t) {
        v = accG[j][r] * dts[s] * fexp(pl[t] - pl[s]);
        if (s == t) v += Dh;
      }
      Cl[t*64 + (((s >> 3) ^ (t & 7))*8 + (s & 7))] = f2bf(v);
    }
  }
  #pragma unroll
  for (int j = 0; j < 4; ++j)
    #pragma unroll
    for (int r = 0; r < 4; ++r)
      accY[j][r] *= pe[t0 + q4*4 + r];
  #pragma unroll
  for (int ks = 0; ks < 2; ++ks) {
    int rowA = t0 + t16;
    short8 a = *(const short8*)&Cl[rowA*64 + (((ks*4 + q4) ^ (rowA & 7))*8)];
    #pragma unroll
    for (int j = 0; j < 4; ++j) {
      int rowB = 16*j + t16;
      short8 b = *(const short8*)&xT[rowB*64 + (((ks*4 + q4) ^ (rowB & 7))*8)];
      accY[j] = __builtin_amdgcn_mfma_f32_16x16x32_bf16(a, b, accY[j], 0, 0, 0);
    }
  }
  __syncthreads();   // all waves done reading h0l/xT
  // write accY into f32 overlay; swizzle: col ^= (q4<<4)
  #pragma unroll
  for (int j = 0; j < 4; ++j)
    #pragma unroll
    for (int r = 0; r < 4; ++r) {
      int t = t0 + q4*4 + r;
      int p = 16*j + t16;
      fT[t*64 + (p ^ (q4 << 4))] = accY[j][r];
    }
  __syncthreads();
  // coalesced epilogue: thread owns 16 contiguous channels of one row
  {
    int swz = ((erow >> 2) & 3) << 4;
    const float* fr = &fT[erow*64 + (ech0 ^ swz)];
    float4 a0 = *(const float4*)(fr);
    float4 a1 = *(const float4*)(fr + 4);
    float4 a2 = *(const float4*)(fr + 8);
    float4 a3 = *(const float4*)(fr + 12);
    float fv[16] = {a0.x,a0.y,a0.z,a0.w, a1.x,a1.y,a1.z,a1.w,
                    a2.x,a2.y,a2.z,a2.w, a3.x,a3.y,a3.z,a3.w};
    short8 o0, o1;
    #pragma unroll
    for (int e = 0; e < 8; ++e) {
      float v0 = fv[e]   * fsilu(bf2f((unsigned short)g0[e]));
      float v1 = fv[8+e] * fsilu(bf2f((unsigned short)g1[e]));
      o0[e] = (short)f2bf(v0);
      o1[e] = (short)f2bf(v1);
    }
    unsigned short* yp = y + (size_t)(c0 + erow)*DI + h*HD + ech0;
    *(short8*)yp = o0;
    *(short8*)(yp + 8) = o1;
  }
}

__global__ void fill_debug(float* out, float v) {
  int i = blockIdx.x*256 + threadIdx.x;
  if (i < L_TOK*DM) out[i] = v;
}

// ---------------- host ----------------

extern "C" void kernel_launch(void* const* d_in, const int* in_sizes, int n_in,
                              void* d_out, int out_size, void* d_ws, size_t ws_size,
                              hipStream_t stream) {
  const float* query = (const float*)d_in[0];
  const float* qpos  = (const float*)d_in[1];
  const float* pre_w = (const float*)d_in[2];
  const float* pre_b = (const float*)d_in[3];
  const float* fin_w = (const float*)d_in[4];
  const float* fin_b = (const float*)d_in[5];
  float* out = (float*)d_out;

  char* ws = (char*)d_ws;
  size_t off = 0;
  auto alloc = [&](size_t bytes) -> void* {
    void* p = ws + off;
    off += (bytes + 255) & ~(size_t)255;
    return p;
  };
  unsigned long long* keys = (unsigned long long*)alloc((size_t)2*L_TOK*8);
  unsigned long long* skeys = (unsigned long long*)alloc((size_t)2*L_TOK*8);
  unsigned int* ord = (unsigned int*)alloc((size_t)2*L_TOK*4);
  unsigned int* inv = (unsigned int*)alloc((size_t)2*L_TOK*4);
  unsigned int* rpart = (unsigned int*)alloc((size_t)32*2*L_TOK*4);
  float* mmpart = (float*)alloc((size_t)64*6*4);
  float* qn   = (float*)alloc((size_t)L_TOK*DM*4);
  unsigned short* qnbf = (unsigned short*)alloc((size_t)L_TOK*DM*2);
  unsigned short* gate_nat = (unsigned short*)alloc((size_t)L_TOK*DI*2);   // natural-order gate
  unsigned short* xTg    = (unsigned short*)alloc((size_t)512*2*L_TOK*2);  // raw x, transposed [ch][dir*L+t]
  unsigned short* bcraw  = (unsigned short*)alloc((size_t)L_TOK*128*2);    // raw B/C, natural token-major
  unsigned short* bcswz  = (unsigned short*)alloc((size_t)2*NC*2*4096*2);  // conv'd B/C, phaseC-layout tiles
  unsigned short* bcswzA = (unsigned short*)alloc((size_t)2*NC*4096*2);    // conv'd B, phaseA-layout tiles
  unsigned short* ybuf   = (unsigned short*)alloc((size_t)2*L_TOK*DI*2);   // gated (unnormalized) y
  float* dtb  = (float*)alloc((size_t)L_TOK*NH*4);                         // natural-order dt
  unsigned short* Sbuf = (unsigned short*)alloc((size_t)2*NH*NC*4096*2);
  unsigned short* xsT  = (unsigned short*)alloc((size_t)2*NH*NC*4096*2);   // silu(conv(x)) pre-swizzled tiles
  float* Pbuf = (float*)alloc((size_t)2*NH*NC*4);
  unsigned short* WtA = (unsigned short*)alloc((size_t)2*1152*DM*2);
  unsigned short* WtO = (unsigned short*)alloc((size_t)2*DM*DI*2);
  if (off > ws_size) {
    fill_debug<<<(L_TOK*DM + 255)/256, 256, 0, stream>>>(out, (float)(ws_size >> 20));
    return;
  }

  minmax_part<<<64, 256, 0, stream>>>(qpos, mmpart);
  hilbert_kernel<<<L_TOK/256, 256, 0, stream>>>(qpos, mmpart, keys);
  sort_tiles<<<64, 256, 0, stream>>>(keys, skeys);
  rank_partial<<<dim3(16, 2, 32), 256, 0, stream>>>(keys, skeys, rpart);
  rank_scatter<<<(2*L_TOK)/256, 256, 0, stream>>>(keys, rpart, ord, inv);
  tcvt_all<<<208, 256, 0, stream>>>((const float*)d_in[6], (const float*)d_in[13], (const float*)d_in[12],
                                    (const float*)d_in[14], (const float*)d_in[21], (const float*)d_in[20],
                                    WtA, WtO);

  for (int l = 0; l < 2; ++l) {
    int base = 6 + 8*l;
    const float* in_proj  = (const float*)d_in[base+0];
    const float* conv_w   = (const float*)d_in[base+1];
    const float* conv_b   = (const float*)d_in[base+2];
    const float* dt_bias  = (const float*)d_in[base+3];
    const float* A_log    = (const float*)d_in[base+4];
    const float* Dp       = (const float*)d_in[base+5];
    const unsigned short* WtAl = WtA + (size_t)l*1152*DM;
    const unsigned short* WtOl = WtO + (size_t)l*DM*DI;

    if (l == 0)
      ln_kernel<<<L_TOK/4, 256, 0, stream>>>(query, qn, qnbf, pre_w, pre_b);
    gemm_in2<<<1664, 256, 0, stream>>>(qnbf, WtAl, ord, gate_nat, bcraw, xTg);
    dtconv<<<1024, 256, 0, stream>>>(qn, in_proj, dt_bias, dtb,
                                     bcraw, conv_w, conv_b, ord, bcswz, bcswzA);
    phaseA_mfma<<<dim3(NH, NC, 2), 256, 0, stream>>>(xTg, bcswzA, conv_w, conv_b, dtb, A_log, ord, Sbuf, Pbuf, xsT);
    phaseB_scan<<<256, 128, 0, stream>>>(Sbuf, Pbuf);
    phaseC_mfma<<<dim3(NH, NC, 2), 256, 0, stream>>>(bcswz, xsT, gate_nat, dtb, A_log, Dp, ord, Sbuf, ybuf);
    gemm_out_gather<<<512, 256, 0, stream>>>(ybuf, WtOl, inv,
                                             l ? (const float*)out : query, out);
    if (l == 0)
      lnfuse_kernel<<<L_TOK/4, 256, 0, stream>>>(out, qn, qnbf, fin_w, fin_b, pre_w, pre_b);
    else
      lnfuse_kernel<<<L_TOK/4, 256, 0, stream>>>(out, nullptr, nullptr, fin_w, fin_b, pre_w, pre_b);
  }
}

// Round 11
// 448.237 us; speedup vs baseline: 1.0094x; 1.0094x over previous
//
#include <hip/hip_runtime.h>
#include <stdint.h>

#define L_TOK 16384
#define DM 256
#define DI 512
#define DS 64
#define NH 8
#define HD 64
#define CD 640
#define DP 1160
#define CHUNK 64
#define NC 256
#define EPSF 1e-5f

typedef __attribute__((ext_vector_type(8))) short short8;
typedef __attribute__((ext_vector_type(4))) float f32x4;

#define GLL16(gp, lp) __builtin_amdgcn_global_load_lds((const __attribute__((address_space(1))) void*)(gp), (__attribute__((address_space(3))) void*)(lp), 16, 0, 0)

__device__ __forceinline__ float warp_sum(float v) {
  v += __shfl_xor(v, 1, 64);
  v += __shfl_xor(v, 2, 64);
  v += __shfl_xor(v, 4, 64);
  v += __shfl_xor(v, 8, 64);
  v += __shfl_xor(v, 16, 64);
  v += __shfl_xor(v, 32, 64);
  return v;
}

__device__ __forceinline__ float fexp(float x) { return __expf(x); }
__device__ __forceinline__ float fsilu(float x) { return x * __builtin_amdgcn_rcpf(1.0f + __expf(-x)); }

__device__ __forceinline__ unsigned short f2bf(float f) {
  unsigned int u = __float_as_uint(f);
  unsigned int r = (u + 0x7FFFu + ((u >> 16) & 1u)) >> 16;
  return (unsigned short)r;
}
__device__ __forceinline__ float bf2f(unsigned short u) {
  return __uint_as_float(((unsigned int)u) << 16);
}

// ---------------- serialization ----------------

__global__ __launch_bounds__(256) void minmax_part(const float* __restrict__ pos, float* __restrict__ part) {
  __shared__ float sm[6][4];
  int tid = threadIdx.x;
  int t = blockIdx.x*256 + tid;
  float a = pos[t*3+0], b = pos[t*3+1], c = pos[t*3+2];
  float mn0=a, mn1=b, mn2=c, mx0=a, mx1=b, mx2=c;
  #pragma unroll
  for (int d = 1; d < 64; d <<= 1) {
    mn0=fminf(mn0,__shfl_xor(mn0,d,64));
    mn1=fminf(mn1,__shfl_xor(mn1,d,64));
    mn2=fminf(mn2,__shfl_xor(mn2,d,64));
    mx0=fmaxf(mx0,__shfl_xor(mx0,d,64));
    mx1=fmaxf(mx1,__shfl_xor(mx1,d,64));
    mx2=fmaxf(mx2,__shfl_xor(mx2,d,64));
  }
  if ((tid & 63) == 0) {
    int w = tid >> 6;
    sm[0][w]=mn0; sm[1][w]=mn1; sm[2][w]=mn2;
    sm[3][w]=mx0; sm[4][w]=mx1; sm[5][w]=mx2;
  }
  __syncthreads();
  if (tid < 6) {
    float r = sm[tid][0];
    if (tid < 3) { r=fminf(r,sm[tid][1]); r=fminf(r,sm[tid][2]); r=fminf(r,sm[tid][3]); }
    else         { r=fmaxf(r,sm[tid][1]); r=fmaxf(r,sm[tid][2]); r=fmaxf(r,sm[tid][3]); }
    part[blockIdx.x*6 + tid] = r;
  }
}

__device__ unsigned int hilbert3(unsigned int a, unsigned int b, unsigned int c) {
  unsigned int x0 = a, x1 = b, x2 = c;
  for (unsigned int Q = 512u; Q > 1u; Q >>= 1) {
    unsigned int P = Q - 1u;
    { if (x0 & Q) x0 ^= P; }
    {
      unsigned int t = (x0 ^ x1) & P;
      if (x1 & Q) { x0 ^= P; }
      else { x0 ^= t; x1 ^= t; }
    }
    {
      unsigned int t = (x0 ^ x2) & P;
      if (x2 & Q) { x0 ^= P; }
      else { x0 ^= t; x2 ^= t; }
    }
  }
  x1 ^= x0; x2 ^= x1;
  unsigned int tt = 0;
  for (unsigned int Q = 512u; Q > 1u; Q >>= 1)
    if (x2 & Q) tt ^= (Q - 1u);
  x0 ^= tt; x1 ^= tt; x2 ^= tt;
  unsigned int code = 0;
  #pragma unroll
  for (int bb = 9; bb >= 0; --bb) {
    code = (code << 1) | ((x0 >> bb) & 1u);
    code = (code << 1) | ((x1 >> bb) & 1u);
    code = (code << 1) | ((x2 >> bb) & 1u);
  }
  return code;
}

// hilbert keys; minmax finalization folded in (each block reduces the 64x6 partials)
__global__ __launch_bounds__(256) void hilbert_kernel(const float* __restrict__ pos, const float* __restrict__ part,
                                                      unsigned long long* __restrict__ keys) {
  __shared__ float spmm[6];
  int tid = threadIdx.x;
  if (tid < 64) {
    const float* p = part + tid*6;
    float mn0=p[0], mn1=p[1], mn2=p[2], mx0=p[3], mx1=p[4], mx2=p[5];
    #pragma unroll
    for (int d = 1; d < 64; d <<= 1) {
      mn0=fminf(mn0,__shfl_xor(mn0,d,64));
      mn1=fminf(mn1,__shfl_xor(mn1,d,64));
      mn2=fminf(mn2,__shfl_xor(mn2,d,64));
      mx0=fmaxf(mx0,__shfl_xor(mx0,d,64));
      mx1=fmaxf(mx1,__shfl_xor(mx1,d,64));
      mx2=fmaxf(mx2,__shfl_xor(mx2,d,64));
    }
    if (tid == 0) {
      spmm[0]=mn0; spmm[1]=mn1; spmm[2]=mn2;
      spmm[3]=mx0; spmm[4]=mx1; spmm[5]=mx2;
    }
  }
  __syncthreads();
  int t = blockIdx.x*256 + tid;
  unsigned int g[3];
  #pragma unroll
  for (int d = 0; d < 3; ++d) {
    float v = (pos[t*3+d] - spmm[d]) / (spmm[3+d] - spmm[d] + 1e-6f) * 1023.0f;
    v = fminf(fmaxf(v, 0.0f), 1023.0f);
    g[d] = (unsigned int)(int)v;
  }
  unsigned int ca = hilbert3(g[0], g[1], g[2]);
  unsigned int cb = hilbert3(g[1], g[0], g[2]);
  keys[t]         = ((unsigned long long)ca << 14) | (unsigned long long)t;
  keys[L_TOK + t] = ((unsigned long long)cb << 14) | (unsigned long long)t;
}

// bitonic-sort each 512-key tile in LDS (64 tiles = 2 arrays x 32)
__global__ __launch_bounds__(256) void sort_tiles(const unsigned long long* __restrict__ keys,
                                                  unsigned long long* __restrict__ skeys) {
  __shared__ unsigned long long s[512];
  int b = blockIdx.x, tid = threadIdx.x;
  size_t base = (size_t)(b >> 5)*L_TOK + (size_t)(b & 31)*512;
  s[tid]       = keys[base + tid];
  s[tid + 256] = keys[base + tid + 256];
  for (unsigned int k = 2; k <= 512; k <<= 1) {
    for (unsigned int j = k >> 1; j > 0; j >>= 1) {
      __syncthreads();
      #pragma unroll
      for (int h = 0; h < 2; ++h) {
        int i = tid + 256*h;
        int ixj = i ^ (int)j;
        if (ixj > i) {
          unsigned long long a = s[i], c = s[ixj];
          bool up = ((i & (int)k) == 0);
          if (up ? (a > c) : (a < c)) { s[i] = c; s[ixj] = a; }
        }
      }
    }
  }
  __syncthreads();
  skeys[base + tid]       = s[tid];
  skeys[base + tid + 256] = s[tid + 256];
}

// rank via binary search in sorted tiles (ranks bit-identical to brute force)
__global__ __launch_bounds__(256) void rank_partial(const unsigned long long* __restrict__ keys,
                                                    const unsigned long long* __restrict__ skeys,
                                                    unsigned int* __restrict__ partial) {
  __shared__ unsigned long long tile[512];
  int arr = blockIdx.y, ks = blockIdx.z;
  const unsigned long long* k = keys + (size_t)arr * L_TOK;
  int qbase = blockIdx.x*1024 + threadIdx.x;
  unsigned long long q[4];
  #pragma unroll
  for (int i = 0; i < 4; ++i) q[i] = k[qbase + 256*i];
  const unsigned long long* src = skeys + (size_t)arr*L_TOK + ks*512;
  tile[threadIdx.x]       = src[threadIdx.x];
  tile[threadIdx.x + 256] = src[threadIdx.x + 256];
  __syncthreads();
  #pragma unroll
  for (int i = 0; i < 4; ++i) {
    unsigned int lo = 0;
    #pragma unroll
    for (unsigned int st = 256; st > 0; st >>= 1)
      if (tile[lo + st - 1] < q[i]) lo += st;
    lo += (tile[lo] < q[i]) ? 1u : 0u;
    partial[(size_t)(ks*2 + arr)*L_TOK + qbase + 256*i] = lo;
  }
}

__global__ __launch_bounds__(256) void rank_scatter(const unsigned long long* __restrict__ keys,
                                                    const unsigned int* __restrict__ partial,
                                                    unsigned int* __restrict__ ord,
                                                    unsigned int* __restrict__ inv) {
  int i = blockIdx.x*256 + threadIdx.x;
  int arr = i >> 14;
  int qi = i & (L_TOK - 1);
  unsigned int r = 0;
  #pragma unroll
  for (int ks = 0; ks < 32; ++ks) r += partial[(size_t)(ks*2 + arr)*L_TOK + qi];
  unsigned int tok = (unsigned int)(keys[i] & 0x3FFFu);
  ord[(size_t)arr*L_TOK + r] = tok;
  inv[(size_t)arr*L_TOK + tok] = r;
}

// ---------------- layernorm ----------------

__global__ __launch_bounds__(256) void ln_kernel(const float* __restrict__ in, float* __restrict__ out,
                                                 unsigned short* __restrict__ outbf,
                                                 const float* __restrict__ w, const float* __restrict__ b) {
  int row = blockIdx.x*4 + (threadIdx.x >> 6);
  int lane = threadIdx.x & 63;
  const float4 v = *(const float4*)(in + (size_t)row*DM + lane*4);
  float s = v.x + v.y + v.z + v.w;
  float mean = warp_sum(s) * (1.0f/DM);
  float4 xc = make_float4(v.x-mean, v.y-mean, v.z-mean, v.w-mean);
  float ss = xc.x*xc.x + xc.y*xc.y + xc.z*xc.z + xc.w*xc.w;
  ss = warp_sum(ss) * (1.0f/DM);
  float inv = rsqrtf(ss + EPSF);
  const float4 w4 = *(const float4*)(w + lane*4);
  const float4 b4 = *(const float4*)(b + lane*4);
  float4 o;
  o.x = xc.x*inv*w4.x + b4.x;
  o.y = xc.y*inv*w4.y + b4.y;
  o.z = xc.z*inv*w4.z + b4.z;
  o.w = xc.w*inv*w4.w + b4.w;
  *(float4*)(out + (size_t)row*DM + lane*4) = o;
  if (outbf) {
    ushort4 ob = make_ushort4(f2bf(o.x), f2bf(o.y), f2bf(o.z), f2bf(o.w));
    *(ushort4*)(outbf + (size_t)row*DM + lane*4) = ob;
  }
}

// fin-LN (in place on io) fused with next layer's pre-LN (writes qn/qnbf) in one read
__global__ __launch_bounds__(256) void lnfuse_kernel(float* __restrict__ io,
                                                     float* __restrict__ qn, unsigned short* __restrict__ qnbf,
                                                     const float* __restrict__ fw, const float* __restrict__ fb,
                                                     const float* __restrict__ pw, const float* __restrict__ pb) {
  int row = blockIdx.x*4 + (threadIdx.x >> 6);
  int lane = threadIdx.x & 63;
  const float4 v = *(const float4*)(io + (size_t)row*DM + lane*4);
  float s = v.x + v.y + v.z + v.w;
  float mean = warp_sum(s) * (1.0f/DM);
  float4 xc = make_float4(v.x-mean, v.y-mean, v.z-mean, v.w-mean);
  float ss = xc.x*xc.x + xc.y*xc.y + xc.z*xc.z + xc.w*xc.w;
  ss = warp_sum(ss) * (1.0f/DM);
  float inv = rsqrtf(ss + EPSF);
  const float4 w4 = *(const float4*)(fw + lane*4);
  const float4 b4 = *(const float4*)(fb + lane*4);
  float4 o;
  o.x = xc.x*inv*w4.x + b4.x;
  o.y = xc.y*inv*w4.y + b4.y;
  o.z = xc.z*inv*w4.z + b4.z;
  o.w = xc.w*inv*w4.w + b4.w;
  *(float4*)(io + (size_t)row*DM + lane*4) = o;
  if (qn) {
    float s2 = o.x + o.y + o.z + o.w;
    float mean2 = warp_sum(s2) * (1.0f/DM);
    float4 x2 = make_float4(o.x-mean2, o.y-mean2, o.z-mean2, o.w-mean2);
    float ss2 = x2.x*x2.x + x2.y*x2.y + x2.z*x2.z + x2.w*x2.w;
    ss2 = warp_sum(ss2) * (1.0f/DM);
    float inv2 = rsqrtf(ss2 + EPSF);
    const float4 pw4 = *(const float4*)(pw + lane*4);
    const float4 pb4 = *(const float4*)(pb + lane*4);
    float4 qv;
    qv.x = x2.x*inv2*pw4.x + pb4.x;
    qv.y = x2.y*inv2*pw4.y + pb4.y;
    qv.z = x2.z*inv2*pw4.z + pb4.z;
    qv.w = x2.w*inv2*pw4.w + pb4.w;
    *(float4*)(qn + (size_t)row*DM + lane*4) = qv;
    ushort4 qb = make_ushort4(f2bf(qv.x), f2bf(qv.y), f2bf(qv.z), f2bf(qv.w));
    *(ushort4*)(qnbf + (size_t)row*DM + lane*4) = qb;
  }
}

// ---------------- weight transpose+convert: both layers in one launch ----------------
// per layer: WtA 72 blocks (18 n-tiles x 4 k-tiles); WtO 32 blocks (4 n-tiles x 8 k-tiles)

__global__ __launch_bounds__(256) void tcvt_all(const float* __restrict__ Wi0, const float* __restrict__ Wo0,
                                                const float* __restrict__ nw0,
                                                const float* __restrict__ Wi1, const float* __restrict__ Wo1,
                                                const float* __restrict__ nw1,
                                                unsigned short* __restrict__ WtA, unsigned short* __restrict__ WtO) {
  __shared__ float lds[64*65];
  int b = blockIdx.x, tid = threadIdx.x;
  int lyr = (b >= 104) ? 1 : 0;
  b -= lyr*104;
  const float* Wi = lyr ? Wi1 : Wi0;
  const float* Wo = lyr ? Wo1 : Wo0;
  const float* nw = lyr ? nw1 : nw0;
  WtA += (size_t)lyr*1152*DM;
  WtO += (size_t)lyr*DM*DI;
  const float* src; int srcld, n0, k0t, dstld; unsigned short* dst; bool useNw;
  if (b < 72) {
    int nt = b >> 2, kt = b & 3;
    n0 = nt*64; k0t = kt*64;
    src = Wi; srcld = DP; dst = WtA; dstld = 256; useNw = false;
  } else {
    int j = b - 72;
    int nt = j >> 3, kt = j & 7;
    n0 = nt*64; k0t = kt*64;
    src = Wo; srcld = DM; dst = WtO; dstld = 512; useNw = true;
  }
  int nn = (tid & 15)*4, kk = tid >> 4;
  #pragma unroll
  for (int p = 0; p < 4; ++p) {
    int k = kk + p*16;
    float4 v = *(const float4*)(src + (size_t)(k0t + k)*srcld + n0 + nn);
    lds[k*65 + nn]   = v.x;
    lds[k*65 + nn+1] = v.y;
    lds[k*65 + nn+2] = v.z;
    lds[k*65 + nn+3] = v.w;
  }
  __syncthreads();
  int n = tid >> 2, kq = (tid & 3)*16;
  float nwv[16];
  if (useNw) {
    #pragma unroll
    for (int e = 0; e < 16; e += 4) {
      float4 t4 = *(const float4*)(nw + k0t + kq + e);
      nwv[e]=t4.x; nwv[e+1]=t4.y; nwv[e+2]=t4.z; nwv[e+3]=t4.w;
    }
  } else {
    #pragma unroll
    for (int e = 0; e < 16; ++e) nwv[e] = 1.0f;
  }
  short8 o0, o1;
  #pragma unroll
  for (int e = 0; e < 8; ++e) {
    o0[e] = (short)f2bf(lds[(kq+e)*65 + n] * nwv[e]);
    o1[e] = (short)f2bf(lds[(kq+8+e)*65 + n] * nwv[8+e]);
  }
  unsigned short* dp = dst + (size_t)(n0 + n)*dstld + k0t + kq;
  *(short8*)dp = o0;
  *(short8*)(dp + 8) = o1;
}

// ---------------- fused input GEMM: nat (gate+BC, 640 blocks) + x (Hilbert transposed, 1024 blocks) ----------------

__global__ __launch_bounds__(256) void gemm_in2(const unsigned short* __restrict__ Abf,
                                                const unsigned short* __restrict__ Wt,
                                                const unsigned int* __restrict__ ord,
                                                unsigned short* __restrict__ gate_nat,
                                                unsigned short* __restrict__ bcraw,
                                                unsigned short* __restrict__ xTg) {
  __shared__ unsigned short Alds[128*64];
  __shared__ unsigned short Blds[128*64];
  int tid = threadIdx.x, lane = tid & 63, w = tid >> 6;
  int bid = blockIdx.x;
  bool natp = bid < 640;
  int rb, cb, dir = 0, wcol0;
  if (natp) {
    int xcd = bid & 7, g = bid >> 3;
    rb = (xcd*16 + g/5)*128;
    cb = (g % 5)*128;
    wcol0 = cb;
  } else {
    int id = bid - 640;
    dir = id >> 9;
    int b = id & 511;
    int xcd = b & 7, g = b >> 3;
    rb = (xcd*16 + g/4)*128;
    cb = (g % 4)*128;
    wcol0 = DI + cb;
  }
  int wm = (w & 1)*64, wn = (w >> 1)*64;
  const unsigned int* ordp = ord + (size_t)dir*L_TOK;
  const unsigned short* pA[4]; const unsigned short* pB[4];
  unsigned short* dA[4]; unsigned short* dB[4];
  #pragma unroll
  for (int s = 0; s < 4; ++s) {
    int inst = w*4 + s;
    int r = inst*8 + (lane >> 3);
    int cA = (lane & 7) ^ (r & 7);
    int arow = natp ? (rb + r) : (int)ordp[rb + r];
    pA[s] = Abf + (size_t)arow*DM + cA*8;
    pB[s] = Wt + (size_t)(wcol0 + r)*DM + cA*8;
    dA[s] = &Alds[inst*512];
    dB[s] = &Blds[inst*512];
  }
  f32x4 zero = {0.f, 0.f, 0.f, 0.f};
  f32x4 acc[4][4];
  #pragma unroll
  for (int i = 0; i < 4; ++i)
    #pragma unroll
    for (int j = 0; j < 4; ++j) acc[i][j] = zero;
  int t = lane & 15, q = lane >> 4;
  for (int k0 = 0; k0 < DM; k0 += 64) {
    #pragma unroll
    for (int s = 0; s < 4; ++s) GLL16(pA[s] + k0, dA[s]);
    #pragma unroll
    for (int s = 0; s < 4; ++s) GLL16(pB[s] + k0, dB[s]);
    __syncthreads();
    #pragma unroll
    for (int ks = 0; ks < 2; ++ks) {
      short8 af[4], bfr[4];
      int cc = ks*4 + q;
      #pragma unroll
      for (int i = 0; i < 4; ++i) {
        int rr = wm + 16*i + t;
        af[i] = *(const short8*)&Alds[rr*64 + ((cc ^ (rr & 7))*8)];
      }
      #pragma unroll
      for (int j = 0; j < 4; ++j) {
        int rr = wn + 16*j + t;
        bfr[j] = *(const short8*)&Blds[rr*64 + ((cc ^ (rr & 7))*8)];
      }
      #pragma unroll
      for (int i = 0; i < 4; ++i)
        #pragma unroll
        for (int j = 0; j < 4; ++j)
          acc[i][j] = __builtin_amdgcn_mfma_f32_16x16x32_bf16(af[i], bfr[j], acc[i][j], 0, 0, 0);
    }
    __syncthreads();
  }
  if (natp) {
    unsigned short* dst; int ld;
    if (cb < DI) { dst = gate_nat + cb; ld = DI; }
    else         { dst = bcraw + (cb - DI); ld = 128; }
    #pragma unroll
    for (int i = 0; i < 4; ++i) {
      int rowb = rb + wm + 16*i + q*4;
      #pragma unroll
      for (int j = 0; j < 4; ++j) {
        int col = wn + 16*j + t;
        #pragma unroll
        for (int r = 0; r < 4; ++r)
          dst[(size_t)(rowb + r)*ld + col] = f2bf(acc[i][j][r]);
      }
    }
  } else {
    #pragma unroll
    for (int i = 0; i < 4; ++i) {
      int rowb = rb + wm + 16*i + q*4;
      #pragma unroll
      for (int j = 0; j < 4; ++j) {
        int col = wn + 16*j + t;
        ushort4 o = make_ushort4(f2bf(acc[i][j][0]), f2bf(acc[i][j][1]),
                                 f2bf(acc[i][j][2]), f2bf(acc[i][j][3]));
        *(ushort4*)(xTg + (size_t)(cb + col)*(2*L_TOK) + (size_t)dir*L_TOK + rowb) = o;
      }
    }
  }
}

// ---------------- gather-based out GEMM + in-kernel RMS (from A fragments) ----------------

__global__ __launch_bounds__(256) void gemm_out_gather(const unsigned short* __restrict__ ybuf,
                                                       const unsigned short* __restrict__ Wt,
                                                       const unsigned int* __restrict__ inv,
                                                       const float* __restrict__ shortcut,
                                                       float* __restrict__ out) {
  __shared__ unsigned short Alds[2*64*64];   // [dir][64 rows][64 k]
  __shared__ unsigned short Blds[128*64];
  __shared__ float sql[2][64];
  int tid = threadIdx.x, lane = tid & 63, w = tid >> 6;
  int bid = blockIdx.x;
  int xcd = bid & 7, g = bid >> 3;
  int rb = (xcd*32 + (g >> 1))*64;
  int cb = (g & 1)*128;
  int wm = (w & 1)*32, wn = (w >> 1)*64;
  bool rmsw = ((w >> 1) == 0);   // only wn==0 waves compute/publish row sums
  const unsigned short* pA0[2]; const unsigned short* pA1[2];
  unsigned short* dA0[2]; unsigned short* dA1[2];
  const unsigned short* pB[4]; unsigned short* dB[4];
  #pragma unroll
  for (int s = 0; s < 2; ++s) {
    int inst = w*2 + s;
    int r = inst*8 + (lane >> 3);
    int cA = (lane & 7) ^ (r & 7);
    int tok = rb + r;
    pA0[s] = ybuf + (size_t)inv[tok]*DI + cA*8;
    pA1[s] = ybuf + (size_t)L_TOK*DI + (size_t)inv[L_TOK + tok]*DI + cA*8;
    dA0[s] = &Alds[inst*512];
    dA1[s] = &Alds[4096 + inst*512];
  }
  #pragma unroll
  for (int s = 0; s < 4; ++s) {
    int inst = w*4 + s;
    int r = inst*8 + (lane >> 3);
    int cA = (lane & 7) ^ (r & 7);
    pB[s] = Wt + (size_t)(cb + r)*DI + cA*8;
    dB[s] = &Blds[inst*512];
  }
  f32x4 zero = {0.f, 0.f, 0.f, 0.f};
  f32x4 acc0[2][4], acc1[2][4];
  #pragma unroll
  for (int i = 0; i < 2; ++i)
    #pragma unroll
    for (int j = 0; j < 4; ++j) { acc0[i][j] = zero; acc1[i][j] = zero; }
  float sq0[2] = {0.f, 0.f}, sq1[2] = {0.f, 0.f};
  int t = lane & 15, q = lane >> 4;
  for (int k0 = 0; k0 < DI; k0 += 64) {
    #pragma unroll
    for (int s = 0; s < 2; ++s) { GLL16(pA0[s] + k0, dA0[s]); GLL16(pA1[s] + k0, dA1[s]); }
    #pragma unroll
    for (int s = 0; s < 4; ++s) GLL16(pB[s] + k0, dB[s]);
    __syncthreads();
    #pragma unroll
    for (int ks = 0; ks < 2; ++ks) {
      short8 af0[2], af1[2], bfr[4];
      int cc = ks*4 + q;
      #pragma unroll
      for (int i = 0; i < 2; ++i) {
        int rr = wm + 16*i + t;
        int off = rr*64 + ((cc ^ (rr & 7))*8);
        af0[i] = *(const short8*)&Alds[off];
        af1[i] = *(const short8*)&Alds[4096 + off];
      }
      // accumulate sum(y^2) from fragments (wn==0 waves only; hidden under MFMA pipe)
      if (rmsw) {
        #pragma unroll
        for (int i = 0; i < 2; ++i)
          #pragma unroll
          for (int e = 0; e < 8; ++e) {
            float a0 = bf2f((unsigned short)af0[i][e]);
            float a1 = bf2f((unsigned short)af1[i][e]);
            sq0[i] = fmaf(a0, a0, sq0[i]);
            sq1[i] = fmaf(a1, a1, sq1[i]);
          }
      }
      #pragma unroll
      for (int j = 0; j < 4; ++j) {
        int rr = wn + 16*j + t;
        bfr[j] = *(const short8*)&Blds[rr*64 + ((cc ^ (rr & 7))*8)];
      }
      #pragma unroll
      for (int i = 0; i < 2; ++i)
        #pragma unroll
        for (int j = 0; j < 4; ++j) {
          acc0[i][j] = __builtin_amdgcn_mfma_f32_16x16x32_bf16(af0[i], bfr[j], acc0[i][j], 0, 0, 0);
          acc1[i][j] = __builtin_amdgcn_mfma_f32_16x16x32_bf16(af1[i], bfr[j], acc1[i][j], 0, 0, 0);
        }
    }
    __syncthreads();
  }
  // reduce sq over the 4 lanes (q) sharing each A row; publish per-row sums via LDS
  if (rmsw) {
    #pragma unroll
    for (int i = 0; i < 2; ++i) {
      float s0 = sq0[i];
      s0 += __shfl_xor(s0, 16, 64);
      s0 += __shfl_xor(s0, 32, 64);
      float s1 = sq1[i];
      s1 += __shfl_xor(s1, 16, 64);
      s1 += __shfl_xor(s1, 32, 64);
      if (q == 0) { sql[0][wm + 16*i + t] = s0; sql[1][wm + 16*i + t] = s1; }
    }
  }
  __syncthreads();
  #pragma unroll
  for (int i = 0; i < 2; ++i) {
    #pragma unroll
    for (int r = 0; r < 4; ++r) {
      int rl = wm + 16*i + q*4 + r;
      int row = rb + rl;
      float ir0 = rsqrtf(sql[0][rl]*(1.0f/DI) + EPSF);
      float ir1 = rsqrtf(sql[1][rl]*(1.0f/DI) + EPSF);
      const float* sp = shortcut + (size_t)row*DM + cb;
      float* op = out + (size_t)row*DM + cb;
      #pragma unroll
      for (int j = 0; j < 4; ++j) {
        int col = wn + 16*j + t;
        op[col] = sp[col] + 0.5f*(ir0*acc0[i][j][r] + ir1*acc1[i][j][r]);
      }
    }
  }
}

// ---------------- fused dt GEMV (blocks 0..511) + convBC swizzled-tile (blocks 512..1023) ----------------

__global__ __launch_bounds__(256) void dtconv(const float* __restrict__ qn, const float* __restrict__ W,
                                              const float* __restrict__ dt_bias, float* __restrict__ dtb,
                                              const unsigned short* __restrict__ bcraw,
                                              const float* __restrict__ cw, const float* __restrict__ cbias,
                                              const unsigned int* __restrict__ ord,
                                              unsigned short* __restrict__ bcswz,
                                              unsigned short* __restrict__ bcswzA) {
  __shared__ unsigned short smem[131*64];
  int tid = threadIdx.x;
  int bx = blockIdx.x;
  if (bx < 512) {
    float* Wl = (float*)smem;
    {
      const float* wp = W + (size_t)tid*DP + (DI + CD);
      float4 wa = *(const float4*)wp;
      float4 wb = *(const float4*)(wp + 4);
      int off = tid*8 + (tid >> 5)*4;
      *(float4*)&Wl[off]     = wa;
      *(float4*)&Wl[off + 4] = wb;
    }
    __syncthreads();
    int lane = tid & 63, w = tid >> 6;
    int r = bx*32 + w*8 + (lane >> 3);
    int kg = lane & 7;
    const float* qp = qn + (size_t)r*DM + kg*32;
    float acc[8] = {};
    #pragma unroll
    for (int i = 0; i < 8; ++i) {
      float4 q4 = *(const float4*)(qp + i*4);
      float qv[4] = {q4.x, q4.y, q4.z, q4.w};
      #pragma unroll
      for (int e = 0; e < 4; ++e) {
        int k = kg*32 + i*4 + e;
        int off = k*8 + kg*4;
        float4 wa = *(const float4*)&Wl[off];
        float4 wb = *(const float4*)&Wl[off + 4];
        acc[0] = fmaf(qv[e], wa.x, acc[0]);
        acc[1] = fmaf(qv[e], wa.y, acc[1]);
        acc[2] = fmaf(qv[e], wa.z, acc[2]);
        acc[3] = fmaf(qv[e], wa.w, acc[3]);
        acc[4] = fmaf(qv[e], wb.x, acc[4]);
        acc[5] = fmaf(qv[e], wb.y, acc[5]);
        acc[6] = fmaf(qv[e], wb.z, acc[6]);
        acc[7] = fmaf(qv[e], wb.w, acc[7]);
      }
    }
    #pragma unroll
    for (int h = 0; h < 8; ++h) {
      acc[h] += __shfl_xor(acc[h], 8, 64);
      acc[h] += __shfl_xor(acc[h], 16, 64);
      acc[h] += __shfl_xor(acc[h], 32, 64);
    }
    float v = 0.f;
    #pragma unroll
    for (int h = 0; h < 8; ++h) if (kg == h) v = acc[h];
    v += dt_bias[kg];
    float sp = (v > 0.0f) ? (v + log1pf(__expf(-v))) : log1pf(__expf(v));
    dtb[(size_t)r*NH + kg] = sp;
  } else {
    int cid = bx - 512;
    int half = cid & 1, ty = (cid >> 1) & 127, dir = cid >> 8;
    unsigned short* tile = smem;
    const unsigned int* ordp = ord + (size_t)dir*L_TOK;
    int ch0 = DI + half*64;
    int co0 = half*64;
    int t0 = ty*128;
    for (int cc = tid; cc < 131*8; cc += 256) {
      int r = cc >> 3, cgc = cc & 7;
      int t = t0 - 3 + r;
      short8 v = {0,0,0,0,0,0,0,0};
      if (t >= 0) v = *(const short8*)(bcraw + (size_t)ordp[t]*128 + co0 + cgc*8);
      *(short8*)&tile[r*64 + ((cgc ^ (r & 7))*8)] = v;
    }
    int cg = tid & 7, tp = tid >> 3;
    int ch = ch0 + cg*8;
    float wv[8][4];
    float bias[8];
    #pragma unroll
    for (int e = 0; e < 8; ++e) {
      float4 c4 = *(const float4*)(cw + (ch + e)*4);
      wv[e][0] = c4.x; wv[e][1] = c4.y; wv[e][2] = c4.z; wv[e][3] = c4.w;
    }
    {
      float4 b0 = *(const float4*)(cbias + ch);
      float4 b1 = *(const float4*)(cbias + ch + 4);
      bias[0]=b0.x; bias[1]=b0.y; bias[2]=b0.z; bias[3]=b0.w;
      bias[4]=b1.x; bias[5]=b1.y; bias[6]=b1.z; bias[7]=b1.w;
    }
    __syncthreads();
    #pragma unroll
    for (int tk = 0; tk < 4; ++tk) {
      int rel = tp + 32*tk;
      float acc[8];
      #pragma unroll
      for (int e = 0; e < 8; ++e) acc[e] = bias[e];
      #pragma unroll
      for (int k = 0; k < 4; ++k) {
        int r = rel + k;
        short8 v = *(const short8*)&tile[r*64 + ((cg ^ (r & 7))*8)];
        #pragma unroll
        for (int e = 0; e < 8; ++e)
          acc[e] = fmaf(wv[e][k], bf2f((unsigned short)v[e]), acc[e]);
      }
      short8 o;
      #pragma unroll
      for (int e = 0; e < 8; ++e) o[e] = (short)f2bf(fsilu(acc[e]));
      int T = t0 + rel;
      int chn = T >> 6, tl = T & 63;
      unsigned short* tb = bcswz + ((size_t)((dir*NC + chn)*2 + half))*4096;
      *(short8*)(tb + tl*64 + ((cg ^ (tl & 7))*8)) = o;
      if (half == 0) {
        unsigned short* ta = bcswzA + ((size_t)(dir*NC + chn))*4096;
        #pragma unroll
        for (int e = 0; e < 8; ++e) {
          int s5 = cg*8 + e;
          ta[s5*64 + (((tl >> 3) ^ (s5 & 7))*8) + (tl & 7)] = (unsigned short)o[e];
        }
      }
    }
  }
}

// ---------------- chunked scan (MFMA, bf16 S) ----------------
// grid = (NC, NH, 2): heads sharing a chunk sit 256 blocks apart (256 % 8 == 0 -> same XCD
// under round-robin dispatch) -> B/C tile L2 reuse.

__global__ __launch_bounds__(256) void phaseA_mfma(const unsigned short* __restrict__ xTg,
                                                   const unsigned short* __restrict__ bcswzA,
                                                   const float* __restrict__ cw, const float* __restrict__ cbias,
                                                   const float* __restrict__ dtb, const float* __restrict__ A_log,
                                                   const unsigned int* __restrict__ ord,
                                                   unsigned short* __restrict__ S, float* __restrict__ P,
                                                   unsigned short* __restrict__ xsT) {
  int c = blockIdx.x, h = blockIdx.y, dir = blockIdx.z, tid = threadIdx.x;
  int lane = tid & 63, w = tid >> 6;
  int hh = dir*NH + h;
  __shared__ unsigned short xT[64*64];
  __shared__ unsigned short Bt[64*64];
  __shared__ float wgt[64];
  int c0 = c*CHUNK;
  float Ah = -expf(A_log[h]);
  const unsigned short* bA = bcswzA + ((size_t)(dir*NC + c))*4096;
  #pragma unroll
  for (int s = 0; s < 2; ++s) {
    int inst = w*2 + s;
    GLL16(bA + (size_t)inst*512 + lane*8, &Bt[inst*512]);
  }
  // wave0: parallel suffix scan of lg = dt*A (dtb gathered via ord)
  if (tid < 64) {
    unsigned int tok = ord[(size_t)dir*L_TOK + c0 + tid];
    float dtv = dtb[(size_t)tok*NH + h];
    float v = dtv*Ah;
    float s = v;
    #pragma unroll
    for (int d = 1; d < 64; d <<= 1) {
      float u = __shfl_down(s, d, 64);
      s += (tid + d < 64) ? u : 0.f;
    }
    wgt[tid] = dtv*fexp(s - v);
    if (tid == 0) P[hh*NC + c] = fexp(s);
  }
  __syncthreads();
  unsigned short* xpg = xsT + ((size_t)(hh*NC + c))*4096;
  #pragma unroll
  for (int i = 0; i < 2; ++i) {
    int q = tid + 256*i;
    int p = q >> 3, tg = q & 7;
    int sw8 = (tg ^ (p & 7))*8;
    const unsigned short* xrow = xTg + (size_t)(h*HD + p)*(2*L_TOK) + (size_t)dir*L_TOK;
    int tb = c0 + tg*8;
    short8 cur = *(const short8*)(xrow + tb);
    int sh5 = __shfl_up((int)(unsigned short)cur[5], 1, 64);
    int sh6 = __shfl_up((int)(unsigned short)cur[6], 1, 64);
    int sh7 = __shfl_up((int)(unsigned short)cur[7], 1, 64);
    unsigned short b5 = 0, b6 = 0, b7 = 0;
    if (tg == 0) {
      if (tb >= 8) {
        ushort4 pv = *(const ushort4*)(xrow + tb - 4);
        b5 = pv.y; b6 = pv.z; b7 = pv.w;
      }
    } else {
      b5 = (unsigned short)sh5; b6 = (unsigned short)sh6; b7 = (unsigned short)sh7;
    }
    float4 w4 = *(const float4*)(cw + (size_t)(h*HD + p)*4);
    float bb = cbias[h*HD + p];
    float xv[11];
    xv[0] = bf2f(b5);
    xv[1] = bf2f(b6);
    xv[2] = bf2f(b7);
    #pragma unroll
    for (int k = 0; k < 8; ++k) xv[3+k] = bf2f((unsigned short)cur[k]);
    short8 raw, wtd;
    #pragma unroll
    for (int k = 0; k < 8; ++k) {
      float a = bb + w4.x*xv[k] + w4.y*xv[k+1] + w4.z*xv[k+2] + w4.w*xv[k+3];
      unsigned short rbf = f2bf(fsilu(a));
      raw[k] = (short)rbf;
      wtd[k] = (short)f2bf(bf2f(rbf)*wgt[tg*8 + k]);
    }
    *(short8*)(xpg + p*64 + sw8) = raw;
    *(short8*)&xT[p*64 + sw8] = wtd;
  }
  __syncthreads();
  int t16 = lane & 15, q4 = lane >> 4;
  f32x4 zero = {0.f,0.f,0.f,0.f};
  f32x4 acc[4];
  #pragma unroll
  for (int j = 0; j < 4; ++j) acc[j] = zero;
  #pragma unroll
  for (int ks = 0; ks < 2; ++ks) {
    int rowA = 16*w + t16;
    short8 a = *(const short8*)&xT[rowA*64 + (((ks*4 + q4) ^ (rowA & 7))*8)];
    #pragma unroll
    for (int j = 0; j < 4; ++j) {
      int rowB = 16*j + t16;
      short8 b = *(const short8*)&Bt[rowB*64 + (((ks*4 + q4) ^ (rowB & 7))*8)];
      acc[j] = __builtin_amdgcn_mfma_f32_16x16x32_bf16(a, b, acc[j], 0, 0, 0);
    }
  }
  unsigned short* Sp = S + ((size_t)(hh*NC + c))*4096;
  #pragma unroll
  for (int j = 0; j < 4; ++j)
    #pragma unroll
    for (int r = 0; r < 4; ++r) {
      int row = 16*w + q4*4 + r;
      int cg2 = 2*j + (t16 >> 3);
      Sp[(size_t)row*64 + (((cg2 ^ (row & 7)) << 3) | (t16 & 7))] = f2bf(acc[j][r]);
    }
}

// ---- phaseB: single-pass in-place exclusive scan over chunks (layout-agnostic) ----

__global__ __launch_bounds__(128) void phaseB_scan(unsigned short* __restrict__ S, const float* __restrict__ P) {
  __shared__ float Pl[NC];
  int b = blockIdx.x;
  int hh = b >> 4;
  int e2 = (b & 15)*128 + threadIdx.x;
  for (int i = threadIdx.x; i < NC; i += 128) Pl[i] = P[hh*NC + i];
  __syncthreads();
  unsigned int* base = (unsigned int*)(S + ((size_t)hh*NC)*4096) + e2;
  float hx = 0.f, hy = 0.f;
  #pragma unroll 1
  for (int k0 = 0; k0 < NC; k0 += 16) {
    unsigned int v[16];
    #pragma unroll
    for (int u = 0; u < 16; ++u) v[u] = base[(size_t)(k0+u)*2048];
    #pragma unroll
    for (int u = 0; u < 16; ++u) {
      float p = Pl[k0+u];
      unsigned int old = v[u];
      base[(size_t)(k0+u)*2048] = (unsigned int)f2bf(hx) | ((unsigned int)f2bf(hy) << 16);
      hx = p*hx + bf2f((unsigned short)(old & 0xffffu));
      hy = p*hy + bf2f((unsigned short)(old >> 16));
    }
  }
}

// phaseC: grid (NC, NH, 2); all staging via GLL16 from pre-swizzled tiles; Gl aliased onto Cl;
// epilogue: accY -> f32 LDS overlay -> coalesced gate-mul + y store (RMS in gemm_out).
__global__ __launch_bounds__(256) void phaseC_mfma(const unsigned short* __restrict__ bcswz,
                                                   const unsigned short* __restrict__ xsT,
                                                   const unsigned short* __restrict__ gate_nat,
                                                   const float* __restrict__ dtb, const float* __restrict__ A_log,
                                                   const float* __restrict__ Dp,
                                                   const unsigned int* __restrict__ ord,
                                                   const unsigned short* __restrict__ S,
                                                   unsigned short* __restrict__ ybuf) {
  int c = blockIdx.x, h = blockIdx.y, dir = blockIdx.z, tid = threadIdx.x;
  int lane = tid & 63, w = tid >> 6;
  int hh = dir*NH + h;
  unsigned short* y = ybuf + (size_t)dir*L_TOK*DI;
  __shared__ __align__(16) unsigned short smemT[4*4096];
  __shared__ float dts[64], pl[64], pe[64];
  unsigned short* Cl  = smemT;            // reused as Gl after stage-1 (wave-private rows)
  unsigned short* Bl  = smemT + 4096;
  unsigned short* h0l = smemT + 8192;
  unsigned short* xT  = smemT + 12288;
  float* fT = (float*)(smemT + 8192);     // 16KB f32 overlay on h0l+xT (dead after MFMAs)
  int c0 = c*CHUNK;
  float Ah = -expf(A_log[h]);
  float Dh = Dp[h];
  const unsigned short* Sp = S + ((size_t)(hh*NC + c))*4096;
  const unsigned short* xp = xsT + ((size_t)(hh*NC + c))*4096;
  const unsigned short* Bg = bcswz + ((size_t)((dir*NC + c)*2 + 0))*4096;
  const unsigned short* Cg = bcswz + ((size_t)((dir*NC + c)*2 + 1))*4096;
  #pragma unroll
  for (int s = 0; s < 2; ++s) {
    int inst = w*2 + s;
    GLL16(Sp + (size_t)inst*512 + lane*8, &h0l[inst*512]);
    GLL16(xp + (size_t)inst*512 + lane*8, &xT[inst*512]);
    GLL16(Bg + (size_t)inst*512 + lane*8, &Bl[inst*512]);
    GLL16(Cg + (size_t)inst*512 + lane*8, &Cl[inst*512]);
  }
  // hoisted epilogue loads (independent): token + gate row-segment for this thread's row
  int erow = tid >> 2;
  int ech0 = (tid & 3) * 16;
  unsigned int etok = ord[(size_t)dir*L_TOK + c0 + erow];
  const unsigned short* gp = gate_nat + (size_t)etok*DI + h*HD + ech0;
  short8 g0 = *(const short8*)gp;
  short8 g1 = *(const short8*)(gp + 8);
  // wave0: parallel inclusive prefix scan of lg = dt*A (dtb gathered via ord)
  if (tid < 64) {
    unsigned int tok = ord[(size_t)dir*L_TOK + c0 + tid];
    float dtv = dtb[(size_t)tok*NH + h];
    dts[tid] = dtv;
    float v = dtv*Ah;
    float s = v;
    #pragma unroll
    for (int d = 1; d < 64; d <<= 1) {
      float u = __shfl_up(s, d, 64);
      s += (tid >= d) ? u : 0.f;
    }
    pl[tid] = s;
    pe[tid] = fexp(s);
  }
  __syncthreads();
  int t16 = lane & 15, q4 = lane >> 4;
  int t0 = 16*w;
  f32x4 zero = {0.f,0.f,0.f,0.f};
  f32x4 accG[4], accY[4];
  #pragma unroll
  for (int j = 0; j < 4; ++j) { accG[j] = zero; accY[j] = zero; }
  #pragma unroll
  for (int ks = 0; ks < 2; ++ks) {
    int rowA = t0 + t16;
    short8 a = *(const short8*)&Cl[rowA*64 + (((ks*4 + q4) ^ (rowA & 7))*8)];
    #pragma unroll
    for (int j = 0; j < 4; ++j) {
      int rowB = 16*j + t16;
      int off = rowB*64 + (((ks*4 + q4) ^ (rowB & 7))*8);
      accG[j] = __builtin_amdgcn_mfma_f32_16x16x32_bf16(a, *(const short8*)&Bl[off], accG[j], 0, 0, 0);
      accY[j] = __builtin_amdgcn_mfma_f32_16x16x32_bf16(a, *(const short8*)&h0l[off], accY[j], 0, 0, 0);
    }
  }
  // Gl (aliased onto Cl): wave w only touches rows [16w,16w+16), which it alone read as A-operand
  #pragma unroll
  for (int j = 0; j < 4; ++j) {
    #pragma unroll
    for (int r = 0; r < 4; ++r) {
      int t = t0 + q4*4 + r;
      int s = 16*j + t16;
      float v = 0.f;
      if (s <= t) {
        v = accG[j][r] * dts[s] * fexp(pl[t] - pl[s]);
        if (s == t) v += Dh;
      }
      Cl[t*64 + (((s >> 3) ^ (t & 7))*8 + (s & 7))] = f2bf(v);
    }
  }
  #pragma unroll
  for (int j = 0; j < 4; ++j)
    #pragma unroll
    for (int r = 0; r < 4; ++r)
      accY[j][r] *= pe[t0 + q4*4 + r];
  #pragma unroll
  for (int ks = 0; ks < 2; ++ks) {
    int rowA = t0 + t16;
    short8 a = *(const short8*)&Cl[rowA*64 + (((ks*4 + q4) ^ (rowA & 7))*8)];
    #pragma unroll
    for (int j = 0; j < 4; ++j) {
      int rowB = 16*j + t16;
      short8 b = *(const short8*)&xT[rowB*64 + (((ks*4 + q4) ^ (rowB & 7))*8)];
      accY[j] = __builtin_amdgcn_mfma_f32_16x16x32_bf16(a, b, accY[j], 0, 0, 0);
    }
  }
  __syncthreads();   // all waves done reading h0l/xT
  // write accY into f32 overlay; swizzle: col ^= (q4<<4)
  #pragma unroll
  for (int j = 0; j < 4; ++j)
    #pragma unroll
    for (int r = 0; r < 4; ++r) {
      int t = t0 + q4*4 + r;
      int p = 16*j + t16;
      fT[t*64 + (p ^ (q4 << 4))] = accY[j][r];
    }
  __syncthreads();
  // coalesced epilogue: thread owns 16 contiguous channels of one row
  {
    int swz = ((erow >> 2) & 3) << 4;
    const float* fr = &fT[erow*64 + (ech0 ^ swz)];
    float4 a0 = *(const float4*)(fr);
    float4 a1 = *(const float4*)(fr + 4);
    float4 a2 = *(const float4*)(fr + 8);
    float4 a3 = *(const float4*)(fr + 12);
    float fv[16] = {a0.x,a0.y,a0.z,a0.w, a1.x,a1.y,a1.z,a1.w,
                    a2.x,a2.y,a2.z,a2.w, a3.x,a3.y,a3.z,a3.w};
    short8 o0, o1;
    #pragma unroll
    for (int e = 0; e < 8; ++e) {
      float v0 = fv[e]   * fsilu(bf2f((unsigned short)g0[e]));
      float v1 = fv[8+e] * fsilu(bf2f((unsigned short)g1[e]));
      o0[e] = (short)f2bf(v0);
      o1[e] = (short)f2bf(v1);
    }
    unsigned short* yp = y + (size_t)(c0 + erow)*DI + h*HD + ech0;
    *(short8*)yp = o0;
    *(short8*)(yp + 8) = o1;
  }
}

__global__ void fill_debug(float* out, float v) {
  int i = blockIdx.x*256 + threadIdx.x;
  if (i < L_TOK*DM) out[i] = v;
}

// ---------------- host ----------------

extern "C" void kernel_launch(void* const* d_in, const int* in_sizes, int n_in,
                              void* d_out, int out_size, void* d_ws, size_t ws_size,
                              hipStream_t stream) {
  const float* query = (const float*)d_in[0];
  const float* qpos  = (const float*)d_in[1];
  const float* pre_w = (const float*)d_in[2];
  const float* pre_b = (const float*)d_in[3];
  const float* fin_w = (const float*)d_in[4];
  const float* fin_b = (const float*)d_in[5];
  float* out = (float*)d_out;

  char* ws = (char*)d_ws;
  size_t off = 0;
  auto alloc = [&](size_t bytes) -> void* {
    void* p = ws + off;
    off += (bytes + 255) & ~(size_t)255;
    return p;
  };
  unsigned long long* keys = (unsigned long long*)alloc((size_t)2*L_TOK*8);
  unsigned long long* skeys = (unsigned long long*)alloc((size_t)2*L_TOK*8);
  unsigned int* ord = (unsigned int*)alloc((size_t)2*L_TOK*4);
  unsigned int* inv = (unsigned int*)alloc((size_t)2*L_TOK*4);
  unsigned int* rpart = (unsigned int*)alloc((size_t)32*2*L_TOK*4);
  float* mmpart = (float*)alloc((size_t)64*6*4);
  float* qn   = (float*)alloc((size_t)L_TOK*DM*4);
  unsigned short* qnbf = (unsigned short*)alloc((size_t)L_TOK*DM*2);
  unsigned short* gate_nat = (unsigned short*)alloc((size_t)L_TOK*DI*2);   // natural-order gate
  unsigned short* xTg    = (unsigned short*)alloc((size_t)512*2*L_TOK*2);  // raw x, transposed [ch][dir*L+t]
  unsigned short* bcraw  = (unsigned short*)alloc((size_t)L_TOK*128*2);    // raw B/C, natural token-major
  unsigned short* bcswz  = (unsigned short*)alloc((size_t)2*NC*2*4096*2);  // conv'd B/C, phaseC-layout tiles
  unsigned short* bcswzA = (unsigned short*)alloc((size_t)2*NC*4096*2);    // conv'd B, phaseA-layout tiles
  unsigned short* ybuf   = (unsigned short*)alloc((size_t)2*L_TOK*DI*2);   // gated (unnormalized) y
  float* dtb  = (float*)alloc((size_t)L_TOK*NH*4);                         // natural-order dt
  unsigned short* Sbuf = (unsigned short*)alloc((size_t)2*NH*NC*4096*2);
  unsigned short* xsT  = (unsigned short*)alloc((size_t)2*NH*NC*4096*2);   // silu(conv(x)) pre-swizzled tiles
  float* Pbuf = (float*)alloc((size_t)2*NH*NC*4);
  unsigned short* WtA = (unsigned short*)alloc((size_t)2*1152*DM*2);
  unsigned short* WtO = (unsigned short*)alloc((size_t)2*DM*DI*2);
  if (off > ws_size) {
    fill_debug<<<(L_TOK*DM + 255)/256, 256, 0, stream>>>(out, (float)(ws_size >> 20));
    return;
  }

  minmax_part<<<64, 256, 0, stream>>>(qpos, mmpart);
  hilbert_kernel<<<L_TOK/256, 256, 0, stream>>>(qpos, mmpart, keys);
  sort_tiles<<<64, 256, 0, stream>>>(keys, skeys);
  rank_partial<<<dim3(16, 2, 32), 256, 0, stream>>>(keys, skeys, rpart);
  rank_scatter<<<(2*L_TOK)/256, 256, 0, stream>>>(keys, rpart, ord, inv);
  tcvt_all<<<208, 256, 0, stream>>>((const float*)d_in[6], (const float*)d_in[13], (const float*)d_in[12],
                                    (const float*)d_in[14], (const float*)d_in[21], (const float*)d_in[20],
                                    WtA, WtO);

  for (int l = 0; l < 2; ++l) {
    int base = 6 + 8*l;
    const float* in_proj  = (const float*)d_in[base+0];
    const float* conv_w   = (const float*)d_in[base+1];
    const float* conv_b   = (const float*)d_in[base+2];
    const float* dt_bias  = (const float*)d_in[base+3];
    const float* A_log    = (const float*)d_in[base+4];
    const float* Dp       = (const float*)d_in[base+5];
    const unsigned short* WtAl = WtA + (size_t)l*1152*DM;
    const unsigned short* WtOl = WtO + (size_t)l*DM*DI;

    if (l == 0)
      ln_kernel<<<L_TOK/4, 256, 0, stream>>>(query, qn, qnbf, pre_w, pre_b);
    gemm_in2<<<1664, 256, 0, stream>>>(qnbf, WtAl, ord, gate_nat, bcraw, xTg);
    dtconv<<<1024, 256, 0, stream>>>(qn, in_proj, dt_bias, dtb,
                                     bcraw, conv_w, conv_b, ord, bcswz, bcswzA);
    phaseA_mfma<<<dim3(NC, NH, 2), 256, 0, stream>>>(xTg, bcswzA, conv_w, conv_b, dtb, A_log, ord, Sbuf, Pbuf, xsT);
    phaseB_scan<<<256, 128, 0, stream>>>(Sbuf, Pbuf);
    phaseC_mfma<<<dim3(NC, NH, 2), 256, 0, stream>>>(bcswz, xsT, gate_nat, dtb, A_log, Dp, ord, Sbuf, ybuf);
    gemm_out_gather<<<512, 256, 0, stream>>>(ybuf, WtOl, inv,
                                             l ? (const float*)out : query, out);
    if (l == 0)
      lnfuse_kernel<<<L_TOK/4, 256, 0, stream>>>(out, qn, qnbf, fin_w, fin_b, pre_w, pre_b);
    else
      lnfuse_kernel<<<L_TOK/4, 256, 0, stream>>>(out, nullptr, nullptr, fin_w, fin_b, pre_w, pre_b);
  }
}

// Round 12
// 439.012 us; speedup vs baseline: 1.0306x; 1.0210x over previous
//
#include <hip/hip_runtime.h>
#include <stdint.h>

#define L_TOK 16384
#define DM 256
#define DI 512
#define DS 64
#define NH 8
#define HD 64
#define CD 640
#define DP 1160
#define CHUNK 64
#define NC 256
#define EPSF 1e-5f

typedef __attribute__((ext_vector_type(8))) short short8;
typedef __attribute__((ext_vector_type(4))) float f32x4;

#define GLL16(gp, lp) __builtin_amdgcn_global_load_lds((const __attribute__((address_space(1))) void*)(gp), (__attribute__((address_space(3))) void*)(lp), 16, 0, 0)

__device__ __forceinline__ float warp_sum(float v) {
  v += __shfl_xor(v, 1, 64);
  v += __shfl_xor(v, 2, 64);
  v += __shfl_xor(v, 4, 64);
  v += __shfl_xor(v, 8, 64);
  v += __shfl_xor(v, 16, 64);
  v += __shfl_xor(v, 32, 64);
  return v;
}

__device__ __forceinline__ float fexp(float x) { return __expf(x); }
__device__ __forceinline__ float fsilu(float x) { return x * __builtin_amdgcn_rcpf(1.0f + __expf(-x)); }

__device__ __forceinline__ unsigned short f2bf(float f) {
  unsigned int u = __float_as_uint(f);
  unsigned int r = (u + 0x7FFFu + ((u >> 16) & 1u)) >> 16;
  return (unsigned short)r;
}
__device__ __forceinline__ float bf2f(unsigned short u) {
  return __uint_as_float(((unsigned int)u) << 16);
}

// ---------------- serialization ----------------

__global__ __launch_bounds__(256) void minmax_part(const float* __restrict__ pos, float* __restrict__ part) {
  __shared__ float sm[6][4];
  int tid = threadIdx.x;
  int t = blockIdx.x*256 + tid;
  float a = pos[t*3+0], b = pos[t*3+1], c = pos[t*3+2];
  float mn0=a, mn1=b, mn2=c, mx0=a, mx1=b, mx2=c;
  #pragma unroll
  for (int d = 1; d < 64; d <<= 1) {
    mn0=fminf(mn0,__shfl_xor(mn0,d,64));
    mn1=fminf(mn1,__shfl_xor(mn1,d,64));
    mn2=fminf(mn2,__shfl_xor(mn2,d,64));
    mx0=fmaxf(mx0,__shfl_xor(mx0,d,64));
    mx1=fmaxf(mx1,__shfl_xor(mx1,d,64));
    mx2=fmaxf(mx2,__shfl_xor(mx2,d,64));
  }
  if ((tid & 63) == 0) {
    int w = tid >> 6;
    sm[0][w]=mn0; sm[1][w]=mn1; sm[2][w]=mn2;
    sm[3][w]=mx0; sm[4][w]=mx1; sm[5][w]=mx2;
  }
  __syncthreads();
  if (tid < 6) {
    float r = sm[tid][0];
    if (tid < 3) { r=fminf(r,sm[tid][1]); r=fminf(r,sm[tid][2]); r=fminf(r,sm[tid][3]); }
    else         { r=fmaxf(r,sm[tid][1]); r=fmaxf(r,sm[tid][2]); r=fmaxf(r,sm[tid][3]); }
    part[blockIdx.x*6 + tid] = r;
  }
}

__device__ unsigned int hilbert3(unsigned int a, unsigned int b, unsigned int c) {
  unsigned int x0 = a, x1 = b, x2 = c;
  for (unsigned int Q = 512u; Q > 1u; Q >>= 1) {
    unsigned int P = Q - 1u;
    { if (x0 & Q) x0 ^= P; }
    {
      unsigned int t = (x0 ^ x1) & P;
      if (x1 & Q) { x0 ^= P; }
      else { x0 ^= t; x1 ^= t; }
    }
    {
      unsigned int t = (x0 ^ x2) & P;
      if (x2 & Q) { x0 ^= P; }
      else { x0 ^= t; x2 ^= t; }
    }
  }
  x1 ^= x0; x2 ^= x1;
  unsigned int tt = 0;
  for (unsigned int Q = 512u; Q > 1u; Q >>= 1)
    if (x2 & Q) tt ^= (Q - 1u);
  x0 ^= tt; x1 ^= tt; x2 ^= tt;
  unsigned int code = 0;
  #pragma unroll
  for (int bb = 9; bb >= 0; --bb) {
    code = (code << 1) | ((x0 >> bb) & 1u);
    code = (code << 1) | ((x1 >> bb) & 1u);
    code = (code << 1) | ((x2 >> bb) & 1u);
  }
  return code;
}

// hilbert keys; minmax finalization folded in (each block reduces the 64x6 partials)
__global__ __launch_bounds__(256) void hilbert_kernel(const float* __restrict__ pos, const float* __restrict__ part,
                                                      unsigned long long* __restrict__ keys) {
  __shared__ float spmm[6];
  int tid = threadIdx.x;
  if (tid < 64) {
    const float* p = part + tid*6;
    float mn0=p[0], mn1=p[1], mn2=p[2], mx0=p[3], mx1=p[4], mx2=p[5];
    #pragma unroll
    for (int d = 1; d < 64; d <<= 1) {
      mn0=fminf(mn0,__shfl_xor(mn0,d,64));
      mn1=fminf(mn1,__shfl_xor(mn1,d,64));
      mn2=fminf(mn2,__shfl_xor(mn2,d,64));
      mx0=fmaxf(mx0,__shfl_xor(mx0,d,64));
      mx1=fmaxf(mx1,__shfl_xor(mx1,d,64));
      mx2=fmaxf(mx2,__shfl_xor(mx2,d,64));
    }
    if (tid == 0) {
      spmm[0]=mn0; spmm[1]=mn1; spmm[2]=mn2;
      spmm[3]=mx0; spmm[4]=mx1; spmm[5]=mx2;
    }
  }
  __syncthreads();
  int t = blockIdx.x*256 + tid;
  unsigned int g[3];
  #pragma unroll
  for (int d = 0; d < 3; ++d) {
    float v = (pos[t*3+d] - spmm[d]) / (spmm[3+d] - spmm[d] + 1e-6f) * 1023.0f;
    v = fminf(fmaxf(v, 0.0f), 1023.0f);
    g[d] = (unsigned int)(int)v;
  }
  unsigned int ca = hilbert3(g[0], g[1], g[2]);
  unsigned int cb = hilbert3(g[1], g[0], g[2]);
  keys[t]         = ((unsigned long long)ca << 14) | (unsigned long long)t;
  keys[L_TOK + t] = ((unsigned long long)cb << 14) | (unsigned long long)t;
}

// bitonic-sort each 512-key tile in LDS (64 tiles = 2 arrays x 32)
__global__ __launch_bounds__(256) void sort_tiles(const unsigned long long* __restrict__ keys,
                                                  unsigned long long* __restrict__ skeys) {
  __shared__ unsigned long long s[512];
  int b = blockIdx.x, tid = threadIdx.x;
  size_t base = (size_t)(b >> 5)*L_TOK + (size_t)(b & 31)*512;
  s[tid]       = keys[base + tid];
  s[tid + 256] = keys[base + tid + 256];
  for (unsigned int k = 2; k <= 512; k <<= 1) {
    for (unsigned int j = k >> 1; j > 0; j >>= 1) {
      __syncthreads();
      #pragma unroll
      for (int h = 0; h < 2; ++h) {
        int i = tid + 256*h;
        int ixj = i ^ (int)j;
        if (ixj > i) {
          unsigned long long a = s[i], c = s[ixj];
          bool up = ((i & (int)k) == 0);
          if (up ? (a > c) : (a < c)) { s[i] = c; s[ixj] = a; }
        }
      }
    }
  }
  __syncthreads();
  skeys[base + tid]       = s[tid];
  skeys[base + tid + 256] = s[tid + 256];
}

// rank via binary search in sorted tiles (ranks bit-identical to brute force)
__global__ __launch_bounds__(256) void rank_partial(const unsigned long long* __restrict__ keys,
                                                    const unsigned long long* __restrict__ skeys,
                                                    unsigned int* __restrict__ partial) {
  __shared__ unsigned long long tile[512];
  int arr = blockIdx.y, ks = blockIdx.z;
  const unsigned long long* k = keys + (size_t)arr * L_TOK;
  int qbase = blockIdx.x*1024 + threadIdx.x;
  unsigned long long q[4];
  #pragma unroll
  for (int i = 0; i < 4; ++i) q[i] = k[qbase + 256*i];
  const unsigned long long* src = skeys + (size_t)arr*L_TOK + ks*512;
  tile[threadIdx.x]       = src[threadIdx.x];
  tile[threadIdx.x + 256] = src[threadIdx.x + 256];
  __syncthreads();
  #pragma unroll
  for (int i = 0; i < 4; ++i) {
    unsigned int lo = 0;
    #pragma unroll
    for (unsigned int st = 256; st > 0; st >>= 1)
      if (tile[lo + st - 1] < q[i]) lo += st;
    lo += (tile[lo] < q[i]) ? 1u : 0u;
    partial[(size_t)(ks*2 + arr)*L_TOK + qbase + 256*i] = lo;
  }
}

__global__ __launch_bounds__(256) void rank_scatter(const unsigned long long* __restrict__ keys,
                                                    const unsigned int* __restrict__ partial,
                                                    unsigned int* __restrict__ ord,
                                                    unsigned int* __restrict__ inv) {
  int i = blockIdx.x*256 + threadIdx.x;
  int arr = i >> 14;
  int qi = i & (L_TOK - 1);
  unsigned int r = 0;
  #pragma unroll
  for (int ks = 0; ks < 32; ++ks) r += partial[(size_t)(ks*2 + arr)*L_TOK + qi];
  unsigned int tok = (unsigned int)(keys[i] & 0x3FFFu);
  ord[(size_t)arr*L_TOK + r] = tok;
  inv[(size_t)arr*L_TOK + tok] = r;
}

// ---------------- layernorm ----------------

__global__ __launch_bounds__(256) void ln_kernel(const float* __restrict__ in, float* __restrict__ out,
                                                 unsigned short* __restrict__ outbf,
                                                 const float* __restrict__ w, const float* __restrict__ b) {
  int row = blockIdx.x*4 + (threadIdx.x >> 6);
  int lane = threadIdx.x & 63;
  const float4 v = *(const float4*)(in + (size_t)row*DM + lane*4);
  float s = v.x + v.y + v.z + v.w;
  float mean = warp_sum(s) * (1.0f/DM);
  float4 xc = make_float4(v.x-mean, v.y-mean, v.z-mean, v.w-mean);
  float ss = xc.x*xc.x + xc.y*xc.y + xc.z*xc.z + xc.w*xc.w;
  ss = warp_sum(ss) * (1.0f/DM);
  float inv = rsqrtf(ss + EPSF);
  const float4 w4 = *(const float4*)(w + lane*4);
  const float4 b4 = *(const float4*)(b + lane*4);
  float4 o;
  o.x = xc.x*inv*w4.x + b4.x;
  o.y = xc.y*inv*w4.y + b4.y;
  o.z = xc.z*inv*w4.z + b4.z;
  o.w = xc.w*inv*w4.w + b4.w;
  *(float4*)(out + (size_t)row*DM + lane*4) = o;
  if (outbf) {
    ushort4 ob = make_ushort4(f2bf(o.x), f2bf(o.y), f2bf(o.z), f2bf(o.w));
    *(ushort4*)(outbf + (size_t)row*DM + lane*4) = ob;
  }
}

// fin-LN (in place on io) fused with next layer's pre-LN (writes qn/qnbf) in one read
__global__ __launch_bounds__(256) void lnfuse_kernel(float* __restrict__ io,
                                                     float* __restrict__ qn, unsigned short* __restrict__ qnbf,
                                                     const float* __restrict__ fw, const float* __restrict__ fb,
                                                     const float* __restrict__ pw, const float* __restrict__ pb) {
  int row = blockIdx.x*4 + (threadIdx.x >> 6);
  int lane = threadIdx.x & 63;
  const float4 v = *(const float4*)(io + (size_t)row*DM + lane*4);
  float s = v.x + v.y + v.z + v.w;
  float mean = warp_sum(s) * (1.0f/DM);
  float4 xc = make_float4(v.x-mean, v.y-mean, v.z-mean, v.w-mean);
  float ss = xc.x*xc.x + xc.y*xc.y + xc.z*xc.z + xc.w*xc.w;
  ss = warp_sum(ss) * (1.0f/DM);
  float inv = rsqrtf(ss + EPSF);
  const float4 w4 = *(const float4*)(fw + lane*4);
  const float4 b4 = *(const float4*)(fb + lane*4);
  float4 o;
  o.x = xc.x*inv*w4.x + b4.x;
  o.y = xc.y*inv*w4.y + b4.y;
  o.z = xc.z*inv*w4.z + b4.z;
  o.w = xc.w*inv*w4.w + b4.w;
  *(float4*)(io + (size_t)row*DM + lane*4) = o;
  if (qn) {
    float s2 = o.x + o.y + o.z + o.w;
    float mean2 = warp_sum(s2) * (1.0f/DM);
    float4 x2 = make_float4(o.x-mean2, o.y-mean2, o.z-mean2, o.w-mean2);
    float ss2 = x2.x*x2.x + x2.y*x2.y + x2.z*x2.z + x2.w*x2.w;
    ss2 = warp_sum(ss2) * (1.0f/DM);
    float inv2 = rsqrtf(ss2 + EPSF);
    const float4 pw4 = *(const float4*)(pw + lane*4);
    const float4 pb4 = *(const float4*)(pb + lane*4);
    float4 qv;
    qv.x = x2.x*inv2*pw4.x + pb4.x;
    qv.y = x2.y*inv2*pw4.y + pb4.y;
    qv.z = x2.z*inv2*pw4.z + pb4.z;
    qv.w = x2.w*inv2*pw4.w + pb4.w;
    *(float4*)(qn + (size_t)row*DM + lane*4) = qv;
    ushort4 qb = make_ushort4(f2bf(qv.x), f2bf(qv.y), f2bf(qv.z), f2bf(qv.w));
    *(ushort4*)(qnbf + (size_t)row*DM + lane*4) = qb;
  }
}

// ---------------- weight transpose+convert: both layers in one launch ----------------

__global__ __launch_bounds__(256) void tcvt_all(const float* __restrict__ Wi0, const float* __restrict__ Wo0,
                                                const float* __restrict__ nw0,
                                                const float* __restrict__ Wi1, const float* __restrict__ Wo1,
                                                const float* __restrict__ nw1,
                                                unsigned short* __restrict__ WtA, unsigned short* __restrict__ WtO) {
  __shared__ float lds[64*65];
  int b = blockIdx.x, tid = threadIdx.x;
  int lyr = (b >= 104) ? 1 : 0;
  b -= lyr*104;
  const float* Wi = lyr ? Wi1 : Wi0;
  const float* Wo = lyr ? Wo1 : Wo0;
  const float* nw = lyr ? nw1 : nw0;
  WtA += (size_t)lyr*1152*DM;
  WtO += (size_t)lyr*DM*DI;
  const float* src; int srcld, n0, k0t, dstld; unsigned short* dst; bool useNw;
  if (b < 72) {
    int nt = b >> 2, kt = b & 3;
    n0 = nt*64; k0t = kt*64;
    src = Wi; srcld = DP; dst = WtA; dstld = 256; useNw = false;
  } else {
    int j = b - 72;
    int nt = j >> 3, kt = j & 7;
    n0 = nt*64; k0t = kt*64;
    src = Wo; srcld = DM; dst = WtO; dstld = 512; useNw = true;
  }
  int nn = (tid & 15)*4, kk = tid >> 4;
  #pragma unroll
  for (int p = 0; p < 4; ++p) {
    int k = kk + p*16;
    float4 v = *(const float4*)(src + (size_t)(k0t + k)*srcld + n0 + nn);
    lds[k*65 + nn]   = v.x;
    lds[k*65 + nn+1] = v.y;
    lds[k*65 + nn+2] = v.z;
    lds[k*65 + nn+3] = v.w;
  }
  __syncthreads();
  int n = tid >> 2, kq = (tid & 3)*16;
  float nwv[16];
  if (useNw) {
    #pragma unroll
    for (int e = 0; e < 16; e += 4) {
      float4 t4 = *(const float4*)(nw + k0t + kq + e);
      nwv[e]=t4.x; nwv[e+1]=t4.y; nwv[e+2]=t4.z; nwv[e+3]=t4.w;
    }
  } else {
    #pragma unroll
    for (int e = 0; e < 16; ++e) nwv[e] = 1.0f;
  }
  short8 o0, o1;
  #pragma unroll
  for (int e = 0; e < 8; ++e) {
    o0[e] = (short)f2bf(lds[(kq+e)*65 + n] * nwv[e]);
    o1[e] = (short)f2bf(lds[(kq+8+e)*65 + n] * nwv[8+e]);
  }
  unsigned short* dp = dst + (size_t)(n0 + n)*dstld + k0t + kq;
  *(short8*)dp = o0;
  *(short8*)(dp + 8) = o1;
}

// ---------------- fused input GEMM: nat (gate+BC, 640 blocks) + x (Hilbert transposed, 1024 blocks) ----------------

__global__ __launch_bounds__(256) void gemm_in2(const unsigned short* __restrict__ Abf,
                                                const unsigned short* __restrict__ Wt,
                                                const unsigned int* __restrict__ ord,
                                                unsigned short* __restrict__ gate_nat,
                                                unsigned short* __restrict__ bcraw,
                                                unsigned short* __restrict__ xTg) {
  __shared__ unsigned short Alds[128*64];
  __shared__ unsigned short Blds[128*64];
  int tid = threadIdx.x, lane = tid & 63, w = tid >> 6;
  int bid = blockIdx.x;
  bool natp = bid < 640;
  int rb, cb, dir = 0, wcol0;
  if (natp) {
    int xcd = bid & 7, g = bid >> 3;
    rb = (xcd*16 + g/5)*128;
    cb = (g % 5)*128;
    wcol0 = cb;
  } else {
    int id = bid - 640;
    dir = id >> 9;
    int b = id & 511;
    int xcd = b & 7, g = b >> 3;
    rb = (xcd*16 + g/4)*128;
    cb = (g % 4)*128;
    wcol0 = DI + cb;
  }
  int wm = (w & 1)*64, wn = (w >> 1)*64;
  const unsigned int* ordp = ord + (size_t)dir*L_TOK;
  const unsigned short* pA[4]; const unsigned short* pB[4];
  unsigned short* dA[4]; unsigned short* dB[4];
  #pragma unroll
  for (int s = 0; s < 4; ++s) {
    int inst = w*4 + s;
    int r = inst*8 + (lane >> 3);
    int cA = (lane & 7) ^ (r & 7);
    int arow = natp ? (rb + r) : (int)ordp[rb + r];
    pA[s] = Abf + (size_t)arow*DM + cA*8;
    pB[s] = Wt + (size_t)(wcol0 + r)*DM + cA*8;
    dA[s] = &Alds[inst*512];
    dB[s] = &Blds[inst*512];
  }
  f32x4 zero = {0.f, 0.f, 0.f, 0.f};
  f32x4 acc[4][4];
  #pragma unroll
  for (int i = 0; i < 4; ++i)
    #pragma unroll
    for (int j = 0; j < 4; ++j) acc[i][j] = zero;
  int t = lane & 15, q = lane >> 4;
  for (int k0 = 0; k0 < DM; k0 += 64) {
    #pragma unroll
    for (int s = 0; s < 4; ++s) GLL16(pA[s] + k0, dA[s]);
    #pragma unroll
    for (int s = 0; s < 4; ++s) GLL16(pB[s] + k0, dB[s]);
    __syncthreads();
    #pragma unroll
    for (int ks = 0; ks < 2; ++ks) {
      short8 af[4], bfr[4];
      int cc = ks*4 + q;
      #pragma unroll
      for (int i = 0; i < 4; ++i) {
        int rr = wm + 16*i + t;
        af[i] = *(const short8*)&Alds[rr*64 + ((cc ^ (rr & 7))*8)];
      }
      #pragma unroll
      for (int j = 0; j < 4; ++j) {
        int rr = wn + 16*j + t;
        bfr[j] = *(const short8*)&Blds[rr*64 + ((cc ^ (rr & 7))*8)];
      }
      #pragma unroll
      for (int i = 0; i < 4; ++i)
        #pragma unroll
        for (int j = 0; j < 4; ++j)
          acc[i][j] = __builtin_amdgcn_mfma_f32_16x16x32_bf16(af[i], bfr[j], acc[i][j], 0, 0, 0);
    }
    __syncthreads();
  }
  if (natp) {
    unsigned short* dst; int ld;
    if (cb < DI) { dst = gate_nat + cb; ld = DI; }
    else         { dst = bcraw + (cb - DI); ld = 128; }
    #pragma unroll
    for (int i = 0; i < 4; ++i) {
      int rowb = rb + wm + 16*i + q*4;
      #pragma unroll
      for (int j = 0; j < 4; ++j) {
        int col = wn + 16*j + t;
        #pragma unroll
        for (int r = 0; r < 4; ++r)
          dst[(size_t)(rowb + r)*ld + col] = f2bf(acc[i][j][r]);
      }
    }
  } else {
    #pragma unroll
    for (int i = 0; i < 4; ++i) {
      int rowb = rb + wm + 16*i + q*4;
      #pragma unroll
      for (int j = 0; j < 4; ++j) {
        int col = wn + 16*j + t;
        ushort4 o = make_ushort4(f2bf(acc[i][j][0]), f2bf(acc[i][j][1]),
                                 f2bf(acc[i][j][2]), f2bf(acc[i][j][3]));
        *(ushort4*)(xTg + (size_t)(cb + col)*(2*L_TOK) + (size_t)dir*L_TOK + rowb) = o;
      }
    }
  }
}

// ---------------- gather-based out GEMM + in-kernel RMS (from A fragments) ----------------

__global__ __launch_bounds__(256) void gemm_out_gather(const unsigned short* __restrict__ ybuf,
                                                       const unsigned short* __restrict__ Wt,
                                                       const unsigned int* __restrict__ inv,
                                                       const float* __restrict__ shortcut,
                                                       float* __restrict__ out) {
  __shared__ unsigned short Alds[2*64*64];   // [dir][64 rows][64 k]
  __shared__ unsigned short Blds[128*64];
  __shared__ float sql[2][64];
  int tid = threadIdx.x, lane = tid & 63, w = tid >> 6;
  int bid = blockIdx.x;
  int xcd = bid & 7, g = bid >> 3;
  int rb = (xcd*32 + (g >> 1))*64;
  int cb = (g & 1)*128;
  int wm = (w & 1)*32, wn = (w >> 1)*64;
  bool rmsw = ((w >> 1) == 0);   // only wn==0 waves compute/publish row sums
  const unsigned short* pA0[2]; const unsigned short* pA1[2];
  unsigned short* dA0[2]; unsigned short* dA1[2];
  const unsigned short* pB[4]; unsigned short* dB[4];
  #pragma unroll
  for (int s = 0; s < 2; ++s) {
    int inst = w*2 + s;
    int r = inst*8 + (lane >> 3);
    int cA = (lane & 7) ^ (r & 7);
    int tok = rb + r;
    pA0[s] = ybuf + (size_t)inv[tok]*DI + cA*8;
    pA1[s] = ybuf + (size_t)L_TOK*DI + (size_t)inv[L_TOK + tok]*DI + cA*8;
    dA0[s] = &Alds[inst*512];
    dA1[s] = &Alds[4096 + inst*512];
  }
  #pragma unroll
  for (int s = 0; s < 4; ++s) {
    int inst = w*4 + s;
    int r = inst*8 + (lane >> 3);
    int cA = (lane & 7) ^ (r & 7);
    pB[s] = Wt + (size_t)(cb + r)*DI + cA*8;
    dB[s] = &Blds[inst*512];
  }
  f32x4 zero = {0.f, 0.f, 0.f, 0.f};
  f32x4 acc0[2][4], acc1[2][4];
  #pragma unroll
  for (int i = 0; i < 2; ++i)
    #pragma unroll
    for (int j = 0; j < 4; ++j) { acc0[i][j] = zero; acc1[i][j] = zero; }
  float sq0[2] = {0.f, 0.f}, sq1[2] = {0.f, 0.f};
  int t = lane & 15, q = lane >> 4;
  for (int k0 = 0; k0 < DI; k0 += 64) {
    #pragma unroll
    for (int s = 0; s < 2; ++s) { GLL16(pA0[s] + k0, dA0[s]); GLL16(pA1[s] + k0, dA1[s]); }
    #pragma unroll
    for (int s = 0; s < 4; ++s) GLL16(pB[s] + k0, dB[s]);
    __syncthreads();
    #pragma unroll
    for (int ks = 0; ks < 2; ++ks) {
      short8 af0[2], af1[2], bfr[4];
      int cc = ks*4 + q;
      #pragma unroll
      for (int i = 0; i < 2; ++i) {
        int rr = wm + 16*i + t;
        int off = rr*64 + ((cc ^ (rr & 7))*8);
        af0[i] = *(const short8*)&Alds[off];
        af1[i] = *(const short8*)&Alds[4096 + off];
      }
      if (rmsw) {
        #pragma unroll
        for (int i = 0; i < 2; ++i)
          #pragma unroll
          for (int e = 0; e < 8; ++e) {
            float a0 = bf2f((unsigned short)af0[i][e]);
            float a1 = bf2f((unsigned short)af1[i][e]);
            sq0[i] = fmaf(a0, a0, sq0[i]);
            sq1[i] = fmaf(a1, a1, sq1[i]);
          }
      }
      #pragma unroll
      for (int j = 0; j < 4; ++j) {
        int rr = wn + 16*j + t;
        bfr[j] = *(const short8*)&Blds[rr*64 + ((cc ^ (rr & 7))*8)];
      }
      #pragma unroll
      for (int i = 0; i < 2; ++i)
        #pragma unroll
        for (int j = 0; j < 4; ++j) {
          acc0[i][j] = __builtin_amdgcn_mfma_f32_16x16x32_bf16(af0[i], bfr[j], acc0[i][j], 0, 0, 0);
          acc1[i][j] = __builtin_amdgcn_mfma_f32_16x16x32_bf16(af1[i], bfr[j], acc1[i][j], 0, 0, 0);
        }
    }
    __syncthreads();
  }
  if (rmsw) {
    #pragma unroll
    for (int i = 0; i < 2; ++i) {
      float s0 = sq0[i];
      s0 += __shfl_xor(s0, 16, 64);
      s0 += __shfl_xor(s0, 32, 64);
      float s1 = sq1[i];
      s1 += __shfl_xor(s1, 16, 64);
      s1 += __shfl_xor(s1, 32, 64);
      if (q == 0) { sql[0][wm + 16*i + t] = s0; sql[1][wm + 16*i + t] = s1; }
    }
  }
  __syncthreads();
  #pragma unroll
  for (int i = 0; i < 2; ++i) {
    #pragma unroll
    for (int r = 0; r < 4; ++r) {
      int rl = wm + 16*i + q*4 + r;
      int row = rb + rl;
      float ir0 = rsqrtf(sql[0][rl]*(1.0f/DI) + EPSF);
      float ir1 = rsqrtf(sql[1][rl]*(1.0f/DI) + EPSF);
      const float* sp = shortcut + (size_t)row*DM + cb;
      float* op = out + (size_t)row*DM + cb;
      #pragma unroll
      for (int j = 0; j < 4; ++j) {
        int col = wn + 16*j + t;
        op[col] = sp[col] + 0.5f*(ir0*acc0[i][j][r] + ir1*acc1[i][j][r]);
      }
    }
  }
}

// ---------------- fused dt GEMV (blocks 0..511) + convBC swizzled-tile (blocks 512..1023) ----------------

__global__ __launch_bounds__(256) void dtconv(const float* __restrict__ qn, const float* __restrict__ W,
                                              const float* __restrict__ dt_bias, float* __restrict__ dtb,
                                              const unsigned short* __restrict__ bcraw,
                                              const float* __restrict__ cw, const float* __restrict__ cbias,
                                              const unsigned int* __restrict__ ord,
                                              unsigned short* __restrict__ bcswz,
                                              unsigned short* __restrict__ bcswzA) {
  __shared__ unsigned short smem[131*64];
  int tid = threadIdx.x;
  int bx = blockIdx.x;
  if (bx < 512) {
    float* Wl = (float*)smem;
    {
      const float* wp = W + (size_t)tid*DP + (DI + CD);
      float4 wa = *(const float4*)wp;
      float4 wb = *(const float4*)(wp + 4);
      int off = tid*8 + (tid >> 5)*4;
      *(float4*)&Wl[off]     = wa;
      *(float4*)&Wl[off + 4] = wb;
    }
    __syncthreads();
    int lane = tid & 63, w = tid >> 6;
    int r = bx*32 + w*8 + (lane >> 3);
    int kg = lane & 7;
    const float* qp = qn + (size_t)r*DM + kg*32;
    float acc[8] = {};
    #pragma unroll
    for (int i = 0; i < 8; ++i) {
      float4 q4 = *(const float4*)(qp + i*4);
      float qv[4] = {q4.x, q4.y, q4.z, q4.w};
      #pragma unroll
      for (int e = 0; e < 4; ++e) {
        int k = kg*32 + i*4 + e;
        int off = k*8 + kg*4;
        float4 wa = *(const float4*)&Wl[off];
        float4 wb = *(const float4*)&Wl[off + 4];
        acc[0] = fmaf(qv[e], wa.x, acc[0]);
        acc[1] = fmaf(qv[e], wa.y, acc[1]);
        acc[2] = fmaf(qv[e], wa.z, acc[2]);
        acc[3] = fmaf(qv[e], wa.w, acc[3]);
        acc[4] = fmaf(qv[e], wb.x, acc[4]);
        acc[5] = fmaf(qv[e], wb.y, acc[5]);
        acc[6] = fmaf(qv[e], wb.z, acc[6]);
        acc[7] = fmaf(qv[e], wb.w, acc[7]);
      }
    }
    #pragma unroll
    for (int h = 0; h < 8; ++h) {
      acc[h] += __shfl_xor(acc[h], 8, 64);
      acc[h] += __shfl_xor(acc[h], 16, 64);
      acc[h] += __shfl_xor(acc[h], 32, 64);
    }
    float v = 0.f;
    #pragma unroll
    for (int h = 0; h < 8; ++h) if (kg == h) v = acc[h];
    v += dt_bias[kg];
    float sp = (v > 0.0f) ? (v + log1pf(__expf(-v))) : log1pf(__expf(v));
    dtb[(size_t)r*NH + kg] = sp;
  } else {
    int cid = bx - 512;
    int half = cid & 1, ty = (cid >> 1) & 127, dir = cid >> 8;
    unsigned short* tile = smem;
    const unsigned int* ordp = ord + (size_t)dir*L_TOK;
    int ch0 = DI + half*64;
    int co0 = half*64;
    int t0 = ty*128;
    for (int cc = tid; cc < 131*8; cc += 256) {
      int r = cc >> 3, cgc = cc & 7;
      int t = t0 - 3 + r;
      short8 v = {0,0,0,0,0,0,0,0};
      if (t >= 0) v = *(const short8*)(bcraw + (size_t)ordp[t]*128 + co0 + cgc*8);
      *(short8*)&tile[r*64 + ((cgc ^ (r & 7))*8)] = v;
    }
    int cg = tid & 7, tp = tid >> 3;
    int ch = ch0 + cg*8;
    float wv[8][4];
    float bias[8];
    #pragma unroll
    for (int e = 0; e < 8; ++e) {
      float4 c4 = *(const float4*)(cw + (ch + e)*4);
      wv[e][0] = c4.x; wv[e][1] = c4.y; wv[e][2] = c4.z; wv[e][3] = c4.w;
    }
    {
      float4 b0 = *(const float4*)(cbias + ch);
      float4 b1 = *(const float4*)(cbias + ch + 4);
      bias[0]=b0.x; bias[1]=b0.y; bias[2]=b0.z; bias[3]=b0.w;
      bias[4]=b1.x; bias[5]=b1.y; bias[6]=b1.z; bias[7]=b1.w;
    }
    __syncthreads();
    #pragma unroll
    for (int tk = 0; tk < 4; ++tk) {
      int rel = tp + 32*tk;
      float acc[8];
      #pragma unroll
      for (int e = 0; e < 8; ++e) acc[e] = bias[e];
      #pragma unroll
      for (int k = 0; k < 4; ++k) {
        int r = rel + k;
        short8 v = *(const short8*)&tile[r*64 + ((cg ^ (r & 7))*8)];
        #pragma unroll
        for (int e = 0; e < 8; ++e)
          acc[e] = fmaf(wv[e][k], bf2f((unsigned short)v[e]), acc[e]);
      }
      short8 o;
      #pragma unroll
      for (int e = 0; e < 8; ++e) o[e] = (short)f2bf(fsilu(acc[e]));
      int T = t0 + rel;
      int chn = T >> 6, tl = T & 63;
      unsigned short* tb = bcswz + ((size_t)((dir*NC + chn)*2 + half))*4096;
      *(short8*)(tb + tl*64 + ((cg ^ (tl & 7))*8)) = o;
      if (half == 0) {
        unsigned short* ta = bcswzA + ((size_t)(dir*NC + chn))*4096;
        #pragma unroll
        for (int e = 0; e < 8; ++e) {
          int s5 = cg*8 + e;
          ta[s5*64 + (((tl >> 3) ^ (s5 & 7))*8) + (tl & 7)] = (unsigned short)o[e];
        }
      }
    }
  }
}

// ---------------- chunked scan (MFMA, bf16 S) ----------------
// grid = (NC, NH, 2); scan held in registers (per-wave redundant), shfl-distributed.

__global__ __launch_bounds__(256) void phaseA_mfma(const unsigned short* __restrict__ xTg,
                                                   const unsigned short* __restrict__ bcswzA,
                                                   const float* __restrict__ cw, const float* __restrict__ cbias,
                                                   const float* __restrict__ dtb, const float* __restrict__ A_log,
                                                   const unsigned int* __restrict__ ord,
                                                   unsigned short* __restrict__ S, float* __restrict__ P,
                                                   unsigned short* __restrict__ xsT) {
  int c = blockIdx.x, h = blockIdx.y, dir = blockIdx.z, tid = threadIdx.x;
  int lane = tid & 63, w = tid >> 6;
  int hh = dir*NH + h;
  __shared__ unsigned short xT[64*64];
  __shared__ unsigned short Bt[64*64];
  int c0 = c*CHUNK;
  float Ah = -expf(A_log[h]);
  const unsigned short* bA = bcswzA + ((size_t)(dir*NC + c))*4096;
  #pragma unroll
  for (int s = 0; s < 2; ++s) {
    int inst = w*2 + s;
    GLL16(bA + (size_t)inst*512 + lane*8, &Bt[inst*512]);
  }
  // per-wave redundant suffix scan of lg = dt*A (lane = t), distributed via shfl
  float wgt_r;
  {
    unsigned int tokl = ord[(size_t)dir*L_TOK + c0 + lane];
    float dtvl = dtb[(size_t)tokl*NH + h];
    float vl = dtvl*Ah;
    float sl = vl;
    #pragma unroll
    for (int d = 1; d < 64; d <<= 1) {
      float u = __shfl_down(sl, d, 64);
      sl += (lane + d < 64) ? u : 0.f;
    }
    wgt_r = dtvl*fexp(sl - vl);
    if (tid == 0) P[hh*NC + c] = fexp(sl);
  }
  int tgc = tid & 7;
  float wgt8[8];
  #pragma unroll
  for (int k = 0; k < 8; ++k) wgt8[k] = __shfl(wgt_r, tgc*8 + k, 64);
  unsigned short* xpg = xsT + ((size_t)(hh*NC + c))*4096;
  #pragma unroll
  for (int i = 0; i < 2; ++i) {
    int q = tid + 256*i;
    int p = q >> 3, tg = q & 7;
    int sw8 = (tg ^ (p & 7))*8;
    const unsigned short* xrow = xTg + (size_t)(h*HD + p)*(2*L_TOK) + (size_t)dir*L_TOK;
    int tb = c0 + tg*8;
    short8 cur = *(const short8*)(xrow + tb);
    int sh5 = __shfl_up((int)(unsigned short)cur[5], 1, 64);
    int sh6 = __shfl_up((int)(unsigned short)cur[6], 1, 64);
    int sh7 = __shfl_up((int)(unsigned short)cur[7], 1, 64);
    unsigned short b5 = 0, b6 = 0, b7 = 0;
    if (tg == 0) {
      if (tb >= 8) {
        ushort4 pv = *(const ushort4*)(xrow + tb - 4);
        b5 = pv.y; b6 = pv.z; b7 = pv.w;
      }
    } else {
      b5 = (unsigned short)sh5; b6 = (unsigned short)sh6; b7 = (unsigned short)sh7;
    }
    float4 w4 = *(const float4*)(cw + (size_t)(h*HD + p)*4);
    float bb = cbias[h*HD + p];
    float xv[11];
    xv[0] = bf2f(b5);
    xv[1] = bf2f(b6);
    xv[2] = bf2f(b7);
    #pragma unroll
    for (int k = 0; k < 8; ++k) xv[3+k] = bf2f((unsigned short)cur[k]);
    short8 raw, wtd;
    #pragma unroll
    for (int k = 0; k < 8; ++k) {
      float a = bb + w4.x*xv[k] + w4.y*xv[k+1] + w4.z*xv[k+2] + w4.w*xv[k+3];
      unsigned short rbf = f2bf(fsilu(a));
      raw[k] = (short)rbf;
      wtd[k] = (short)f2bf(bf2f(rbf)*wgt8[k]);
    }
    *(short8*)(xpg + p*64 + sw8) = raw;
    *(short8*)&xT[p*64 + sw8] = wtd;
  }
  __syncthreads();
  int t16 = lane & 15, q4 = lane >> 4;
  f32x4 zero = {0.f,0.f,0.f,0.f};
  f32x4 acc[4];
  #pragma unroll
  for (int j = 0; j < 4; ++j) acc[j] = zero;
  #pragma unroll
  for (int ks = 0; ks < 2; ++ks) {
    int rowA = 16*w + t16;
    short8 a = *(const short8*)&xT[rowA*64 + (((ks*4 + q4) ^ (rowA & 7))*8)];
    #pragma unroll
    for (int j = 0; j < 4; ++j) {
      int rowB = 16*j + t16;
      short8 b = *(const short8*)&Bt[rowB*64 + (((ks*4 + q4) ^ (rowB & 7))*8)];
      acc[j] = __builtin_amdgcn_mfma_f32_16x16x32_bf16(a, b, acc[j], 0, 0, 0);
    }
  }
  unsigned short* Sp = S + ((size_t)(hh*NC + c))*4096;
  #pragma unroll
  for (int j = 0; j < 4; ++j)
    #pragma unroll
    for (int r = 0; r < 4; ++r) {
      int row = 16*w + q4*4 + r;
      int cg2 = 2*j + (t16 >> 3);
      Sp[(size_t)row*64 + (((cg2 ^ (row & 7)) << 3) | (t16 & 7))] = f2bf(acc[j][r]);
    }
}

// ---- phaseB: single-pass in-place exclusive scan over chunks (layout-agnostic) ----

__global__ __launch_bounds__(128) void phaseB_scan(unsigned short* __restrict__ S, const float* __restrict__ P) {
  __shared__ float Pl[NC];
  int b = blockIdx.x;
  int hh = b >> 4;
  int e2 = (b & 15)*128 + threadIdx.x;
  for (int i = threadIdx.x; i < NC; i += 128) Pl[i] = P[hh*NC + i];
  __syncthreads();
  unsigned int* base = (unsigned int*)(S + ((size_t)hh*NC)*4096) + e2;
  float hx = 0.f, hy = 0.f;
  #pragma unroll 1
  for (int k0 = 0; k0 < NC; k0 += 16) {
    unsigned int v[16];
    #pragma unroll
    for (int u = 0; u < 16; ++u) v[u] = base[(size_t)(k0+u)*2048];
    #pragma unroll
    for (int u = 0; u < 16; ++u) {
      float p = Pl[k0+u];
      unsigned int old = v[u];
      base[(size_t)(k0+u)*2048] = (unsigned int)f2bf(hx) | ((unsigned int)f2bf(hy) << 16);
      hx = p*hx + bf2f((unsigned short)(old & 0xffffu));
      hy = p*hy + bf2f((unsigned short)(old >> 16));
    }
  }
}

// phaseC: grid (NC, NH, 2); scan in registers (per-wave redundant); LDS = exactly 32KB -> 5 blocks/CU.
__global__ __launch_bounds__(256) void phaseC_mfma(const unsigned short* __restrict__ bcswz,
                                                   const unsigned short* __restrict__ xsT,
                                                   const unsigned short* __restrict__ gate_nat,
                                                   const float* __restrict__ dtb, const float* __restrict__ A_log,
                                                   const float* __restrict__ Dp,
                                                   const unsigned int* __restrict__ ord,
                                                   const unsigned short* __restrict__ S,
                                                   unsigned short* __restrict__ ybuf) {
  int c = blockIdx.x, h = blockIdx.y, dir = blockIdx.z, tid = threadIdx.x;
  int lane = tid & 63, w = tid >> 6;
  int hh = dir*NH + h;
  unsigned short* y = ybuf + (size_t)dir*L_TOK*DI;
  __shared__ __align__(16) unsigned short smemT[4*4096];
  unsigned short* Cl  = smemT;            // reused as Gl after stage-1 (wave-private rows)
  unsigned short* Bl  = smemT + 4096;
  unsigned short* h0l = smemT + 8192;
  unsigned short* xT  = smemT + 12288;
  float* fT = (float*)(smemT + 8192);     // 16KB f32 overlay on h0l+xT (dead after MFMAs)
  int c0 = c*CHUNK;
  float Ah = -expf(A_log[h]);
  float Dh = Dp[h];
  const unsigned short* Sp = S + ((size_t)(hh*NC + c))*4096;
  const unsigned short* xp = xsT + ((size_t)(hh*NC + c))*4096;
  const unsigned short* Bg = bcswz + ((size_t)((dir*NC + c)*2 + 0))*4096;
  const unsigned short* Cg = bcswz + ((size_t)((dir*NC + c)*2 + 1))*4096;
  #pragma unroll
  for (int s = 0; s < 2; ++s) {
    int inst = w*2 + s;
    GLL16(Sp + (size_t)inst*512 + lane*8, &h0l[inst*512]);
    GLL16(xp + (size_t)inst*512 + lane*8, &xT[inst*512]);
    GLL16(Bg + (size_t)inst*512 + lane*8, &Bl[inst*512]);
    GLL16(Cg + (size_t)inst*512 + lane*8, &Cl[inst*512]);
  }
  // hoisted epilogue loads (independent): token + gate row-segment for this thread's row
  int erow = tid >> 2;
  int ech0 = (tid & 3) * 16;
  unsigned int etok = ord[(size_t)dir*L_TOK + c0 + erow];
  const unsigned short* gp = gate_nat + (size_t)etok*DI + h*HD + ech0;
  short8 g0 = *(const short8*)gp;
  short8 g1 = *(const short8*)(gp + 8);
  // per-wave redundant inclusive prefix scan of lg = dt*A (lane = t)
  float dts_r, pl_r, pe_r;
  {
    unsigned int tokl = ord[(size_t)dir*L_TOK + c0 + lane];
    dts_r = dtb[(size_t)tokl*NH + h];
    float vl = dts_r*Ah;
    float sl = vl;
    #pragma unroll
    for (int d = 1; d < 64; d <<= 1) {
      float u = __shfl_up(sl, d, 64);
      sl += (lane >= d) ? u : 0.f;
    }
    pl_r = sl;
    pe_r = fexp(sl);
  }
  __syncthreads();
  int t16 = lane & 15, q4 = lane >> 4;
  int t0 = 16*w;
  f32x4 zero = {0.f,0.f,0.f,0.f};
  f32x4 accG[4], accY[4];
  #pragma unroll
  for (int j = 0; j < 4; ++j) { accG[j] = zero; accY[j] = zero; }
  #pragma unroll
  for (int ks = 0; ks < 2; ++ks) {
    int rowA = t0 + t16;
    short8 a = *(const short8*)&Cl[rowA*64 + (((ks*4 + q4) ^ (rowA & 7))*8)];
    #pragma unroll
    for (int j = 0; j < 4; ++j) {
      int rowB = 16*j + t16;
      int off = rowB*64 + (((ks*4 + q4) ^ (rowB & 7))*8);
      accG[j] = __builtin_amdgcn_mfma_f32_16x16x32_bf16(a, *(const short8*)&Bl[off], accG[j], 0, 0, 0);
      accY[j] = __builtin_amdgcn_mfma_f32_16x16x32_bf16(a, *(const short8*)&h0l[off], accY[j], 0, 0, 0);
    }
  }
  // per-lane pl/pe for this wave's 4 rows
  float pl_t[4], pe_t[4];
  #pragma unroll
  for (int r = 0; r < 4; ++r) {
    int t = t0 + q4*4 + r;
    pl_t[r] = __shfl(pl_r, t, 64);
    pe_t[r] = __shfl(pe_r, t, 64);
  }
  // Gl (aliased onto Cl): wave w only touches rows [16w,16w+16), which it alone read as A-operand
  #pragma unroll
  for (int j = 0; j < 4; ++j) {
    int sidx = 16*j + t16;
    float dts_s = __shfl(dts_r, sidx, 64);
    float pl_s  = __shfl(pl_r, sidx, 64);
    #pragma unroll
    for (int r = 0; r < 4; ++r) {
      int t = t0 + q4*4 + r;
      float v = 0.f;
      if (sidx <= t) {
        v = accG[j][r] * dts_s * fexp(pl_t[r] - pl_s);
        if (sidx == t) v += Dh;
      }
      Cl[t*64 + (((sidx >> 3) ^ (t & 7))*8 + (sidx & 7))] = f2bf(v);
    }
  }
  #pragma unroll
  for (int j = 0; j < 4; ++j)
    #pragma unroll
    for (int r = 0; r < 4; ++r)
      accY[j][r] *= pe_t[r];
  #pragma unroll
  for (int ks = 0; ks < 2; ++ks) {
    int rowA = t0 + t16;
    short8 a = *(const short8*)&Cl[rowA*64 + (((ks*4 + q4) ^ (rowA & 7))*8)];
    #pragma unroll
    for (int j = 0; j < 4; ++j) {
      int rowB = 16*j + t16;
      short8 b = *(const short8*)&xT[rowB*64 + (((ks*4 + q4) ^ (rowB & 7))*8)];
      accY[j] = __builtin_amdgcn_mfma_f32_16x16x32_bf16(a, b, accY[j], 0, 0, 0);
    }
  }
  __syncthreads();   // all waves done reading h0l/xT
  // write accY into f32 overlay; swizzle: col ^= (q4<<4)
  #pragma unroll
  for (int j = 0; j < 4; ++j)
    #pragma unroll
    for (int r = 0; r < 4; ++r) {
      int t = t0 + q4*4 + r;
      int p = 16*j + t16;
      fT[t*64 + (p ^ (q4 << 4))] = accY[j][r];
    }
  __syncthreads();
  // coalesced epilogue: thread owns 16 contiguous channels of one row
  {
    int swz = ((erow >> 2) & 3) << 4;
    const float* fr = &fT[erow*64 + (ech0 ^ swz)];
    float4 a0 = *(const float4*)(fr);
    float4 a1 = *(const float4*)(fr + 4);
    float4 a2 = *(const float4*)(fr + 8);
    float4 a3 = *(const float4*)(fr + 12);
    float fv[16] = {a0.x,a0.y,a0.z,a0.w, a1.x,a1.y,a1.z,a1.w,
                    a2.x,a2.y,a2.z,a2.w, a3.x,a3.y,a3.z,a3.w};
    short8 o0, o1;
    #pragma unroll
    for (int e = 0; e < 8; ++e) {
      float v0 = fv[e]   * fsilu(bf2f((unsigned short)g0[e]));
      float v1 = fv[8+e] * fsilu(bf2f((unsigned short)g1[e]));
      o0[e] = (short)f2bf(v0);
      o1[e] = (short)f2bf(v1);
    }
    unsigned short* yp = y + (size_t)(c0 + erow)*DI + h*HD + ech0;
    *(short8*)yp = o0;
    *(short8*)(yp + 8) = o1;
  }
}

__global__ void fill_debug(float* out, float v) {
  int i = blockIdx.x*256 + threadIdx.x;
  if (i < L_TOK*DM) out[i] = v;
}

// ---------------- host ----------------

extern "C" void kernel_launch(void* const* d_in, const int* in_sizes, int n_in,
                              void* d_out, int out_size, void* d_ws, size_t ws_size,
                              hipStream_t stream) {
  const float* query = (const float*)d_in[0];
  const float* qpos  = (const float*)d_in[1];
  const float* pre_w = (const float*)d_in[2];
  const float* pre_b = (const float*)d_in[3];
  const float* fin_w = (const float*)d_in[4];
  const float* fin_b = (const float*)d_in[5];
  float* out = (float*)d_out;

  char* ws = (char*)d_ws;
  size_t off = 0;
  auto alloc = [&](size_t bytes) -> void* {
    void* p = ws + off;
    off += (bytes + 255) & ~(size_t)255;
    return p;
  };
  unsigned long long* keys = (unsigned long long*)alloc((size_t)2*L_TOK*8);
  unsigned long long* skeys = (unsigned long long*)alloc((size_t)2*L_TOK*8);
  unsigned int* ord = (unsigned int*)alloc((size_t)2*L_TOK*4);
  unsigned int* inv = (unsigned int*)alloc((size_t)2*L_TOK*4);
  unsigned int* rpart = (unsigned int*)alloc((size_t)32*2*L_TOK*4);
  float* mmpart = (float*)alloc((size_t)64*6*4);
  float* qn   = (float*)alloc((size_t)L_TOK*DM*4);
  unsigned short* qnbf = (unsigned short*)alloc((size_t)L_TOK*DM*2);
  unsigned short* gate_nat = (unsigned short*)alloc((size_t)L_TOK*DI*2);   // natural-order gate
  unsigned short* xTg    = (unsigned short*)alloc((size_t)512*2*L_TOK*2);  // raw x, transposed [ch][dir*L+t]
  unsigned short* bcraw  = (unsigned short*)alloc((size_t)L_TOK*128*2);    // raw B/C, natural token-major
  unsigned short* bcswz  = (unsigned short*)alloc((size_t)2*NC*2*4096*2);  // conv'd B/C, phaseC-layout tiles
  unsigned short* bcswzA = (unsigned short*)alloc((size_t)2*NC*4096*2);    // conv'd B, phaseA-layout tiles
  unsigned short* ybuf   = (unsigned short*)alloc((size_t)2*L_TOK*DI*2);   // gated (unnormalized) y
  float* dtb  = (float*)alloc((size_t)L_TOK*NH*4);                         // natural-order dt
  unsigned short* Sbuf = (unsigned short*)alloc((size_t)2*NH*NC*4096*2);
  unsigned short* xsT  = (unsigned short*)alloc((size_t)2*NH*NC*4096*2);   // silu(conv(x)) pre-swizzled tiles
  float* Pbuf = (float*)alloc((size_t)2*NH*NC*4);
  unsigned short* WtA = (unsigned short*)alloc((size_t)2*1152*DM*2);
  unsigned short* WtO = (unsigned short*)alloc((size_t)2*DM*DI*2);
  if (off > ws_size) {
    fill_debug<<<(L_TOK*DM + 255)/256, 256, 0, stream>>>(out, (float)(ws_size >> 20));
    return;
  }

  minmax_part<<<64, 256, 0, stream>>>(qpos, mmpart);
  hilbert_kernel<<<L_TOK/256, 256, 0, stream>>>(qpos, mmpart, keys);
  sort_tiles<<<64, 256, 0, stream>>>(keys, skeys);
  rank_partial<<<dim3(16, 2, 32), 256, 0, stream>>>(keys, skeys, rpart);
  rank_scatter<<<(2*L_TOK)/256, 256, 0, stream>>>(keys, rpart, ord, inv);
  tcvt_all<<<208, 256, 0, stream>>>((const float*)d_in[6], (const float*)d_in[13], (const float*)d_in[12],
                                    (const float*)d_in[14], (const float*)d_in[21], (const float*)d_in[20],
                                    WtA, WtO);

  for (int l = 0; l < 2; ++l) {
    int base = 6 + 8*l;
    const float* in_proj  = (const float*)d_in[base+0];
    const float* conv_w   = (const float*)d_in[base+1];
    const float* conv_b   = (const float*)d_in[base+2];
    const float* dt_bias  = (const float*)d_in[base+3];
    const float* A_log    = (const float*)d_in[base+4];
    const float* Dp       = (const float*)d_in[base+5];
    const unsigned short* WtAl = WtA + (size_t)l*1152*DM;
    const unsigned short* WtOl = WtO + (size_t)l*DM*DI;

    if (l == 0)
      ln_kernel<<<L_TOK/4, 256, 0, stream>>>(query, qn, qnbf, pre_w, pre_b);
    gemm_in2<<<1664, 256, 0, stream>>>(qnbf, WtAl, ord, gate_nat, bcraw, xTg);
    dtconv<<<1024, 256, 0, stream>>>(qn, in_proj, dt_bias, dtb,
                                     bcraw, conv_w, conv_b, ord, bcswz, bcswzA);
    phaseA_mfma<<<dim3(NC, NH, 2), 256, 0, stream>>>(xTg, bcswzA, conv_w, conv_b, dtb, A_log, ord, Sbuf, Pbuf, xsT);
    phaseB_scan<<<256, 128, 0, stream>>>(Sbuf, Pbuf);
    phaseC_mfma<<<dim3(NC, NH, 2), 256, 0, stream>>>(bcswz, xsT, gate_nat, dtb, A_log, Dp, ord, Sbuf, ybuf);
    gemm_out_gather<<<512, 256, 0, stream>>>(ybuf, WtOl, inv,
                                             l ? (const float*)out : query, out);
    if (l == 0)
      lnfuse_kernel<<<L_TOK/4, 256, 0, stream>>>(out, qn, qnbf, fin_w, fin_b, pre_w, pre_b);
    else
      lnfuse_kernel<<<L_TOK/4, 256, 0, stream>>>(out, nullptr, nullptr, fin_w, fin_b, pre_w, pre_b);
  }
}

// Round 13
// 426.412 us; speedup vs baseline: 1.0610x; 1.0295x over previous
//
#include <hip/hip_runtime.h>
#include <stdint.h>

#define L_TOK 16384
#define DM 256
#define DI 512
#define DS 64
#define NH 8
#define HD 64
#define CD 640
#define DP 1160
#define CHUNK 64
#define NC 256
#define EPSF 1e-5f

typedef __attribute__((ext_vector_type(8))) short short8;
typedef __attribute__((ext_vector_type(4))) float f32x4;

#define GLL16(gp, lp) __builtin_amdgcn_global_load_lds((const __attribute__((address_space(1))) void*)(gp), (__attribute__((address_space(3))) void*)(lp), 16, 0, 0)

__device__ __forceinline__ float warp_sum(float v) {
  v += __shfl_xor(v, 1, 64);
  v += __shfl_xor(v, 2, 64);
  v += __shfl_xor(v, 4, 64);
  v += __shfl_xor(v, 8, 64);
  v += __shfl_xor(v, 16, 64);
  v += __shfl_xor(v, 32, 64);
  return v;
}

__device__ __forceinline__ float fexp(float x) { return __expf(x); }
__device__ __forceinline__ float fsilu(float x) { return x * __builtin_amdgcn_rcpf(1.0f + __expf(-x)); }

__device__ __forceinline__ unsigned short f2bf(float f) {
  unsigned int u = __float_as_uint(f);
  unsigned int r = (u + 0x7FFFu + ((u >> 16) & 1u)) >> 16;
  return (unsigned short)r;
}
__device__ __forceinline__ float bf2f(unsigned short u) {
  return __uint_as_float(((unsigned int)u) << 16);
}

// ---------------- serialization ----------------

__global__ __launch_bounds__(256) void minmax_part(const float* __restrict__ pos, float* __restrict__ part) {
  __shared__ float sm[6][4];
  int tid = threadIdx.x;
  int t = blockIdx.x*256 + tid;
  float a = pos[t*3+0], b = pos[t*3+1], c = pos[t*3+2];
  float mn0=a, mn1=b, mn2=c, mx0=a, mx1=b, mx2=c;
  #pragma unroll
  for (int d = 1; d < 64; d <<= 1) {
    mn0=fminf(mn0,__shfl_xor(mn0,d,64));
    mn1=fminf(mn1,__shfl_xor(mn1,d,64));
    mn2=fminf(mn2,__shfl_xor(mn2,d,64));
    mx0=fmaxf(mx0,__shfl_xor(mx0,d,64));
    mx1=fmaxf(mx1,__shfl_xor(mx1,d,64));
    mx2=fmaxf(mx2,__shfl_xor(mx2,d,64));
  }
  if ((tid & 63) == 0) {
    int w = tid >> 6;
    sm[0][w]=mn0; sm[1][w]=mn1; sm[2][w]=mn2;
    sm[3][w]=mx0; sm[4][w]=mx1; sm[5][w]=mx2;
  }
  __syncthreads();
  if (tid < 6) {
    float r = sm[tid][0];
    if (tid < 3) { r=fminf(r,sm[tid][1]); r=fminf(r,sm[tid][2]); r=fminf(r,sm[tid][3]); }
    else         { r=fmaxf(r,sm[tid][1]); r=fmaxf(r,sm[tid][2]); r=fmaxf(r,sm[tid][3]); }
    part[blockIdx.x*6 + tid] = r;
  }
}

__device__ unsigned int hilbert3(unsigned int a, unsigned int b, unsigned int c) {
  unsigned int x0 = a, x1 = b, x2 = c;
  for (unsigned int Q = 512u; Q > 1u; Q >>= 1) {
    unsigned int P = Q - 1u;
    { if (x0 & Q) x0 ^= P; }
    {
      unsigned int t = (x0 ^ x1) & P;
      if (x1 & Q) { x0 ^= P; }
      else { x0 ^= t; x1 ^= t; }
    }
    {
      unsigned int t = (x0 ^ x2) & P;
      if (x2 & Q) { x0 ^= P; }
      else { x0 ^= t; x2 ^= t; }
    }
  }
  x1 ^= x0; x2 ^= x1;
  unsigned int tt = 0;
  for (unsigned int Q = 512u; Q > 1u; Q >>= 1)
    if (x2 & Q) tt ^= (Q - 1u);
  x0 ^= tt; x1 ^= tt; x2 ^= tt;
  unsigned int code = 0;
  #pragma unroll
  for (int bb = 9; bb >= 0; --bb) {
    code = (code << 1) | ((x0 >> bb) & 1u);
    code = (code << 1) | ((x1 >> bb) & 1u);
    code = (code << 1) | ((x2 >> bb) & 1u);
  }
  return code;
}

// hilbert keys; minmax finalization folded in (each block reduces the 64x6 partials)
__global__ __launch_bounds__(256) void hilbert_kernel(const float* __restrict__ pos, const float* __restrict__ part,
                                                      unsigned long long* __restrict__ keys) {
  __shared__ float spmm[6];
  int tid = threadIdx.x;
  if (tid < 64) {
    const float* p = part + tid*6;
    float mn0=p[0], mn1=p[1], mn2=p[2], mx0=p[3], mx1=p[4], mx2=p[5];
    #pragma unroll
    for (int d = 1; d < 64; d <<= 1) {
      mn0=fminf(mn0,__shfl_xor(mn0,d,64));
      mn1=fminf(mn1,__shfl_xor(mn1,d,64));
      mn2=fminf(mn2,__shfl_xor(mn2,d,64));
      mx0=fmaxf(mx0,__shfl_xor(mx0,d,64));
      mx1=fmaxf(mx1,__shfl_xor(mx1,d,64));
      mx2=fmaxf(mx2,__shfl_xor(mx2,d,64));
    }
    if (tid == 0) {
      spmm[0]=mn0; spmm[1]=mn1; spmm[2]=mn2;
      spmm[3]=mx0; spmm[4]=mx1; spmm[5]=mx2;
    }
  }
  __syncthreads();
  int t = blockIdx.x*256 + tid;
  unsigned int g[3];
  #pragma unroll
  for (int d = 0; d < 3; ++d) {
    float v = (pos[t*3+d] - spmm[d]) / (spmm[3+d] - spmm[d] + 1e-6f) * 1023.0f;
    v = fminf(fmaxf(v, 0.0f), 1023.0f);
    g[d] = (unsigned int)(int)v;
  }
  unsigned int ca = hilbert3(g[0], g[1], g[2]);
  unsigned int cb = hilbert3(g[1], g[0], g[2]);
  keys[t]         = ((unsigned long long)ca << 14) | (unsigned long long)t;
  keys[L_TOK + t] = ((unsigned long long)cb << 14) | (unsigned long long)t;
}

// bitonic-sort each 512-key tile in LDS (64 tiles = 2 arrays x 32)
__global__ __launch_bounds__(256) void sort_tiles(const unsigned long long* __restrict__ keys,
                                                  unsigned long long* __restrict__ skeys) {
  __shared__ unsigned long long s[512];
  int b = blockIdx.x, tid = threadIdx.x;
  size_t base = (size_t)(b >> 5)*L_TOK + (size_t)(b & 31)*512;
  s[tid]       = keys[base + tid];
  s[tid + 256] = keys[base + tid + 256];
  for (unsigned int k = 2; k <= 512; k <<= 1) {
    for (unsigned int j = k >> 1; j > 0; j >>= 1) {
      __syncthreads();
      #pragma unroll
      for (int h = 0; h < 2; ++h) {
        int i = tid + 256*h;
        int ixj = i ^ (int)j;
        if (ixj > i) {
          unsigned long long a = s[i], c = s[ixj];
          bool up = ((i & (int)k) == 0);
          if (up ? (a > c) : (a < c)) { s[i] = c; s[ixj] = a; }
        }
      }
    }
  }
  __syncthreads();
  skeys[base + tid]       = s[tid];
  skeys[base + tid + 256] = s[tid + 256];
}

// rank via binary search in sorted tiles (ranks bit-identical to brute force)
__global__ __launch_bounds__(256) void rank_partial(const unsigned long long* __restrict__ keys,
                                                    const unsigned long long* __restrict__ skeys,
                                                    unsigned int* __restrict__ partial) {
  __shared__ unsigned long long tile[512];
  int arr = blockIdx.y, ks = blockIdx.z;
  const unsigned long long* k = keys + (size_t)arr * L_TOK;
  int qbase = blockIdx.x*1024 + threadIdx.x;
  unsigned long long q[4];
  #pragma unroll
  for (int i = 0; i < 4; ++i) q[i] = k[qbase + 256*i];
  const unsigned long long* src = skeys + (size_t)arr*L_TOK + ks*512;
  tile[threadIdx.x]       = src[threadIdx.x];
  tile[threadIdx.x + 256] = src[threadIdx.x + 256];
  __syncthreads();
  #pragma unroll
  for (int i = 0; i < 4; ++i) {
    unsigned int lo = 0;
    #pragma unroll
    for (unsigned int st = 256; st > 0; st >>= 1)
      if (tile[lo + st - 1] < q[i]) lo += st;
    lo += (tile[lo] < q[i]) ? 1u : 0u;
    partial[(size_t)(ks*2 + arr)*L_TOK + qbase + 256*i] = lo;
  }
}

__global__ __launch_bounds__(256) void rank_scatter(const unsigned long long* __restrict__ keys,
                                                    const unsigned int* __restrict__ partial,
                                                    unsigned int* __restrict__ ord,
                                                    unsigned int* __restrict__ inv) {
  int i = blockIdx.x*256 + threadIdx.x;
  int arr = i >> 14;
  int qi = i & (L_TOK - 1);
  unsigned int r = 0;
  #pragma unroll
  for (int ks = 0; ks < 32; ++ks) r += partial[(size_t)(ks*2 + arr)*L_TOK + qi];
  unsigned int tok = (unsigned int)(keys[i] & 0x3FFFu);
  ord[(size_t)arr*L_TOK + r] = tok;
  inv[(size_t)arr*L_TOK + tok] = r;
}

// ---------------- layernorm ----------------

__global__ __launch_bounds__(256) void ln_kernel(const float* __restrict__ in, float* __restrict__ out,
                                                 unsigned short* __restrict__ outbf,
                                                 const float* __restrict__ w, const float* __restrict__ b) {
  int row = blockIdx.x*4 + (threadIdx.x >> 6);
  int lane = threadIdx.x & 63;
  const float4 v = *(const float4*)(in + (size_t)row*DM + lane*4);
  float s = v.x + v.y + v.z + v.w;
  float mean = warp_sum(s) * (1.0f/DM);
  float4 xc = make_float4(v.x-mean, v.y-mean, v.z-mean, v.w-mean);
  float ss = xc.x*xc.x + xc.y*xc.y + xc.z*xc.z + xc.w*xc.w;
  ss = warp_sum(ss) * (1.0f/DM);
  float inv = rsqrtf(ss + EPSF);
  const float4 w4 = *(const float4*)(w + lane*4);
  const float4 b4 = *(const float4*)(b + lane*4);
  float4 o;
  o.x = xc.x*inv*w4.x + b4.x;
  o.y = xc.y*inv*w4.y + b4.y;
  o.z = xc.z*inv*w4.z + b4.z;
  o.w = xc.w*inv*w4.w + b4.w;
  *(float4*)(out + (size_t)row*DM + lane*4) = o;
  if (outbf) {
    ushort4 ob = make_ushort4(f2bf(o.x), f2bf(o.y), f2bf(o.z), f2bf(o.w));
    *(ushort4*)(outbf + (size_t)row*DM + lane*4) = ob;
  }
}

// fin-LN (in place on io) fused with next layer's pre-LN (writes qn/qnbf) in one read
__global__ __launch_bounds__(256) void lnfuse_kernel(float* __restrict__ io,
                                                     float* __restrict__ qn, unsigned short* __restrict__ qnbf,
                                                     const float* __restrict__ fw, const float* __restrict__ fb,
                                                     const float* __restrict__ pw, const float* __restrict__ pb) {
  int row = blockIdx.x*4 + (threadIdx.x >> 6);
  int lane = threadIdx.x & 63;
  const float4 v = *(const float4*)(io + (size_t)row*DM + lane*4);
  float s = v.x + v.y + v.z + v.w;
  float mean = warp_sum(s) * (1.0f/DM);
  float4 xc = make_float4(v.x-mean, v.y-mean, v.z-mean, v.w-mean);
  float ss = xc.x*xc.x + xc.y*xc.y + xc.z*xc.z + xc.w*xc.w;
  ss = warp_sum(ss) * (1.0f/DM);
  float inv = rsqrtf(ss + EPSF);
  const float4 w4 = *(const float4*)(fw + lane*4);
  const float4 b4 = *(const float4*)(fb + lane*4);
  float4 o;
  o.x = xc.x*inv*w4.x + b4.x;
  o.y = xc.y*inv*w4.y + b4.y;
  o.z = xc.z*inv*w4.z + b4.z;
  o.w = xc.w*inv*w4.w + b4.w;
  *(float4*)(io + (size_t)row*DM + lane*4) = o;
  if (qn) {
    float s2 = o.x + o.y + o.z + o.w;
    float mean2 = warp_sum(s2) * (1.0f/DM);
    float4 x2 = make_float4(o.x-mean2, o.y-mean2, o.z-mean2, o.w-mean2);
    float ss2 = x2.x*x2.x + x2.y*x2.y + x2.z*x2.z + x2.w*x2.w;
    ss2 = warp_sum(ss2) * (1.0f/DM);
    float inv2 = rsqrtf(ss2 + EPSF);
    const float4 pw4 = *(const float4*)(pw + lane*4);
    const float4 pb4 = *(const float4*)(pb + lane*4);
    float4 qv;
    qv.x = x2.x*inv2*pw4.x + pb4.x;
    qv.y = x2.y*inv2*pw4.y + pb4.y;
    qv.z = x2.z*inv2*pw4.z + pb4.z;
    qv.w = x2.w*inv2*pw4.w + pb4.w;
    *(float4*)(qn + (size_t)row*DM + lane*4) = qv;
    ushort4 qb = make_ushort4(f2bf(qv.x), f2bf(qv.y), f2bf(qv.z), f2bf(qv.w));
    *(ushort4*)(qnbf + (size_t)row*DM + lane*4) = qb;
  }
}

// ---------------- weight transpose+convert: both layers in one launch ----------------

__global__ __launch_bounds__(256) void tcvt_all(const float* __restrict__ Wi0, const float* __restrict__ Wo0,
                                                const float* __restrict__ nw0,
                                                const float* __restrict__ Wi1, const float* __restrict__ Wo1,
                                                const float* __restrict__ nw1,
                                                unsigned short* __restrict__ WtA, unsigned short* __restrict__ WtO) {
  __shared__ float lds[64*65];
  int b = blockIdx.x, tid = threadIdx.x;
  int lyr = (b >= 104) ? 1 : 0;
  b -= lyr*104;
  const float* Wi = lyr ? Wi1 : Wi0;
  const float* Wo = lyr ? Wo1 : Wo0;
  const float* nw = lyr ? nw1 : nw0;
  WtA += (size_t)lyr*1152*DM;
  WtO += (size_t)lyr*DM*DI;
  const float* src; int srcld, n0, k0t, dstld; unsigned short* dst; bool useNw;
  if (b < 72) {
    int nt = b >> 2, kt = b & 3;
    n0 = nt*64; k0t = kt*64;
    src = Wi; srcld = DP; dst = WtA; dstld = 256; useNw = false;
  } else {
    int j = b - 72;
    int nt = j >> 3, kt = j & 7;
    n0 = nt*64; k0t = kt*64;
    src = Wo; srcld = DM; dst = WtO; dstld = 512; useNw = true;
  }
  int nn = (tid & 15)*4, kk = tid >> 4;
  #pragma unroll
  for (int p = 0; p < 4; ++p) {
    int k = kk + p*16;
    float4 v = *(const float4*)(src + (size_t)(k0t + k)*srcld + n0 + nn);
    lds[k*65 + nn]   = v.x;
    lds[k*65 + nn+1] = v.y;
    lds[k*65 + nn+2] = v.z;
    lds[k*65 + nn+3] = v.w;
  }
  __syncthreads();
  int n = tid >> 2, kq = (tid & 3)*16;
  float nwv[16];
  if (useNw) {
    #pragma unroll
    for (int e = 0; e < 16; e += 4) {
      float4 t4 = *(const float4*)(nw + k0t + kq + e);
      nwv[e]=t4.x; nwv[e+1]=t4.y; nwv[e+2]=t4.z; nwv[e+3]=t4.w;
    }
  } else {
    #pragma unroll
    for (int e = 0; e < 16; ++e) nwv[e] = 1.0f;
  }
  short8 o0, o1;
  #pragma unroll
  for (int e = 0; e < 8; ++e) {
    o0[e] = (short)f2bf(lds[(kq+e)*65 + n] * nwv[e]);
    o1[e] = (short)f2bf(lds[(kq+8+e)*65 + n] * nwv[8+e]);
  }
  unsigned short* dp = dst + (size_t)(n0 + n)*dstld + k0t + kq;
  *(short8*)dp = o0;
  *(short8*)(dp + 8) = o1;
}

// ---------------- fused input GEMM: nat (gate+BC, 640 blocks) + x (Hilbert transposed, 1024 blocks) ----------------

__global__ __launch_bounds__(256) void gemm_in2(const unsigned short* __restrict__ Abf,
                                                const unsigned short* __restrict__ Wt,
                                                const unsigned int* __restrict__ ord,
                                                unsigned short* __restrict__ gate_nat,
                                                unsigned short* __restrict__ bcraw,
                                                unsigned short* __restrict__ xTg) {
  __shared__ unsigned short Alds[128*64];
  __shared__ unsigned short Blds[128*64];
  int tid = threadIdx.x, lane = tid & 63, w = tid >> 6;
  int bid = blockIdx.x;
  bool natp = bid < 640;
  int rb, cb, dir = 0, wcol0;
  if (natp) {
    int xcd = bid & 7, g = bid >> 3;
    rb = (xcd*16 + g/5)*128;
    cb = (g % 5)*128;
    wcol0 = cb;
  } else {
    int id = bid - 640;
    dir = id >> 9;
    int b = id & 511;
    int xcd = b & 7, g = b >> 3;
    rb = (xcd*16 + g/4)*128;
    cb = (g % 4)*128;
    wcol0 = DI + cb;
  }
  int wm = (w & 1)*64, wn = (w >> 1)*64;
  const unsigned int* ordp = ord + (size_t)dir*L_TOK;
  const unsigned short* pA[4]; const unsigned short* pB[4];
  unsigned short* dA[4]; unsigned short* dB[4];
  #pragma unroll
  for (int s = 0; s < 4; ++s) {
    int inst = w*4 + s;
    int r = inst*8 + (lane >> 3);
    int cA = (lane & 7) ^ (r & 7);
    int arow = natp ? (rb + r) : (int)ordp[rb + r];
    pA[s] = Abf + (size_t)arow*DM + cA*8;
    pB[s] = Wt + (size_t)(wcol0 + r)*DM + cA*8;
    dA[s] = &Alds[inst*512];
    dB[s] = &Blds[inst*512];
  }
  f32x4 zero = {0.f, 0.f, 0.f, 0.f};
  f32x4 acc[4][4];
  #pragma unroll
  for (int i = 0; i < 4; ++i)
    #pragma unroll
    for (int j = 0; j < 4; ++j) acc[i][j] = zero;
  int t = lane & 15, q = lane >> 4;
  for (int k0 = 0; k0 < DM; k0 += 64) {
    #pragma unroll
    for (int s = 0; s < 4; ++s) GLL16(pA[s] + k0, dA[s]);
    #pragma unroll
    for (int s = 0; s < 4; ++s) GLL16(pB[s] + k0, dB[s]);
    __syncthreads();
    #pragma unroll
    for (int ks = 0; ks < 2; ++ks) {
      short8 af[4], bfr[4];
      int cc = ks*4 + q;
      #pragma unroll
      for (int i = 0; i < 4; ++i) {
        int rr = wm + 16*i + t;
        af[i] = *(const short8*)&Alds[rr*64 + ((cc ^ (rr & 7))*8)];
      }
      #pragma unroll
      for (int j = 0; j < 4; ++j) {
        int rr = wn + 16*j + t;
        bfr[j] = *(const short8*)&Blds[rr*64 + ((cc ^ (rr & 7))*8)];
      }
      #pragma unroll
      for (int i = 0; i < 4; ++i)
        #pragma unroll
        for (int j = 0; j < 4; ++j)
          acc[i][j] = __builtin_amdgcn_mfma_f32_16x16x32_bf16(af[i], bfr[j], acc[i][j], 0, 0, 0);
    }
    __syncthreads();
  }
  if (natp) {
    unsigned short* dst; int ld;
    if (cb < DI) { dst = gate_nat + cb; ld = DI; }
    else         { dst = bcraw + (cb - DI); ld = 128; }
    #pragma unroll
    for (int i = 0; i < 4; ++i) {
      int rowb = rb + wm + 16*i + q*4;
      #pragma unroll
      for (int j = 0; j < 4; ++j) {
        int col = wn + 16*j + t;
        #pragma unroll
        for (int r = 0; r < 4; ++r)
          dst[(size_t)(rowb + r)*ld + col] = f2bf(acc[i][j][r]);
      }
    }
  } else {
    #pragma unroll
    for (int i = 0; i < 4; ++i) {
      int rowb = rb + wm + 16*i + q*4;
      #pragma unroll
      for (int j = 0; j < 4; ++j) {
        int col = wn + 16*j + t;
        ushort4 o = make_ushort4(f2bf(acc[i][j][0]), f2bf(acc[i][j][1]),
                                 f2bf(acc[i][j][2]), f2bf(acc[i][j][3]));
        *(ushort4*)(xTg + (size_t)(cb + col)*(2*L_TOK) + (size_t)dir*L_TOK + rowb) = o;
      }
    }
  }
}

// ---------------- gather-based out GEMM + in-kernel RMS (from A fragments) ----------------
// sql aliased onto Alds (dead after K-loop) -> LDS exactly 32KB -> 5 blocks/CU.

__global__ __launch_bounds__(256) void gemm_out_gather(const unsigned short* __restrict__ ybuf,
                                                       const unsigned short* __restrict__ Wt,
                                                       const unsigned int* __restrict__ inv,
                                                       const float* __restrict__ shortcut,
                                                       float* __restrict__ out) {
  __shared__ __align__(16) unsigned short Alds[2*64*64];   // [dir][64 rows][64 k]; epilogue: aliased as sql[128]
  __shared__ unsigned short Blds[128*64];
  float* sql = (float*)Alds;   // [2][64] row sums; written only after final K-loop barrier
  int tid = threadIdx.x, lane = tid & 63, w = tid >> 6;
  int bid = blockIdx.x;
  int xcd = bid & 7, g = bid >> 3;
  int rb = (xcd*32 + (g >> 1))*64;
  int cb = (g & 1)*128;
  int wm = (w & 1)*32, wn = (w >> 1)*64;
  bool rmsw = ((w >> 1) == 0);   // only wn==0 waves compute/publish row sums
  const unsigned short* pA0[2]; const unsigned short* pA1[2];
  unsigned short* dA0[2]; unsigned short* dA1[2];
  const unsigned short* pB[4]; unsigned short* dB[4];
  #pragma unroll
  for (int s = 0; s < 2; ++s) {
    int inst = w*2 + s;
    int r = inst*8 + (lane >> 3);
    int cA = (lane & 7) ^ (r & 7);
    int tok = rb + r;
    pA0[s] = ybuf + (size_t)inv[tok]*DI + cA*8;
    pA1[s] = ybuf + (size_t)L_TOK*DI + (size_t)inv[L_TOK + tok]*DI + cA*8;
    dA0[s] = &Alds[inst*512];
    dA1[s] = &Alds[4096 + inst*512];
  }
  #pragma unroll
  for (int s = 0; s < 4; ++s) {
    int inst = w*4 + s;
    int r = inst*8 + (lane >> 3);
    int cA = (lane & 7) ^ (r & 7);
    pB[s] = Wt + (size_t)(cb + r)*DI + cA*8;
    dB[s] = &Blds[inst*512];
  }
  f32x4 zero = {0.f, 0.f, 0.f, 0.f};
  f32x4 acc0[2][4], acc1[2][4];
  #pragma unroll
  for (int i = 0; i < 2; ++i)
    #pragma unroll
    for (int j = 0; j < 4; ++j) { acc0[i][j] = zero; acc1[i][j] = zero; }
  float sq0[2] = {0.f, 0.f}, sq1[2] = {0.f, 0.f};
  int t = lane & 15, q = lane >> 4;
  for (int k0 = 0; k0 < DI; k0 += 64) {
    #pragma unroll
    for (int s = 0; s < 2; ++s) { GLL16(pA0[s] + k0, dA0[s]); GLL16(pA1[s] + k0, dA1[s]); }
    #pragma unroll
    for (int s = 0; s < 4; ++s) GLL16(pB[s] + k0, dB[s]);
    __syncthreads();
    #pragma unroll
    for (int ks = 0; ks < 2; ++ks) {
      short8 af0[2], af1[2], bfr[4];
      int cc = ks*4 + q;
      #pragma unroll
      for (int i = 0; i < 2; ++i) {
        int rr = wm + 16*i + t;
        int off = rr*64 + ((cc ^ (rr & 7))*8);
        af0[i] = *(const short8*)&Alds[off];
        af1[i] = *(const short8*)&Alds[4096 + off];
      }
      if (rmsw) {
        #pragma unroll
        for (int i = 0; i < 2; ++i)
          #pragma unroll
          for (int e = 0; e < 8; ++e) {
            float a0 = bf2f((unsigned short)af0[i][e]);
            float a1 = bf2f((unsigned short)af1[i][e]);
            sq0[i] = fmaf(a0, a0, sq0[i]);
            sq1[i] = fmaf(a1, a1, sq1[i]);
          }
      }
      #pragma unroll
      for (int j = 0; j < 4; ++j) {
        int rr = wn + 16*j + t;
        bfr[j] = *(const short8*)&Blds[rr*64 + ((cc ^ (rr & 7))*8)];
      }
      #pragma unroll
      for (int i = 0; i < 2; ++i)
        #pragma unroll
        for (int j = 0; j < 4; ++j) {
          acc0[i][j] = __builtin_amdgcn_mfma_f32_16x16x32_bf16(af0[i], bfr[j], acc0[i][j], 0, 0, 0);
          acc1[i][j] = __builtin_amdgcn_mfma_f32_16x16x32_bf16(af1[i], bfr[j], acc1[i][j], 0, 0, 0);
        }
    }
    __syncthreads();   // final iteration: all Alds reads complete -> safe to alias as sql
  }
  if (rmsw) {
    #pragma unroll
    for (int i = 0; i < 2; ++i) {
      float s0 = sq0[i];
      s0 += __shfl_xor(s0, 16, 64);
      s0 += __shfl_xor(s0, 32, 64);
      float s1 = sq1[i];
      s1 += __shfl_xor(s1, 16, 64);
      s1 += __shfl_xor(s1, 32, 64);
      if (q == 0) { sql[wm + 16*i + t] = s0; sql[64 + wm + 16*i + t] = s1; }
    }
  }
  __syncthreads();
  #pragma unroll
  for (int i = 0; i < 2; ++i) {
    #pragma unroll
    for (int r = 0; r < 4; ++r) {
      int rl = wm + 16*i + q*4 + r;
      int row = rb + rl;
      float ir0 = rsqrtf(sql[rl]*(1.0f/DI) + EPSF);
      float ir1 = rsqrtf(sql[64 + rl]*(1.0f/DI) + EPSF);
      const float* sp = shortcut + (size_t)row*DM + cb;
      float* op = out + (size_t)row*DM + cb;
      #pragma unroll
      for (int j = 0; j < 4; ++j) {
        int col = wn + 16*j + t;
        op[col] = sp[col] + 0.5f*(ir0*acc0[i][j][r] + ir1*acc1[i][j][r]);
      }
    }
  }
}

// ---------------- fused dt GEMV (blocks 0..511) + convBC swizzled-tile (blocks 512..1023) ----------------

__global__ __launch_bounds__(256) void dtconv(const float* __restrict__ qn, const float* __restrict__ W,
                                              const float* __restrict__ dt_bias, float* __restrict__ dtb,
                                              const unsigned short* __restrict__ bcraw,
                                              const float* __restrict__ cw, const float* __restrict__ cbias,
                                              const unsigned int* __restrict__ ord,
                                              unsigned short* __restrict__ bcswz,
                                              unsigned short* __restrict__ bcswzA) {
  __shared__ unsigned short smem[131*64];
  int tid = threadIdx.x;
  int bx = blockIdx.x;
  if (bx < 512) {
    float* Wl = (float*)smem;
    {
      const float* wp = W + (size_t)tid*DP + (DI + CD);
      float4 wa = *(const float4*)wp;
      float4 wb = *(const float4*)(wp + 4);
      int off = tid*8 + (tid >> 5)*4;
      *(float4*)&Wl[off]     = wa;
      *(float4*)&Wl[off + 4] = wb;
    }
    __syncthreads();
    int lane = tid & 63, w = tid >> 6;
    int r = bx*32 + w*8 + (lane >> 3);
    int kg = lane & 7;
    const float* qp = qn + (size_t)r*DM + kg*32;
    float acc[8] = {};
    #pragma unroll
    for (int i = 0; i < 8; ++i) {
      float4 q4 = *(const float4*)(qp + i*4);
      float qv[4] = {q4.x, q4.y, q4.z, q4.w};
      #pragma unroll
      for (int e = 0; e < 4; ++e) {
        int k = kg*32 + i*4 + e;
        int off = k*8 + kg*4;
        float4 wa = *(const float4*)&Wl[off];
        float4 wb = *(const float4*)&Wl[off + 4];
        acc[0] = fmaf(qv[e], wa.x, acc[0]);
        acc[1] = fmaf(qv[e], wa.y, acc[1]);
        acc[2] = fmaf(qv[e], wa.z, acc[2]);
        acc[3] = fmaf(qv[e], wa.w, acc[3]);
        acc[4] = fmaf(qv[e], wb.x, acc[4]);
        acc[5] = fmaf(qv[e], wb.y, acc[5]);
        acc[6] = fmaf(qv[e], wb.z, acc[6]);
        acc[7] = fmaf(qv[e], wb.w, acc[7]);
      }
    }
    #pragma unroll
    for (int h = 0; h < 8; ++h) {
      acc[h] += __shfl_xor(acc[h], 8, 64);
      acc[h] += __shfl_xor(acc[h], 16, 64);
      acc[h] += __shfl_xor(acc[h], 32, 64);
    }
    float v = 0.f;
    #pragma unroll
    for (int h = 0; h < 8; ++h) if (kg == h) v = acc[h];
    v += dt_bias[kg];
    float sp = (v > 0.0f) ? (v + log1pf(__expf(-v))) : log1pf(__expf(v));
    dtb[(size_t)r*NH + kg] = sp;
  } else {
    int cid = bx - 512;
    int half = cid & 1, ty = (cid >> 1) & 127, dir = cid >> 8;
    unsigned short* tile = smem;
    const unsigned int* ordp = ord + (size_t)dir*L_TOK;
    int ch0 = DI + half*64;
    int co0 = half*64;
    int t0 = ty*128;
    for (int cc = tid; cc < 131*8; cc += 256) {
      int r = cc >> 3, cgc = cc & 7;
      int t = t0 - 3 + r;
      short8 v = {0,0,0,0,0,0,0,0};
      if (t >= 0) v = *(const short8*)(bcraw + (size_t)ordp[t]*128 + co0 + cgc*8);
      *(short8*)&tile[r*64 + ((cgc ^ (r & 7))*8)] = v;
    }
    int cg = tid & 7, tp = tid >> 3;
    int ch = ch0 + cg*8;
    float wv[8][4];
    float bias[8];
    #pragma unroll
    for (int e = 0; e < 8; ++e) {
      float4 c4 = *(const float4*)(cw + (ch + e)*4);
      wv[e][0] = c4.x; wv[e][1] = c4.y; wv[e][2] = c4.z; wv[e][3] = c4.w;
    }
    {
      float4 b0 = *(const float4*)(cbias + ch);
      float4 b1 = *(const float4*)(cbias + ch + 4);
      bias[0]=b0.x; bias[1]=b0.y; bias[2]=b0.z; bias[3]=b0.w;
      bias[4]=b1.x; bias[5]=b1.y; bias[6]=b1.z; bias[7]=b1.w;
    }
    __syncthreads();
    #pragma unroll
    for (int tk = 0; tk < 4; ++tk) {
      int rel = tp + 32*tk;
      float acc[8];
      #pragma unroll
      for (int e = 0; e < 8; ++e) acc[e] = bias[e];
      #pragma unroll
      for (int k = 0; k < 4; ++k) {
        int r = rel + k;
        short8 v = *(const short8*)&tile[r*64 + ((cg ^ (r & 7))*8)];
        #pragma unroll
        for (int e = 0; e < 8; ++e)
          acc[e] = fmaf(wv[e][k], bf2f((unsigned short)v[e]), acc[e]);
      }
      short8 o;
      #pragma unroll
      for (int e = 0; e < 8; ++e) o[e] = (short)f2bf(fsilu(acc[e]));
      int T = t0 + rel;
      int chn = T >> 6, tl = T & 63;
      unsigned short* tb = bcswz + ((size_t)((dir*NC + chn)*2 + half))*4096;
      *(short8*)(tb + tl*64 + ((cg ^ (tl & 7))*8)) = o;
      if (half == 0) {
        unsigned short* ta = bcswzA + ((size_t)(dir*NC + chn))*4096;
        #pragma unroll
        for (int e = 0; e < 8; ++e) {
          int s5 = cg*8 + e;
          ta[s5*64 + (((tl >> 3) ^ (s5 & 7))*8) + (tl & 7)] = (unsigned short)o[e];
        }
      }
    }
  }
}

// ---------------- chunked scan (MFMA, bf16 S) ----------------
// grid = (NC, NH, 2); scan held in registers (per-wave redundant), shfl-distributed.

__global__ __launch_bounds__(256) void phaseA_mfma(const unsigned short* __restrict__ xTg,
                                                   const unsigned short* __restrict__ bcswzA,
                                                   const float* __restrict__ cw, const float* __restrict__ cbias,
                                                   const float* __restrict__ dtb, const float* __restrict__ A_log,
                                                   const unsigned int* __restrict__ ord,
                                                   unsigned short* __restrict__ S, float* __restrict__ P,
                                                   unsigned short* __restrict__ xsT) {
  int c = blockIdx.x, h = blockIdx.y, dir = blockIdx.z, tid = threadIdx.x;
  int lane = tid & 63, w = tid >> 6;
  int hh = dir*NH + h;
  __shared__ unsigned short xT[64*64];
  __shared__ unsigned short Bt[64*64];
  int c0 = c*CHUNK;
  float Ah = -expf(A_log[h]);
  const unsigned short* bA = bcswzA + ((size_t)(dir*NC + c))*4096;
  #pragma unroll
  for (int s = 0; s < 2; ++s) {
    int inst = w*2 + s;
    GLL16(bA + (size_t)inst*512 + lane*8, &Bt[inst*512]);
  }
  // per-wave redundant suffix scan of lg = dt*A (lane = t), distributed via shfl
  float wgt_r;
  {
    unsigned int tokl = ord[(size_t)dir*L_TOK + c0 + lane];
    float dtvl = dtb[(size_t)tokl*NH + h];
    float vl = dtvl*Ah;
    float sl = vl;
    #pragma unroll
    for (int d = 1; d < 64; d <<= 1) {
      float u = __shfl_down(sl, d, 64);
      sl += (lane + d < 64) ? u : 0.f;
    }
    wgt_r = dtvl*fexp(sl - vl);
    if (tid == 0) P[hh*NC + c] = fexp(sl);
  }
  int tgc = tid & 7;
  float wgt8[8];
  #pragma unroll
  for (int k = 0; k < 8; ++k) wgt8[k] = __shfl(wgt_r, tgc*8 + k, 64);
  unsigned short* xpg = xsT + ((size_t)(hh*NC + c))*4096;
  #pragma unroll
  for (int i = 0; i < 2; ++i) {
    int q = tid + 256*i;
    int p = q >> 3, tg = q & 7;
    int sw8 = (tg ^ (p & 7))*8;
    const unsigned short* xrow = xTg + (size_t)(h*HD + p)*(2*L_TOK) + (size_t)dir*L_TOK;
    int tb = c0 + tg*8;
    short8 cur = *(const short8*)(xrow + tb);
    int sh5 = __shfl_up((int)(unsigned short)cur[5], 1, 64);
    int sh6 = __shfl_up((int)(unsigned short)cur[6], 1, 64);
    int sh7 = __shfl_up((int)(unsigned short)cur[7], 1, 64);
    unsigned short b5 = 0, b6 = 0, b7 = 0;
    if (tg == 0) {
      if (tb >= 8) {
        ushort4 pv = *(const ushort4*)(xrow + tb - 4);
        b5 = pv.y; b6 = pv.z; b7 = pv.w;
      }
    } else {
      b5 = (unsigned short)sh5; b6 = (unsigned short)sh6; b7 = (unsigned short)sh7;
    }
    float4 w4 = *(const float4*)(cw + (size_t)(h*HD + p)*4);
    float bb = cbias[h*HD + p];
    float xv[11];
    xv[0] = bf2f(b5);
    xv[1] = bf2f(b6);
    xv[2] = bf2f(b7);
    #pragma unroll
    for (int k = 0; k < 8; ++k) xv[3+k] = bf2f((unsigned short)cur[k]);
    short8 raw, wtd;
    #pragma unroll
    for (int k = 0; k < 8; ++k) {
      float a = bb + w4.x*xv[k] + w4.y*xv[k+1] + w4.z*xv[k+2] + w4.w*xv[k+3];
      unsigned short rbf = f2bf(fsilu(a));
      raw[k] = (short)rbf;
      wtd[k] = (short)f2bf(bf2f(rbf)*wgt8[k]);
    }
    *(short8*)(xpg + p*64 + sw8) = raw;
    *(short8*)&xT[p*64 + sw8] = wtd;
  }
  __syncthreads();
  int t16 = lane & 15, q4 = lane >> 4;
  f32x4 zero = {0.f,0.f,0.f,0.f};
  f32x4 acc[4];
  #pragma unroll
  for (int j = 0; j < 4; ++j) acc[j] = zero;
  #pragma unroll
  for (int ks = 0; ks < 2; ++ks) {
    int rowA = 16*w + t16;
    short8 a = *(const short8*)&xT[rowA*64 + (((ks*4 + q4) ^ (rowA & 7))*8)];
    #pragma unroll
    for (int j = 0; j < 4; ++j) {
      int rowB = 16*j + t16;
      short8 b = *(const short8*)&Bt[rowB*64 + (((ks*4 + q4) ^ (rowB & 7))*8)];
      acc[j] = __builtin_amdgcn_mfma_f32_16x16x32_bf16(a, b, acc[j], 0, 0, 0);
    }
  }
  unsigned short* Sp = S + ((size_t)(hh*NC + c))*4096;
  #pragma unroll
  for (int j = 0; j < 4; ++j)
    #pragma unroll
    for (int r = 0; r < 4; ++r) {
      int row = 16*w + q4*4 + r;
      int cg2 = 2*j + (t16 >> 3);
      Sp[(size_t)row*64 + (((cg2 ^ (row & 7)) << 3) | (t16 & 7))] = f2bf(acc[j][r]);
    }
}

// ---- phaseB: single-pass in-place exclusive scan over chunks (layout-agnostic) ----

__global__ __launch_bounds__(128) void phaseB_scan(unsigned short* __restrict__ S, const float* __restrict__ P) {
  __shared__ float Pl[NC];
  int b = blockIdx.x;
  int hh = b >> 4;
  int e2 = (b & 15)*128 + threadIdx.x;
  for (int i = threadIdx.x; i < NC; i += 128) Pl[i] = P[hh*NC + i];
  __syncthreads();
  unsigned int* base = (unsigned int*)(S + ((size_t)hh*NC)*4096) + e2;
  float hx = 0.f, hy = 0.f;
  #pragma unroll 1
  for (int k0 = 0; k0 < NC; k0 += 16) {
    unsigned int v[16];
    #pragma unroll
    for (int u = 0; u < 16; ++u) v[u] = base[(size_t)(k0+u)*2048];
    #pragma unroll
    for (int u = 0; u < 16; ++u) {
      float p = Pl[k0+u];
      unsigned int old = v[u];
      base[(size_t)(k0+u)*2048] = (unsigned int)f2bf(hx) | ((unsigned int)f2bf(hy) << 16);
      hx = p*hx + bf2f((unsigned short)(old & 0xffffu));
      hy = p*hy + bf2f((unsigned short)(old >> 16));
    }
  }
}

// phaseC: grid (NC, NH, 2); scan in registers (per-wave redundant); LDS = exactly 32KB -> 5 blocks/CU.
__global__ __launch_bounds__(256) void phaseC_mfma(const unsigned short* __restrict__ bcswz,
                                                   const unsigned short* __restrict__ xsT,
                                                   const unsigned short* __restrict__ gate_nat,
                                                   const float* __restrict__ dtb, const float* __restrict__ A_log,
                                                   const float* __restrict__ Dp,
                                                   const unsigned int* __restrict__ ord,
                                                   const unsigned short* __restrict__ S,
                                                   unsigned short* __restrict__ ybuf) {
  int c = blockIdx.x, h = blockIdx.y, dir = blockIdx.z, tid = threadIdx.x;
  int lane = tid & 63, w = tid >> 6;
  int hh = dir*NH + h;
  unsigned short* y = ybuf + (size_t)dir*L_TOK*DI;
  __shared__ __align__(16) unsigned short smemT[4*4096];
  unsigned short* Cl  = smemT;            // reused as Gl after stage-1 (wave-private rows)
  unsigned short* Bl  = smemT + 4096;
  unsigned short* h0l = smemT + 8192;
  unsigned short* xT  = smemT + 12288;
  float* fT = (float*)(smemT + 8192);     // 16KB f32 overlay on h0l+xT (dead after MFMAs)
  int c0 = c*CHUNK;
  float Ah = -expf(A_log[h]);
  float Dh = Dp[h];
  const unsigned short* Sp = S + ((size_t)(hh*NC + c))*4096;
  const unsigned short* xp = xsT + ((size_t)(hh*NC + c))*4096;
  const unsigned short* Bg = bcswz + ((size_t)((dir*NC + c)*2 + 0))*4096;
  const unsigned short* Cg = bcswz + ((size_t)((dir*NC + c)*2 + 1))*4096;
  #pragma unroll
  for (int s = 0; s < 2; ++s) {
    int inst = w*2 + s;
    GLL16(Sp + (size_t)inst*512 + lane*8, &h0l[inst*512]);
    GLL16(xp + (size_t)inst*512 + lane*8, &xT[inst*512]);
    GLL16(Bg + (size_t)inst*512 + lane*8, &Bl[inst*512]);
    GLL16(Cg + (size_t)inst*512 + lane*8, &Cl[inst*512]);
  }
  // hoisted epilogue loads (independent): token + gate row-segment for this thread's row
  int erow = tid >> 2;
  int ech0 = (tid & 3) * 16;
  unsigned int etok = ord[(size_t)dir*L_TOK + c0 + erow];
  const unsigned short* gp = gate_nat + (size_t)etok*DI + h*HD + ech0;
  short8 g0 = *(const short8*)gp;
  short8 g1 = *(const short8*)(gp + 8);
  // per-wave redundant inclusive prefix scan of lg = dt*A (lane = t)
  float dts_r, pl_r, pe_r;
  {
    unsigned int tokl = ord[(size_t)dir*L_TOK + c0 + lane];
    dts_r = dtb[(size_t)tokl*NH + h];
    float vl = dts_r*Ah;
    float sl = vl;
    #pragma unroll
    for (int d = 1; d < 64; d <<= 1) {
      float u = __shfl_up(sl, d, 64);
      sl += (lane >= d) ? u : 0.f;
    }
    pl_r = sl;
    pe_r = fexp(sl);
  }
  __syncthreads();
  int t16 = lane & 15, q4 = lane >> 4;
  int t0 = 16*w;
  f32x4 zero = {0.f,0.f,0.f,0.f};
  f32x4 accG[4], accY[4];
  #pragma unroll
  for (int j = 0; j < 4; ++j) { accG[j] = zero; accY[j] = zero; }
  #pragma unroll
  for (int ks = 0; ks < 2; ++ks) {
    int rowA = t0 + t16;
    short8 a = *(const short8*)&Cl[rowA*64 + (((ks*4 + q4) ^ (rowA & 7))*8)];
    #pragma unroll
    for (int j = 0; j < 4; ++j) {
      int rowB = 16*j + t16;
      int off = rowB*64 + (((ks*4 + q4) ^ (rowB & 7))*8);
      accG[j] = __builtin_amdgcn_mfma_f32_16x16x32_bf16(a, *(const short8*)&Bl[off], accG[j], 0, 0, 0);
      accY[j] = __builtin_amdgcn_mfma_f32_16x16x32_bf16(a, *(const short8*)&h0l[off], accY[j], 0, 0, 0);
    }
  }
  // per-lane pl/pe for this wave's 4 rows
  float pl_t[4], pe_t[4];
  #pragma unroll
  for (int r = 0; r < 4; ++r) {
    int t = t0 + q4*4 + r;
    pl_t[r] = __shfl(pl_r, t, 64);
    pe_t[r] = __shfl(pe_r, t, 64);
  }
  // Gl (aliased onto Cl): wave w only touches rows [16w,16w+16), which it alone read as A-operand
  #pragma unroll
  for (int j = 0; j < 4; ++j) {
    int sidx = 16*j + t16;
    float dts_s = __shfl(dts_r, sidx, 64);
    float pl_s  = __shfl(pl_r, sidx, 64);
    #pragma unroll
    for (int r = 0; r < 4; ++r) {
      int t = t0 + q4*4 + r;
      float v = 0.f;
      if (sidx <= t) {
        v = accG[j][r] * dts_s * fexp(pl_t[r] - pl_s);
        if (sidx == t) v += Dh;
      }
      Cl[t*64 + (((sidx >> 3) ^ (t & 7))*8 + (sidx & 7))] = f2bf(v);
    }
  }
  #pragma unroll
  for (int j = 0; j < 4; ++j)
    #pragma unroll
    for (int r = 0; r < 4; ++r)
      accY[j][r] *= pe_t[r];
  #pragma unroll
  for (int ks = 0; ks < 2; ++ks) {
    int rowA = t0 + t16;
    short8 a = *(const short8*)&Cl[rowA*64 + (((ks*4 + q4) ^ (rowA & 7))*8)];
    #pragma unroll
    for (int j = 0; j < 4; ++j) {
      int rowB = 16*j + t16;
      short8 b = *(const short8*)&xT[rowB*64 + (((ks*4 + q4) ^ (rowB & 7))*8)];
      accY[j] = __builtin_amdgcn_mfma_f32_16x16x32_bf16(a, b, accY[j], 0, 0, 0);
    }
  }
  __syncthreads();   // all waves done reading h0l/xT
  // write accY into f32 overlay; swizzle: col ^= (q4<<4)
  #pragma unroll
  for (int j = 0; j < 4; ++j)
    #pragma unroll
    for (int r = 0; r < 4; ++r) {
      int t = t0 + q4*4 + r;
      int p = 16*j + t16;
      fT[t*64 + (p ^ (q4 << 4))] = accY[j][r];
    }
  __syncthreads();
  // coalesced epilogue: thread owns 16 contiguous channels of one row
  {
    int swz = ((erow >> 2) & 3) << 4;
    const float* fr = &fT[erow*64 + (ech0 ^ swz)];
    float4 a0 = *(const float4*)(fr);
    float4 a1 = *(const float4*)(fr + 4);
    float4 a2 = *(const float4*)(fr + 8);
    float4 a3 = *(const float4*)(fr + 12);
    float fv[16] = {a0.x,a0.y,a0.z,a0.w, a1.x,a1.y,a1.z,a1.w,
                    a2.x,a2.y,a2.z,a2.w, a3.x,a3.y,a3.z,a3.w};
    short8 o0, o1;
    #pragma unroll
    for (int e = 0; e < 8; ++e) {
      float v0 = fv[e]   * fsilu(bf2f((unsigned short)g0[e]));
      float v1 = fv[8+e] * fsilu(bf2f((unsigned short)g1[e]));
      o0[e] = (short)f2bf(v0);
      o1[e] = (short)f2bf(v1);
    }
    unsigned short* yp = y + (size_t)(c0 + erow)*DI + h*HD + ech0;
    *(short8*)yp = o0;
    *(short8*)(yp + 8) = o1;
  }
}

__global__ void fill_debug(float* out, float v) {
  int i = blockIdx.x*256 + threadIdx.x;
  if (i < L_TOK*DM) out[i] = v;
}

// ---------------- host ----------------

extern "C" void kernel_launch(void* const* d_in, const int* in_sizes, int n_in,
                              void* d_out, int out_size, void* d_ws, size_t ws_size,
                              hipStream_t stream) {
  const float* query = (const float*)d_in[0];
  const float* qpos  = (const float*)d_in[1];
  const float* pre_w = (const float*)d_in[2];
  const float* pre_b = (const float*)d_in[3];
  const float* fin_w = (const float*)d_in[4];
  const float* fin_b = (const float*)d_in[5];
  float* out = (float*)d_out;

  char* ws = (char*)d_ws;
  size_t off = 0;
  auto alloc = [&](size_t bytes) -> void* {
    void* p = ws + off;
    off += (bytes + 255) & ~(size_t)255;
    return p;
  };
  unsigned long long* keys = (unsigned long long*)alloc((size_t)2*L_TOK*8);
  unsigned long long* skeys = (unsigned long long*)alloc((size_t)2*L_TOK*8);
  unsigned int* ord = (unsigned int*)alloc((size_t)2*L_TOK*4);
  unsigned int* inv = (unsigned int*)alloc((size_t)2*L_TOK*4);
  unsigned int* rpart = (unsigned int*)alloc((size_t)32*2*L_TOK*4);
  float* mmpart = (float*)alloc((size_t)64*6*4);
  float* qn   = (float*)alloc((size_t)L_TOK*DM*4);
  unsigned short* qnbf = (unsigned short*)alloc((size_t)L_TOK*DM*2);
  unsigned short* gate_nat = (unsigned short*)alloc((size_t)L_TOK*DI*2);   // natural-order gate
  unsigned short* xTg    = (unsigned short*)alloc((size_t)512*2*L_TOK*2);  // raw x, transposed [ch][dir*L+t]
  unsigned short* bcraw  = (unsigned short*)alloc((size_t)L_TOK*128*2);    // raw B/C, natural token-major
  unsigned short* bcswz  = (unsigned short*)alloc((size_t)2*NC*2*4096*2);  // conv'd B/C, phaseC-layout tiles
  unsigned short* bcswzA = (unsigned short*)alloc((size_t)2*NC*4096*2);    // conv'd B, phaseA-layout tiles
  unsigned short* ybuf   = (unsigned short*)alloc((size_t)2*L_TOK*DI*2);   // gated (unnormalized) y
  float* dtb  = (float*)alloc((size_t)L_TOK*NH*4);                         // natural-order dt
  unsigned short* Sbuf = (unsigned short*)alloc((size_t)2*NH*NC*4096*2);
  unsigned short* xsT  = (unsigned short*)alloc((size_t)2*NH*NC*4096*2);   // silu(conv(x)) pre-swizzled tiles
  float* Pbuf = (float*)alloc((size_t)2*NH*NC*4);
  unsigned short* WtA = (unsigned short*)alloc((size_t)2*1152*DM*2);
  unsigned short* WtO = (unsigned short*)alloc((size_t)2*DM*DI*2);
  if (off > ws_size) {
    fill_debug<<<(L_TOK*DM + 255)/256, 256, 0, stream>>>(out, (float)(ws_size >> 20));
    return;
  }

  minmax_part<<<64, 256, 0, stream>>>(qpos, mmpart);
  hilbert_kernel<<<L_TOK/256, 256, 0, stream>>>(qpos, mmpart, keys);
  sort_tiles<<<64, 256, 0, stream>>>(keys, skeys);
  rank_partial<<<dim3(16, 2, 32), 256, 0, stream>>>(keys, skeys, rpart);
  rank_scatter<<<(2*L_TOK)/256, 256, 0, stream>>>(keys, rpart, ord, inv);
  tcvt_all<<<208, 256, 0, stream>>>((const float*)d_in[6], (const float*)d_in[13], (const float*)d_in[12],
                                    (const float*)d_in[14], (const float*)d_in[21], (const float*)d_in[20],
                                    WtA, WtO);

  for (int l = 0; l < 2; ++l) {
    int base = 6 + 8*l;
    const float* in_proj  = (const float*)d_in[base+0];
    const float* conv_w   = (const float*)d_in[base+1];
    const float* conv_b   = (const float*)d_in[base+2];
    const float* dt_bias  = (const float*)d_in[base+3];
    const float* A_log    = (const float*)d_in[base+4];
    const float* Dp       = (const float*)d_in[base+5];
    const unsigned short* WtAl = WtA + (size_t)l*1152*DM;
    const unsigned short* WtOl = WtO + (size_t)l*DM*DI;

    if (l == 0)
      ln_kernel<<<L_TOK/4, 256, 0, stream>>>(query, qn, qnbf, pre_w, pre_b);
    gemm_in2<<<1664, 256, 0, stream>>>(qnbf, WtAl, ord, gate_nat, bcraw, xTg);
    dtconv<<<1024, 256, 0, stream>>>(qn, in_proj, dt_bias, dtb,
                                     bcraw, conv_w, conv_b, ord, bcswz, bcswzA);
    phaseA_mfma<<<dim3(NC, NH, 2), 256, 0, stream>>>(xTg, bcswzA, conv_w, conv_b, dtb, A_log, ord, Sbuf, Pbuf, xsT);
    phaseB_scan<<<256, 128, 0, stream>>>(Sbuf, Pbuf);
    phaseC_mfma<<<dim3(NC, NH, 2), 256, 0, stream>>>(bcswz, xsT, gate_nat, dtb, A_log, Dp, ord, Sbuf, ybuf);
    gemm_out_gather<<<512, 256, 0, stream>>>(ybuf, WtOl, inv,
                                             l ? (const float*)out : query, out);
    if (l == 0)
      lnfuse_kernel<<<L_TOK/4, 256, 0, stream>>>(out, qn, qnbf, fin_w, fin_b, pre_w, pre_b);
    else
      lnfuse_kernel<<<L_TOK/4, 256, 0, stream>>>(out, nullptr, nullptr, fin_w, fin_b, pre_w, pre_b);
  }
}